// Round 19
// baseline (380.312 us; speedup 1.0000x reference)
//
#include <hip/hip_runtime.h>
#include <hip/hip_bf16.h>

// Problem constants (fixed by reference)
#define LSEQ   1024
#define BATCH  8
#define MTOT   8192      // B*L
#define DMODEL 512
#define EDIM   1024      // EXPAND*D_MODEL
#define DSTATE 16
#define DTRANK 32
#define DFF    1024
#define EPSLN  1e-5f
#define NCH    16        // scan chunks per direction
#define CHLEN  64        // LSEQ/NCH

typedef __attribute__((ext_vector_type(8))) short bf16x8;
typedef __attribute__((ext_vector_type(4))) float f32x4;

__device__ __forceinline__ unsigned short f2bf(float f) {
    __hip_bfloat16 h = __float2bfloat16(f);   // RNE
    unsigned short u;
    __builtin_memcpy(&u, &h, 2);
    return u;
}
__device__ __forceinline__ float bf2f(unsigned short u) {
    unsigned int x = ((unsigned int)u) << 16;
    float f;
    __builtin_memcpy(&f, &x, 4);
    return f;
}

// fast softplus: HW v_exp + v_log (libm log1pf cost r16's dt 78us)
__device__ __forceinline__ float softplus_fast(float v) {
    float sp = __logf(1.f + __expf(v));
    return v > 80.f ? v : sp;
}

// q^(n+1) for n=0..15, log-depth chain (replaces 16 exps when Aen=-(n+1))
__device__ __forceinline__ void pow16(float q, float* da) {
    da[0] = q;
    da[1] = q * q;
    da[2] = da[1] * q;
    da[3] = da[1] * da[1];
    da[4] = da[3] * da[0];
    da[5] = da[3] * da[1];
    da[6] = da[3] * da[2];
    da[7] = da[3] * da[3];
    da[8]  = da[7] * da[0];
    da[9]  = da[7] * da[1];
    da[10] = da[7] * da[2];
    da[11] = da[7] * da[3];
    da[12] = da[7] * da[4];
    da[13] = da[7] * da[5];
    da[14] = da[7] * da[6];
    da[15] = da[7] * da[7];
}

// async global->LDS, 16B per lane. LDS dest = wave-uniform base + lane*16.
__device__ __forceinline__ void gload16(const unsigned short* g, unsigned short* l) {
    __builtin_amdgcn_global_load_lds(
        (const __attribute__((address_space(1))) void*)g,
        (__attribute__((address_space(3))) void*)l, 16, 0, 0);
}

// ---------------------------------------------------------------------------
// Merged f32->bf16 cast: 9 segments in one dispatch.
// ---------------------------------------------------------------------------
__device__ __forceinline__ void cast8(const float* in, unsigned short* out, int i) {
    float4 f0 = *(const float4*)&in[(size_t)i * 8];
    float4 f1 = *(const float4*)&in[(size_t)i * 8 + 4];
    unsigned short v[8] = {f2bf(f0.x), f2bf(f0.y), f2bf(f0.z), f2bf(f0.w),
                           f2bf(f1.x), f2bf(f1.y), f2bf(f1.z), f2bf(f1.w)};
    *(uint4*)&out[(size_t)i * 8] = *(uint4*)v;
}

__global__ __launch_bounds__(256) void cast_all(
    const float* x,  unsigned short* xb,
    const float* w1, unsigned short* w1b,
    const float* w2, unsigned short* w2b,
    const float* w3, unsigned short* w3b,
    const float* w4, unsigned short* w4b,
    const float* w5, unsigned short* w5b,
    const float* w6, unsigned short* w6b,
    const float* w7, unsigned short* w7b,
    const float* w8, unsigned short* w8b)
{
    const int blk = blockIdx.x;
    const int tid = threadIdx.x;
    if (blk < 2048)        cast8(x,  xb,  blk * 256 + tid);
    else if (blk < 2560)   cast8(w1, w1b, (blk - 2048) * 256 + tid);
    else if (blk < 3072)   cast8(w2, w2b, (blk - 2560) * 256 + tid);
    else if (blk < 3328)   cast8(w3, w3b, (blk - 3072) * 256 + tid);
    else if (blk < 3584)   cast8(w4, w4b, (blk - 3328) * 256 + tid);
    else if (blk < 3840)   cast8(w5, w5b, (blk - 3584) * 256 + tid);
    else if (blk < 4096)   cast8(w6, w6b, (blk - 3840) * 256 + tid);
    else if (blk < 4128)   cast8(w7, w7b, (blk - 4096) * 256 + tid);
    else                   cast8(w8, w8b, (blk - 4128) * 256 + tid);
}

// ---------------------------------------------------------------------------
// Fused dual-direction in-projection (bf16 out, flip-the-write for bwd).
// r18: LDS-buffered epilogue — C-tile staged bf16 in the dead 32KB LDS, then
// written as contiguous 16B chunks (fixes 1.6x write amplification: r17
// WRITE_SIZE 110MB vs 64MB ideal from 2B-granule strided stores).
// ---------------------------------------------------------------------------
__global__ __launch_bounds__(256) void inproj_bf16(
    const unsigned short* __restrict__ A,
    const unsigned short* __restrict__ Wf,
    const unsigned short* __restrict__ Wb,
    unsigned short* __restrict__ Cf,
    unsigned short* __restrict__ Cb)
{
    __shared__ unsigned short As[2][128][32];
    __shared__ unsigned short Ws[2][128][32];

    const int K = DMODEL;
    const int tid = threadIdx.x;
    const int rowbase = blockIdx.y * 128;
    const int colg = blockIdx.x * 128;
    const int back = colg >= 2048;
    const unsigned short* W = back ? Wb : Wf;
    const int colbase = colg - (back ? 2048 : 0);
    unsigned short* Cout = back ? Cb : Cf;

    const int wave = tid >> 6, lane = tid & 63;
    const int wm = wave >> 1, wn = wave & 1;
    const int lr = lane & 15;
    const int lc = lane >> 4;

    const int r0 = tid >> 2;
    const int cl = (tid & 3) ^ ((r0 >> 1) & 3);
    const unsigned short* Ag0 = A + (size_t)(rowbase + r0) * K + (cl << 3);
    const unsigned short* Ag1 = A + (size_t)(rowbase + r0 + 64) * K + (cl << 3);
    const unsigned short* Wg0 = W + (size_t)(colbase + r0) * K + (cl << 3);
    const unsigned short* Wg1 = W + (size_t)(colbase + r0 + 64) * K + (cl << 3);

    f32x4 acc[4][4];
#pragma unroll
    for (int i = 0; i < 4; ++i)
#pragma unroll
        for (int j = 0; j < 4; ++j)
            acc[i][j] = (f32x4){0.f, 0.f, 0.f, 0.f};

#define G_STAGE(bi, ko) do {                                   \
        gload16(Ag0 + (ko), &As[bi][wave << 4][0]);            \
        gload16(Ag1 + (ko), &As[bi][64 + (wave << 4)][0]);     \
        gload16(Wg0 + (ko), &Ws[bi][wave << 4][0]);            \
        gload16(Wg1 + (ko), &Ws[bi][64 + (wave << 4)][0]);     \
    } while (0)

#define G_COMPUTE(bi) do {                                     \
        bf16x8 af[4], bfv[4];                                  \
        _Pragma("unroll")                                      \
        for (int i = 0; i < 4; ++i) {                          \
            int R = wm * 64 + i * 16 + lr;                     \
            int pc = lc ^ ((R >> 1) & 3);                      \
            af[i] = *(const bf16x8*)&As[bi][R][pc << 3];       \
        }                                                      \
        _Pragma("unroll")                                      \
        for (int j = 0; j < 4; ++j) {                          \
            int R = wn * 64 + j * 16 + lr;                     \
            int pc = lc ^ ((R >> 1) & 3);                      \
            bfv[j] = *(const bf16x8*)&Ws[bi][R][pc << 3];      \
        }                                                      \
        _Pragma("unroll")                                      \
        for (int i = 0; i < 4; ++i)                            \
            _Pragma("unroll")                                  \
            for (int j = 0; j < 4; ++j)                        \
                acc[i][j] = __builtin_amdgcn_mfma_f32_16x16x32_bf16( \
                    af[i], bfv[j], acc[i][j], 0, 0, 0);        \
    } while (0)

    G_STAGE(0, 0);
    __syncthreads();
    for (int k0 = 0; k0 < K; k0 += 64) {
        G_STAGE(1, k0 + 32);
        __builtin_amdgcn_sched_barrier(0);
        G_COMPUTE(0);
        __syncthreads();
        if (k0 + 64 < K) G_STAGE(0, k0 + 64);
        __builtin_amdgcn_sched_barrier(0);
        G_COMPUTE(1);
        __syncthreads();
    }
#undef G_STAGE
#undef G_COMPUTE

    // Epilogue: stage bf16 tile in LDS (128x128x2B = 32KB, exact fit), then
    // coalesced 16B-chunk writes (flip is row-granular -> stays coalesced).
    __syncthreads();
    unsigned short* Cl = &As[0][0][0];
    const int rloc0 = wm * 64 + ((lane >> 4) << 2);
    const int cloc0 = wn * 64 + lr;
#pragma unroll
    for (int j = 0; j < 4; ++j)
#pragma unroll
        for (int i = 0; i < 4; ++i)
#pragma unroll
            for (int r = 0; r < 4; ++r)
                Cl[(rloc0 + i * 16 + r) * 128 + cloc0 + j * 16] =
                    f2bf(acc[i][j][r]);
    __syncthreads();
#pragma unroll
    for (int c = 0; c < 8; ++c) {
        int q = tid * 8 + c;              // 0..2047 chunks of 8 ush
        int rl = q >> 4;                  // 16 chunks per 128-col row
        int cc = (q & 15) << 3;
        int row = rowbase + rl;
        if (back) row = (row & ~(LSEQ - 1)) + (LSEQ - 1 - (row & (LSEQ - 1)));
        *(uint4*)&Cout[(size_t)row * 2048 + colbase + cc] =
            *(const uint4*)&Cl[rl * 128 + cc];
    }
}

// ---------------------------------------------------------------------------
// bf16 MFMA GEMM v6: rows >= MTOT switch to (A_hi, W_hi). LDS-buffered
// coalesced epilogue (bf16: whole tile; f32: two 64-row halves).
// ---------------------------------------------------------------------------
__global__ __launch_bounds__(256) void gemm_bf16(
    const unsigned short* __restrict__ A,
    const unsigned short* __restrict__ A_hi, int lda,
    const unsigned short* __restrict__ W,
    const unsigned short* __restrict__ W_hi,
    const float* __restrict__ bias,
    void* __restrict__ Cp, int ldc, int c_bf16,
    int K, int act)
{
    __shared__ unsigned short As[2][128][32];
    __shared__ unsigned short Ws[2][128][32];

    const int tid = threadIdx.x;
    const int rowbase = blockIdx.y * 128;
    const int colbase = blockIdx.x * 128;
    const unsigned short* Ause = A;
    const unsigned short* Wuse = W;
    int rlocal = rowbase;
    if (rowbase >= MTOT) { Ause = A_hi; Wuse = W_hi; rlocal = rowbase - MTOT; }

    const int wave = tid >> 6, lane = tid & 63;
    const int wm = wave >> 1, wn = wave & 1;
    const int lr = lane & 15;
    const int lc = lane >> 4;

    const int r0 = tid >> 2;
    const int cl = (tid & 3) ^ ((r0 >> 1) & 3);
    const unsigned short* Ag0 = Ause + (size_t)(rlocal + r0) * lda + (cl << 3);
    const unsigned short* Ag1 = Ause + (size_t)(rlocal + r0 + 64) * lda + (cl << 3);
    const unsigned short* Wg0 = Wuse + (size_t)(colbase + r0) * K + (cl << 3);
    const unsigned short* Wg1 = Wuse + (size_t)(colbase + r0 + 64) * K + (cl << 3);

    f32x4 acc[4][4];
#pragma unroll
    for (int i = 0; i < 4; ++i)
#pragma unroll
        for (int j = 0; j < 4; ++j)
            acc[i][j] = (f32x4){0.f, 0.f, 0.f, 0.f};

#define G_STAGE(bi, ko) do {                                   \
        gload16(Ag0 + (ko), &As[bi][wave << 4][0]);            \
        gload16(Ag1 + (ko), &As[bi][64 + (wave << 4)][0]);     \
        gload16(Wg0 + (ko), &Ws[bi][wave << 4][0]);            \
        gload16(Wg1 + (ko), &Ws[bi][64 + (wave << 4)][0]);     \
    } while (0)

#define G_COMPUTE(bi) do {                                     \
        bf16x8 af[4], bfv[4];                                  \
        _Pragma("unroll")                                      \
        for (int i = 0; i < 4; ++i) {                          \
            int R = wm * 64 + i * 16 + lr;                     \
            int pc = lc ^ ((R >> 1) & 3);                      \
            af[i] = *(const bf16x8*)&As[bi][R][pc << 3];       \
        }                                                      \
        _Pragma("unroll")                                      \
        for (int j = 0; j < 4; ++j) {                          \
            int R = wn * 64 + j * 16 + lr;                     \
            int pc = lc ^ ((R >> 1) & 3);                      \
            bfv[j] = *(const bf16x8*)&Ws[bi][R][pc << 3];      \
        }                                                      \
        _Pragma("unroll")                                      \
        for (int i = 0; i < 4; ++i)                            \
            _Pragma("unroll")                                  \
            for (int j = 0; j < 4; ++j)                        \
                acc[i][j] = __builtin_amdgcn_mfma_f32_16x16x32_bf16( \
                    af[i], bfv[j], acc[i][j], 0, 0, 0);        \
    } while (0)

    G_STAGE(0, 0);
    __syncthreads();
    for (int k0 = 0; k0 < K; k0 += 64) {
        G_STAGE(1, k0 + 32);
        __builtin_amdgcn_sched_barrier(0);
        G_COMPUTE(0);
        __syncthreads();
        if (k0 + 64 < K) G_STAGE(0, k0 + 64);
        __builtin_amdgcn_sched_barrier(0);
        G_COMPUTE(1);
        __syncthreads();
    }
#undef G_STAGE
#undef G_COMPUTE

    // bias + act in registers
    const int cloc0 = wn * 64 + lr;
#pragma unroll
    for (int j = 0; j < 4; ++j) {
        float bv = bias ? bias[colbase + cloc0 + j * 16] : 0.f;
#pragma unroll
        for (int i = 0; i < 4; ++i)
#pragma unroll
            for (int r = 0; r < 4; ++r) {
                float v = acc[i][j][r] + bv;
                acc[i][j][r] = (act == 1) ? fmaxf(v, 0.f) : v;
            }
    }

    __syncthreads();
    const int rloc0 = wm * 64 + ((lane >> 4) << 2);
    if (c_bf16) {
        unsigned short* Cl = &As[0][0][0];     // 128x128 bf16 = 32KB
#pragma unroll
        for (int j = 0; j < 4; ++j)
#pragma unroll
            for (int i = 0; i < 4; ++i)
#pragma unroll
                for (int r = 0; r < 4; ++r)
                    Cl[(rloc0 + i * 16 + r) * 128 + cloc0 + j * 16] =
                        f2bf(acc[i][j][r]);
        __syncthreads();
#pragma unroll
        for (int c = 0; c < 8; ++c) {
            int q = tid * 8 + c;
            int rl = q >> 4;
            int cc = (q & 15) << 3;
            *(uint4*)&((unsigned short*)Cp)[(size_t)(rowbase + rl) * ldc + cc + colbase] =
                *(const uint4*)&Cl[rl * 128 + cc];
        }
    } else {
        float* Cl = (float*)&As[0][0][0];      // 64x128 f32 = 32KB per half
#pragma unroll
        for (int half = 0; half < 2; ++half) {
            if (wm == half) {
#pragma unroll
                for (int j = 0; j < 4; ++j)
#pragma unroll
                    for (int i = 0; i < 4; ++i)
#pragma unroll
                        for (int r = 0; r < 4; ++r)
                            Cl[(rloc0 - half * 64 + i * 16 + r) * 128 +
                               cloc0 + j * 16] = acc[i][j][r];
            }
            __syncthreads();
#pragma unroll
            for (int c = 0; c < 8; ++c) {
                int q = tid * 8 + c;          // 2048 chunks of 4 floats
                int rl = q >> 5;              // 32 chunks per 128-col row
                int cc = (q & 31) << 2;
                *(float4*)&((float*)Cp)[(size_t)(rowbase + half * 64 + rl) * ldc +
                                        colbase + cc] =
                    *(const float4*)&Cl[rl * 128 + cc];
            }
            __syncthreads();
        }
    }
}

// ---------------------------------------------------------------------------
// Dual-dir xproj (split-K): dbc2[2M,64] += xcbf2[2M,1024] @ xpw^T
// ---------------------------------------------------------------------------
__global__ __launch_bounds__(256) void xproj_bf16(
    const unsigned short* __restrict__ A,
    const unsigned short* __restrict__ Wf,
    const unsigned short* __restrict__ Wb,
    float* __restrict__ Cp)
{
    __shared__ unsigned short As[2][128][32];
    __shared__ unsigned short Ws[2][64][32];

    const int tid = threadIdx.x;
    const int rowbase = blockIdx.x * 128;
    const int kbase = blockIdx.y * 256;
    const unsigned short* W = (rowbase >= MTOT) ? Wb : Wf;
    const int wave = tid >> 6, lane = tid & 63;
    const int wm = wave >> 1, wn = wave & 1;
    const int lr = lane & 15;
    const int lc = lane >> 4;

    const int r0 = tid >> 2;
    const int cl = (tid & 3) ^ ((r0 >> 1) & 3);
    const unsigned short* Ag0 = A + (size_t)(rowbase + r0) * EDIM + kbase + (cl << 3);
    const unsigned short* Ag1 = A + (size_t)(rowbase + r0 + 64) * EDIM + kbase + (cl << 3);
    const unsigned short* Wg  = W + (size_t)r0 * EDIM + kbase + (cl << 3);

    f32x4 acc[4][2];
#pragma unroll
    for (int i = 0; i < 4; ++i)
#pragma unroll
        for (int j = 0; j < 2; ++j)
            acc[i][j] = (f32x4){0.f, 0.f, 0.f, 0.f};

#define X_STAGE(bi, ko) do {                                   \
        gload16(Ag0 + (ko), &As[bi][wave << 4][0]);            \
        gload16(Ag1 + (ko), &As[bi][64 + (wave << 4)][0]);     \
        gload16(Wg  + (ko), &Ws[bi][wave << 4][0]);            \
    } while (0)

#define X_COMPUTE(bi) do {                                     \
        bf16x8 af[4], bfv[2];                                  \
        _Pragma("unroll")                                      \
        for (int i = 0; i < 4; ++i) {                          \
            int R = wm * 64 + i * 16 + lr;                     \
            int pc = lc ^ ((R >> 1) & 3);                      \
            af[i] = *(const bf16x8*)&As[bi][R][pc << 3];       \
        }                                                      \
        _Pragma("unroll")                                      \
        for (int j = 0; j < 2; ++j) {                          \
            int R = wn * 32 + j * 16 + lr;                     \
            int pc = lc ^ ((R >> 1) & 3);                      \
            bfv[j] = *(const bf16x8*)&Ws[bi][R][pc << 3];      \
        }                                                      \
        _Pragma("unroll")                                      \
        for (int i = 0; i < 4; ++i)                            \
            _Pragma("unroll")                                  \
            for (int j = 0; j < 2; ++j)                        \
                acc[i][j] = __builtin_amdgcn_mfma_f32_16x16x32_bf16( \
                    af[i], bfv[j], acc[i][j], 0, 0, 0);        \
    } while (0)

    X_STAGE(0, 0);
    __syncthreads();
    for (int k0 = 0; k0 < 256; k0 += 64) {
        X_STAGE(1, k0 + 32);
        __builtin_amdgcn_sched_barrier(0);
        X_COMPUTE(0);
        __syncthreads();
        if (k0 + 64 < 256) X_STAGE(0, k0 + 64);
        __builtin_amdgcn_sched_barrier(0);
        X_COMPUTE(1);
        __syncthreads();
    }
#undef X_STAGE
#undef X_COMPUTE

    const int crow0 = rowbase + wm * 64 + ((lane >> 4) << 2);
    const int ccol0 = wn * 32 + lr;
#pragma unroll
    for (int i = 0; i < 4; ++i)
#pragma unroll
        for (int j = 0; j < 2; ++j)
#pragma unroll
            for (int r = 0; r < 4; ++r)
                atomicAdd(&Cp[(size_t)(crow0 + i * 16 + r) * 64 + ccol0 + j * 16],
                          acc[i][j][r]);
}

// ---------------------------------------------------------------------------
// Dual-dir dt: delta2[2M][1024] (bf16), 16 rows/block, fast softplus.
// ---------------------------------------------------------------------------
__global__ __launch_bounds__(256) void dt_fused(
    const float* __restrict__ dbc2,
    const float* __restrict__ dtw_f, const float* __restrict__ dtb_f,
    const float* __restrict__ dtw_b, const float* __restrict__ dtb_b,
    unsigned short* __restrict__ delta2)
{
    __shared__ float sd[16][32];

    const int e  = blockIdx.x * 256 + threadIdx.x;
    const int m0 = blockIdx.y * 16;
    const float* dtw = (m0 >= MTOT) ? dtw_b : dtw_f;
    const float* dtb = (m0 >= MTOT) ? dtb_b : dtb_f;

    float w[32];
#pragma unroll
    for (int k = 0; k < 8; ++k) {
        float4 v = *(const float4*)&dtw[(size_t)e * 32 + k * 4];
        w[k * 4 + 0] = v.x; w[k * 4 + 1] = v.y;
        w[k * 4 + 2] = v.z; w[k * 4 + 3] = v.w;
    }
    const float bv = dtb[e];

    if (threadIdx.x < 128) {
        int r = threadIdx.x >> 3;
        int c = (threadIdx.x & 7) << 2;
        *(float4*)&sd[r][c] = *(const float4*)&dbc2[(size_t)(m0 + r) * 64 + c];
    }
    __syncthreads();

#pragma unroll
    for (int mm = 0; mm < 16; ++mm) {
        float acc = bv;
#pragma unroll
        for (int k = 0; k < 8; ++k) {
            float4 b4 = *(const float4*)&sd[mm][k * 4];
            acc = fmaf(b4.x, w[k * 4 + 0], acc);
            acc = fmaf(b4.y, w[k * 4 + 1], acc);
            acc = fmaf(b4.z, w[k * 4 + 2], acc);
            acc = fmaf(b4.w, w[k * 4 + 3], acc);
        }
        delta2[(size_t)(m0 + mm) * EDIM + e] = f2bf(softplus_fast(acc));
    }
}

// ---------------------------------------------------------------------------
// Dual-dir depthwise causal conv + bias + silu (bf16 in/out).
// ---------------------------------------------------------------------------
__global__ __launch_bounds__(256) void conv_silu(
    const unsigned short* __restrict__ xzf, const unsigned short* __restrict__ xzb_,
    const float* __restrict__ cwf, const float* __restrict__ cbf,
    const float* __restrict__ cwb, const float* __restrict__ cbb,
    unsigned short* __restrict__ xcbf2)
{
    const int dir = blockIdx.y;
    const unsigned short* xzb = dir ? xzb_ : xzf;
    const float* cw = dir ? cwb : cwf;
    const float* cb = dir ? cbb : cbf;
    const int e = threadIdx.x << 2;
    const int m = blockIdx.x;
    const int t = m & (LSEQ - 1);

    float4 w0 = *(const float4*)&cw[e * 4];
    float4 w1 = *(const float4*)&cw[e * 4 + 4];
    float4 w2 = *(const float4*)&cw[e * 4 + 8];
    float4 w3 = *(const float4*)&cw[e * 4 + 12];
    float4 acc = *(const float4*)&cb[e];
#pragma unroll
    for (int k = 0; k < 4; ++k) {
        if (t - 3 + k >= 0) {
            const unsigned short* p = &xzb[(size_t)(m - 3 + k) * 2048 + e];
            uint2 raw = *(const uint2*)p;
            float x0 = bf2f((unsigned short)(raw.x & 0xffff));
            float x1 = bf2f((unsigned short)(raw.x >> 16));
            float x2 = bf2f((unsigned short)(raw.y & 0xffff));
            float x3 = bf2f((unsigned short)(raw.y >> 16));
            acc.x = fmaf((&w0.x)[k], x0, acc.x);
            acc.y = fmaf((&w1.x)[k], x1, acc.y);
            acc.z = fmaf((&w2.x)[k], x2, acc.z);
            acc.w = fmaf((&w3.x)[k], x3, acc.w);
        }
    }
    float4 o;
    o.x = acc.x / (1.f + __expf(-acc.x));
    o.y = acc.y / (1.f + __expf(-acc.y));
    o.z = acc.z / (1.f + __expf(-acc.z));
    o.w = acc.w / (1.f + __expf(-acc.w));
    unsigned short b4[4] = {f2bf(o.x), f2bf(o.y), f2bf(o.z), f2bf(o.w)};
    *(uint2*)&xcbf2[((size_t)dir * MTOT + m) * EDIM + e] = *(uint2*)b4;
}

// ---------------------------------------------------------------------------
// Dual-dir chunked scan with power-chain fast path.
// ---------------------------------------------------------------------------
__global__ __launch_bounds__(256) void scan_part1(
    const unsigned short* __restrict__ delta2,
    const unsigned short* __restrict__ xcbf2,
    const float* __restrict__ dbc2,
    const float* __restrict__ Alog_f, const float* __restrict__ Alog_b,
    float* __restrict__ Psum, float* __restrict__ Ssum)
{
    __shared__ float sB[CHLEN][16];

    const int bd = blockIdx.y;               // 0..15 = dir*8 + b
    const int dir = bd >> 3;
    const int b = bd & 7;
    const int ch = blockIdx.z;
    const int tid = threadIdx.x;
    const int e  = blockIdx.x * 256 + tid;
    const size_t dirOff = (size_t)dir * MTOT;
    const int row0 = b * LSEQ + ch * CHLEN;
    const float* Alog = dir ? Alog_b : Alog_f;

#pragma unroll
    for (int it = 0; it < 4; ++it) {
        int q = tid + it * 256;
        int t = q >> 4, n = q & 15;
        sB[t][n] = dbc2[(dirOff + row0 + t) * 64 + 32 + n];
    }

    float Aen[16];
    bool fastA = true;
#pragma unroll
    for (int k = 0; k < 4; ++k) {
        float4 a4 = *(const float4*)&Alog[e * DSTATE + k * 4];
        Aen[k * 4 + 0] = -__expf(a4.x);
        Aen[k * 4 + 1] = -__expf(a4.y);
        Aen[k * 4 + 2] = -__expf(a4.z);
        Aen[k * 4 + 3] = -__expf(a4.w);
    }
#pragma unroll
    for (int n = 0; n < 16; ++n)
        fastA = fastA && (fabsf(Aen[n] + (float)(n + 1)) <= 1e-3f * (n + 1));

    float h[16];
#pragma unroll
    for (int n = 0; n < 16; ++n) h[n] = 0.f;
    float sumd = 0.f;

    __syncthreads();

    const size_t base = (dirOff + row0) * EDIM + e;
    float dnx = bf2f(delta2[base]);
    float xnx = bf2f(xcbf2[base]);

    for (int t = 0; t < CHLEN; ++t) {
        float d = dnx, xcv = xnx;
        if (t + 1 < CHLEN) {
            dnx = bf2f(delta2[base + (size_t)(t + 1) * EDIM]);
            xnx = bf2f(xcbf2[base + (size_t)(t + 1) * EDIM]);
        }
        sumd += d;
        float dx = d * xcv;
        float Bt[16];
        *(float4*)&Bt[0]  = *(const float4*)&sB[t][0];
        *(float4*)&Bt[4]  = *(const float4*)&sB[t][4];
        *(float4*)&Bt[8]  = *(const float4*)&sB[t][8];
        *(float4*)&Bt[12] = *(const float4*)&sB[t][12];
        float da[16];
        if (fastA) {
            pow16(__expf(-d), da);
        } else {
#pragma unroll
            for (int n = 0; n < 16; ++n) da[n] = __expf(d * Aen[n]);
        }
#pragma unroll
        for (int n = 0; n < 16; ++n)
            h[n] = fmaf(da[n], h[n], dx * Bt[n]);
    }

    size_t idx = ((size_t)(bd * NCH + ch) * EDIM + e) * DSTATE;
    float P[16];
    if (fastA) {
        pow16(__expf(-sumd), P);
    } else {
#pragma unroll
        for (int n = 0; n < 16; ++n) P[n] = __expf(Aen[n] * sumd);
    }
#pragma unroll
    for (int k = 0; k < 4; ++k) {
        *(float4*)&Psum[idx + k * 4] = *(float4*)&P[k * 4];
        *(float4*)&Ssum[idx + k * 4] = *(float4*)&h[k * 4];
    }
}

__global__ __launch_bounds__(256) void scan_combine(
    float* __restrict__ Psum, const float* __restrict__ Ssum)
{
    int i = blockIdx.x * 256 + threadIdx.x;
    int bd = i >> 14;
    int r = i & 16383;
    float H = 0.f;
#pragma unroll
    for (int ch = 0; ch < NCH; ++ch) {
        size_t idx = ((size_t)(bd * NCH + ch) << 14) + r;
        float p = Psum[idx];
        float s = Ssum[idx];
        Psum[idx] = H;
        H = fmaf(p, H, s);
    }
}

__global__ __launch_bounds__(256) void scan_part2(
    unsigned short* __restrict__ delta2,          // in: delta, out: g (in-place)
    const unsigned short* __restrict__ xcbf2,
    const float* __restrict__ dbc2,
    const float* __restrict__ Alog_f, const float* __restrict__ Alog_b,
    const float* __restrict__ Dvec_f, const float* __restrict__ Dvec_b,
    const unsigned short* __restrict__ xzf, const unsigned short* __restrict__ xzb_,
    const float* __restrict__ Hstart)
{
    __shared__ float sB[CHLEN][16], sC[CHLEN][16];

    const int bd = blockIdx.y;
    const int dir = bd >> 3;
    const int b = bd & 7;
    const int ch = blockIdx.z;
    const int tid = threadIdx.x;
    const int e  = blockIdx.x * 256 + tid;
    const size_t dirOff = (size_t)dir * MTOT;
    const int row0 = b * LSEQ + ch * CHLEN;
    const float* Alog = dir ? Alog_b : Alog_f;
    const float* Dvec = dir ? Dvec_b : Dvec_f;
    const unsigned short* zb = dir ? xzb_ : xzf;

#pragma unroll
    for (int it = 0; it < 8; ++it) {
        int q = tid + it * 256;
        int t = q >> 5, c = q & 31;
        float v = dbc2[(dirOff + row0 + t) * 64 + 32 + c];
        if (c < 16) sB[t][c] = v; else sC[t][c - 16] = v;
    }

    float Aen[16];
    bool fastA = true;
#pragma unroll
    for (int k = 0; k < 4; ++k) {
        float4 a4 = *(const float4*)&Alog[e * DSTATE + k * 4];
        Aen[k * 4 + 0] = -__expf(a4.x);
        Aen[k * 4 + 1] = -__expf(a4.y);
        Aen[k * 4 + 2] = -__expf(a4.z);
        Aen[k * 4 + 3] = -__expf(a4.w);
    }
#pragma unroll
    for (int n = 0; n < 16; ++n)
        fastA = fastA && (fabsf(Aen[n] + (float)(n + 1)) <= 1e-3f * (n + 1));
    const float Dv = Dvec[e];

    float h[16];
    {
        size_t idx = ((size_t)(bd * NCH + ch) * EDIM + e) * DSTATE;
#pragma unroll
        for (int k = 0; k < 4; ++k)
            *(float4*)&h[k * 4] = *(const float4*)&Hstart[idx + k * 4];
    }

    __syncthreads();

    const size_t base = (dirOff + row0) * EDIM + e;
    const size_t zbase = (size_t)row0 * 2048 + 1024 + e;
    float dnx = bf2f(delta2[base]);
    float xnx = bf2f(xcbf2[base]);
    float znx = bf2f(zb[zbase]);

    for (int t = 0; t < CHLEN; ++t) {
        float d = dnx, xcv = xnx, zv = znx;
        if (t + 1 < CHLEN) {
            dnx = bf2f(delta2[base + (size_t)(t + 1) * EDIM]);
            xnx = bf2f(xcbf2[base + (size_t)(t + 1) * EDIM]);
            znx = bf2f(zb[zbase + (size_t)(t + 1) * 2048]);
        }
        float dx = d * xcv;
        float Bt[16], Ct[16];
        *(float4*)&Bt[0]  = *(const float4*)&sB[t][0];
        *(float4*)&Bt[4]  = *(const float4*)&sB[t][4];
        *(float4*)&Bt[8]  = *(const float4*)&sB[t][8];
        *(float4*)&Bt[12] = *(const float4*)&sB[t][12];
        *(float4*)&Ct[0]  = *(const float4*)&sC[t][0];
        *(float4*)&Ct[4]  = *(const float4*)&sC[t][4];
        *(float4*)&Ct[8]  = *(const float4*)&sC[t][8];
        *(float4*)&Ct[12] = *(const float4*)&sC[t][12];
        float da[16];
        if (fastA) {
            pow16(__expf(-d), da);
        } else {
#pragma unroll
            for (int n = 0; n < 16; ++n) da[n] = __expf(d * Aen[n]);
        }
        float y = 0.f;
#pragma unroll
        for (int n = 0; n < 16; ++n) {
            h[n] = fmaf(da[n], h[n], dx * Bt[n]);
            y = fmaf(h[n], Ct[n], y);
        }
        y = fmaf(Dv, xcv, y);
        float sig = 1.f / (1.f + __expf(-zv));
        float zz  = zv * sig;
        delta2[base + (size_t)t * EDIM] = f2bf(fmaf(zz, y - xcv, xcv));
    }
}

// ---------------------------------------------------------------------------
__device__ __forceinline__ void block_reduce4(float4& s, float4* red, int tid)
{
#pragma unroll
    for (int off = 1; off < 64; off <<= 1) {
        s.x += __shfl_xor(s.x, off);
        s.y += __shfl_xor(s.y, off);
        s.z += __shfl_xor(s.z, off);
        s.w += __shfl_xor(s.w, off);
    }
    if ((tid & 63) == 0) red[tid >> 6] = s;
    __syncthreads();
    float4 a = red[0], b = red[1], c = red[2], d = red[3];
    s.x = a.x + b.x + c.x + d.x;
    s.y = a.y + b.y + c.y + d.y;
    s.z = a.z + b.z + c.z + d.z;
    s.w = a.w + b.w + c.w + d.w;
}

__global__ __launch_bounds__(256) void ln_combine(
    const float* __restrict__ yproj, const float* __restrict__ x,
    const float* __restrict__ g1, const float* __restrict__ b1,
    const float* __restrict__ g2, const float* __restrict__ b2,
    float* __restrict__ xs, unsigned short* __restrict__ xsbf)
{
    __shared__ float4 red[4];
    const int row = blockIdx.x, tid = threadIdx.x;
    const float* yf = yproj + (size_t)row * DMODEL;
    const float* yb = yproj + (size_t)(MTOT + row) * DMODEL;
    const float* xr = x + (size_t)row * DMODEL;

    float vf[2], vb[2];
#pragma unroll
    for (int j = 0; j < 2; ++j) {
        int i = tid + j * 256;
        float xi = xr[i];
        vf[j] = yf[i] + xi;
        vb[j] = yb[i] + xi;
    }
    float4 s = make_float4(vf[0] + vf[1], vf[0] * vf[0] + vf[1] * vf[1],
                           vb[0] + vb[1], vb[0] * vb[0] + vb[1] * vb[1]);
    block_reduce4(s, red, tid);
    const float inv = 1.f / DMODEL;
    float mf = s.x * inv, mb = s.z * inv;
    float rf = rsqrtf(s.y * inv - mf * mf + EPSLN);
    float rb = rsqrtf(s.w * inv - mb * mb + EPSLN);
#pragma unroll
    for (int j = 0; j < 2; ++j) {
        int i = tid + j * 256;
        float a  = (vf[j] - mf) * rf * g1[i] + b1[i];
        float bb = (vb[j] - mb) * rb * g2[i] + b2[i];
        float v = a + bb;
        xs[(size_t)row * DMODEL + i] = v;
        xsbf[(size_t)row * DMODEL + i] = f2bf(v);
    }
}

__global__ __launch_bounds__(256) void ln_final(
    const float* __restrict__ h2, const float* __restrict__ xs,
    const float* __restrict__ g3, const float* __restrict__ b3,
    float* __restrict__ out)
{
    __shared__ float4 red[4];
    const int row = blockIdx.x, tid = threadIdx.x;
    float v[2];
#pragma unroll
    for (int j = 0; j < 2; ++j) {
        int i = tid + j * 256;
        v[j] = h2[(size_t)row * DMODEL + i] + xs[(size_t)row * DMODEL + i];
    }
    float4 s = make_float4(v[0] + v[1], v[0] * v[0] + v[1] * v[1], 0.f, 0.f);
    block_reduce4(s, red, tid);
    const float inv = 1.f / DMODEL;
    float m  = s.x * inv;
    float rs = rsqrtf(s.y * inv - m * m + EPSLN);
#pragma unroll
    for (int j = 0; j < 2; ++j) {
        int i = tid + j * 256;
        out[(size_t)row * DMODEL + i] = (v[j] - m) * rs * g3[i] + b3[i];
    }
}

// ---------------------------------------------------------------------------
extern "C" void kernel_launch(void* const* d_in, const int* in_sizes, int n_in,
                              void* d_out, int out_size, void* d_ws, size_t ws_size,
                              hipStream_t stream)
{
    (void)in_sizes; (void)n_in;

    const float* x    = (const float*)d_in[28];
    const float* n1g  = (const float*)d_in[18];
    const float* n1b  = (const float*)d_in[19];
    const float* n2g  = (const float*)d_in[20];
    const float* n2b  = (const float*)d_in[21];
    const float* n3g  = (const float*)d_in[22];
    const float* n3b  = (const float*)d_in[23];
    const float* ff1w = (const float*)d_in[24];
    const float* ff1b = (const float*)d_in[25];
    const float* ff2w = (const float*)d_in[26];
    const float* ff2b = (const float*)d_in[27];

    const size_t need_floats =
        (size_t)MTOT * 2048 + (size_t)MTOT * 1024 + (size_t)MTOT * 1024 +
        (size_t)MTOT * 64 + (size_t)2 * MTOT * 512 + (size_t)MTOT * 512;
    if (ws_size < need_floats * sizeof(float)) return;
    if (out_size < MTOT * DMODEL) return;

    float* ws = (float*)d_ws;
    float* region0 = ws;
    float* region1 = ws + (size_t)16 * 1048576;
    float* region2 = ws + (size_t)24 * 1048576;
    float* super   = ws + (size_t)32 * 1048576;

    unsigned short* xzf_bf = (unsigned short*)region0;
    unsigned short* xzb_bf = xzf_bf + (size_t)MTOT * 2048;
    unsigned short* xcbf2  = (unsigned short*)region1;
    unsigned short* delta2 = (unsigned short*)region2;   // becomes g2
    float* dbc2 = super;                                 // 1M floats [2M][64]
    float* Psum = super + (size_t)1 * 1048576;
    float* Ssum = super + (size_t)5 * 1048576;
    unsigned short* xpwb_f = (unsigned short*)(super + (size_t)9 * 1048576);
    unsigned short* xpwb_b = xpwb_f + 65536;
    // post-scan overlays:
    float* yproj = super;
    float* xs    = super + (size_t)8 * 1048576;
    unsigned short* xsbf = (unsigned short*)region0;
    unsigned short* h1bf = (unsigned short*)(region0 + (size_t)4 * 1048576);
    float* h2    = region1;

    unsigned short* ob     = (unsigned short*)d_out;
    unsigned short* xbf    = ob;
    unsigned short* inwf_b = ob + (size_t)4194304;
    unsigned short* inwb_b = ob + (size_t)5242880;
    unsigned short* outwf_b= ob + (size_t)6291456;
    unsigned short* outwb_b= ob + (size_t)6815744;
    unsigned short* ff1w_b = ob + (size_t)7340032;
    unsigned short* ff2w_b = ob + (size_t)7864320;

    cast_all<<<4160, 256, 0, stream>>>(
        x, xbf,
        (const float*)d_in[0], inwf_b,
        (const float*)d_in[9], inwb_b,
        (const float*)d_in[8], outwf_b,
        (const float*)d_in[17], outwb_b,
        ff1w, ff1w_b,
        ff2w, ff2w_b,
        (const float*)d_in[3], xpwb_f,
        (const float*)d_in[12], xpwb_b);

    inproj_bf16<<<dim3(4096 / 128, MTOT / 128), 256, 0, stream>>>(
        xbf, inwf_b, inwb_b, xzf_bf, xzb_bf);

    conv_silu<<<dim3(MTOT, 2), 256, 0, stream>>>(
        xzf_bf, xzb_bf,
        (const float*)d_in[1], (const float*)d_in[2],
        (const float*)d_in[10], (const float*)d_in[11], xcbf2);

    hipMemsetAsync(dbc2, 0, (size_t)2 * MTOT * 64 * sizeof(float), stream);
    xproj_bf16<<<dim3(2 * MTOT / 128, 4), 256, 0, stream>>>(
        xcbf2, xpwb_f, xpwb_b, dbc2);

    dt_fused<<<dim3(EDIM / 256, 2 * MTOT / 16), 256, 0, stream>>>(
        dbc2, (const float*)d_in[4], (const float*)d_in[5],
        (const float*)d_in[13], (const float*)d_in[14], delta2);

    scan_part1<<<dim3(EDIM / 256, 2 * BATCH, NCH), 256, 0, stream>>>(
        delta2, xcbf2, dbc2,
        (const float*)d_in[6], (const float*)d_in[15], Psum, Ssum);
    scan_combine<<<(2 * BATCH * EDIM * DSTATE) / 256, 256, 0, stream>>>(
        Psum, Ssum);
    scan_part2<<<dim3(EDIM / 256, 2 * BATCH, NCH), 256, 0, stream>>>(
        delta2, xcbf2, dbc2,
        (const float*)d_in[6], (const float*)d_in[15],
        (const float*)d_in[7], (const float*)d_in[16],
        xzf_bf, xzb_bf, Psum);

    gemm_bf16<<<dim3(512 / 128, 2 * MTOT / 128), 256, 0, stream>>>(
        delta2, delta2 + (size_t)MTOT * EDIM, EDIM, outwf_b, outwb_b,
        nullptr, yproj, DMODEL, 0, EDIM, 0);

    ln_combine<<<MTOT, 256, 0, stream>>>(yproj, x, n1g, n1b, n2g, n2b, xs, xsbf);
    gemm_bf16<<<dim3(DFF / 128, MTOT / 128), 256, 0, stream>>>(
        xsbf, xsbf, DMODEL, ff1w_b, ff1w_b, ff1b, h1bf, DFF, 1, DMODEL, 1);
    gemm_bf16<<<dim3(DMODEL / 128, MTOT / 128), 256, 0, stream>>>(
        h1bf, h1bf, DFF, ff2w_b, ff2w_b, ff2b, h2, DMODEL, 0, DFF, 0);
    ln_final<<<MTOT, 256, 0, stream>>>(h2, xs, n3g, n3b, (float*)d_out);
}

// Round 20
// 358.711 us; speedup vs baseline: 1.0602x; 1.0602x over previous
//
#include <hip/hip_runtime.h>
#include <hip/hip_bf16.h>

// Problem constants (fixed by reference)
#define LSEQ   1024
#define BATCH  8
#define MTOT   8192      // B*L
#define DMODEL 512
#define EDIM   1024      // EXPAND*D_MODEL
#define DSTATE 16
#define DTRANK 32
#define DFF    1024
#define EPSLN  1e-5f
#define NCH    16        // scan chunks per direction
#define CHLEN  64        // LSEQ/NCH

typedef __attribute__((ext_vector_type(8))) short bf16x8;
typedef __attribute__((ext_vector_type(4))) float f32x4;

__device__ __forceinline__ unsigned short f2bf(float f) {
    __hip_bfloat16 h = __float2bfloat16(f);   // RNE
    unsigned short u;
    __builtin_memcpy(&u, &h, 2);
    return u;
}
__device__ __forceinline__ float bf2f(unsigned short u) {
    unsigned int x = ((unsigned int)u) << 16;
    float f;
    __builtin_memcpy(&f, &x, 4);
    return f;
}

// fast softplus: HW v_exp + v_log (libm log1pf cost r16's dt 78us)
__device__ __forceinline__ float softplus_fast(float v) {
    float sp = __logf(1.f + __expf(v));
    return v > 80.f ? v : sp;
}

// q^(n+1) for n=0..15, log-depth chain (replaces 16 exps when Aen=-(n+1))
__device__ __forceinline__ void pow16(float q, float* da) {
    da[0] = q;
    da[1] = q * q;
    da[2] = da[1] * q;
    da[3] = da[1] * da[1];
    da[4] = da[3] * da[0];
    da[5] = da[3] * da[1];
    da[6] = da[3] * da[2];
    da[7] = da[3] * da[3];
    da[8]  = da[7] * da[0];
    da[9]  = da[7] * da[1];
    da[10] = da[7] * da[2];
    da[11] = da[7] * da[3];
    da[12] = da[7] * da[4];
    da[13] = da[7] * da[5];
    da[14] = da[7] * da[6];
    da[15] = da[7] * da[7];
}

// async global->LDS, 16B per lane. LDS dest = wave-uniform base + lane*16.
__device__ __forceinline__ void gload16(const unsigned short* g, unsigned short* l) {
    __builtin_amdgcn_global_load_lds(
        (const __attribute__((address_space(1))) void*)g,
        (__attribute__((address_space(3))) void*)l, 16, 0, 0);
}

// ---------------------------------------------------------------------------
// Merged f32->bf16 cast: 9 segments in one dispatch.
// ---------------------------------------------------------------------------
__device__ __forceinline__ void cast8(const float* in, unsigned short* out, int i) {
    float4 f0 = *(const float4*)&in[(size_t)i * 8];
    float4 f1 = *(const float4*)&in[(size_t)i * 8 + 4];
    unsigned short v[8] = {f2bf(f0.x), f2bf(f0.y), f2bf(f0.z), f2bf(f0.w),
                           f2bf(f1.x), f2bf(f1.y), f2bf(f1.z), f2bf(f1.w)};
    *(uint4*)&out[(size_t)i * 8] = *(uint4*)v;
}

__global__ __launch_bounds__(256) void cast_all(
    const float* x,  unsigned short* xb,
    const float* w1, unsigned short* w1b,
    const float* w2, unsigned short* w2b,
    const float* w3, unsigned short* w3b,
    const float* w4, unsigned short* w4b,
    const float* w5, unsigned short* w5b,
    const float* w6, unsigned short* w6b,
    const float* w7, unsigned short* w7b,
    const float* w8, unsigned short* w8b)
{
    const int blk = blockIdx.x;
    const int tid = threadIdx.x;
    if (blk < 2048)        cast8(x,  xb,  blk * 256 + tid);
    else if (blk < 2560)   cast8(w1, w1b, (blk - 2048) * 256 + tid);
    else if (blk < 3072)   cast8(w2, w2b, (blk - 2560) * 256 + tid);
    else if (blk < 3328)   cast8(w3, w3b, (blk - 3072) * 256 + tid);
    else if (blk < 3584)   cast8(w4, w4b, (blk - 3328) * 256 + tid);
    else if (blk < 3840)   cast8(w5, w5b, (blk - 3584) * 256 + tid);
    else if (blk < 4096)   cast8(w6, w6b, (blk - 3840) * 256 + tid);
    else if (blk < 4128)   cast8(w7, w7b, (blk - 4096) * 256 + tid);
    else                   cast8(w8, w8b, (blk - 4128) * 256 + tid);
}

// ---------------------------------------------------------------------------
// Fused dual-direction in-projection (bf16 out, flip-the-write for bwd).
// Direct strided stores (r19's LDS-buffered epilogue cut WRITE_SIZE to the
// 64MB ideal but regressed: +2.9M bank conflicts + 2 barriers on a
// latency-bound kernel; HBM was at 25% so the RMW traffic wasn't critical).
// ---------------------------------------------------------------------------
__global__ __launch_bounds__(256) void inproj_bf16(
    const unsigned short* __restrict__ A,
    const unsigned short* __restrict__ Wf,
    const unsigned short* __restrict__ Wb,
    unsigned short* __restrict__ Cf,
    unsigned short* __restrict__ Cb)
{
    __shared__ unsigned short As[2][128][32];
    __shared__ unsigned short Ws[2][128][32];

    const int K = DMODEL;
    const int tid = threadIdx.x;
    const int rowbase = blockIdx.y * 128;
    const int colg = blockIdx.x * 128;
    const int back = colg >= 2048;
    const unsigned short* W = back ? Wb : Wf;
    const int colbase = colg - (back ? 2048 : 0);
    unsigned short* Cout = back ? Cb : Cf;

    const int wave = tid >> 6, lane = tid & 63;
    const int wm = wave >> 1, wn = wave & 1;
    const int lr = lane & 15;
    const int lc = lane >> 4;

    const int r0 = tid >> 2;
    const int cl = (tid & 3) ^ ((r0 >> 1) & 3);
    const unsigned short* Ag0 = A + (size_t)(rowbase + r0) * K + (cl << 3);
    const unsigned short* Ag1 = A + (size_t)(rowbase + r0 + 64) * K + (cl << 3);
    const unsigned short* Wg0 = W + (size_t)(colbase + r0) * K + (cl << 3);
    const unsigned short* Wg1 = W + (size_t)(colbase + r0 + 64) * K + (cl << 3);

    f32x4 acc[4][4];
#pragma unroll
    for (int i = 0; i < 4; ++i)
#pragma unroll
        for (int j = 0; j < 4; ++j)
            acc[i][j] = (f32x4){0.f, 0.f, 0.f, 0.f};

#define G_STAGE(bi, ko) do {                                   \
        gload16(Ag0 + (ko), &As[bi][wave << 4][0]);            \
        gload16(Ag1 + (ko), &As[bi][64 + (wave << 4)][0]);     \
        gload16(Wg0 + (ko), &Ws[bi][wave << 4][0]);            \
        gload16(Wg1 + (ko), &Ws[bi][64 + (wave << 4)][0]);     \
    } while (0)

#define G_COMPUTE(bi) do {                                     \
        bf16x8 af[4], bfv[4];                                  \
        _Pragma("unroll")                                      \
        for (int i = 0; i < 4; ++i) {                          \
            int R = wm * 64 + i * 16 + lr;                     \
            int pc = lc ^ ((R >> 1) & 3);                      \
            af[i] = *(const bf16x8*)&As[bi][R][pc << 3];       \
        }                                                      \
        _Pragma("unroll")                                      \
        for (int j = 0; j < 4; ++j) {                          \
            int R = wn * 64 + j * 16 + lr;                     \
            int pc = lc ^ ((R >> 1) & 3);                      \
            bfv[j] = *(const bf16x8*)&Ws[bi][R][pc << 3];      \
        }                                                      \
        _Pragma("unroll")                                      \
        for (int i = 0; i < 4; ++i)                            \
            _Pragma("unroll")                                  \
            for (int j = 0; j < 4; ++j)                        \
                acc[i][j] = __builtin_amdgcn_mfma_f32_16x16x32_bf16( \
                    af[i], bfv[j], acc[i][j], 0, 0, 0);        \
    } while (0)

    G_STAGE(0, 0);
    __syncthreads();
    for (int k0 = 0; k0 < K; k0 += 64) {
        G_STAGE(1, k0 + 32);
        __builtin_amdgcn_sched_barrier(0);
        G_COMPUTE(0);
        __syncthreads();
        if (k0 + 64 < K) G_STAGE(0, k0 + 64);
        __builtin_amdgcn_sched_barrier(0);
        G_COMPUTE(1);
        __syncthreads();
    }
#undef G_STAGE
#undef G_COMPUTE

    const int crow0 = rowbase + wm * 64 + ((lane >> 4) << 2);
    const int ccol0 = colbase + wn * 64 + lr;
#pragma unroll
    for (int j = 0; j < 4; ++j) {
        int col = ccol0 + j * 16;
#pragma unroll
        for (int i = 0; i < 4; ++i) {
#pragma unroll
            for (int r = 0; r < 4; ++r) {
                int row = crow0 + i * 16 + r;
                if (back) row = (row & ~(LSEQ - 1)) + (LSEQ - 1 - (row & (LSEQ - 1)));
                Cout[(size_t)row * 2048 + col] = f2bf(acc[i][j][r]);
            }
        }
    }
}

// ---------------------------------------------------------------------------
// bf16 MFMA GEMM v5: rows >= MTOT switch to (A_hi, W_hi) — merged dispatches.
// ---------------------------------------------------------------------------
__global__ __launch_bounds__(256) void gemm_bf16(
    const unsigned short* __restrict__ A,
    const unsigned short* __restrict__ A_hi, int lda,
    const unsigned short* __restrict__ W,
    const unsigned short* __restrict__ W_hi,
    const float* __restrict__ bias,
    void* __restrict__ Cp, int ldc, int c_bf16,
    int K, int act)
{
    __shared__ unsigned short As[2][128][32];
    __shared__ unsigned short Ws[2][128][32];

    const int tid = threadIdx.x;
    const int rowbase = blockIdx.y * 128;
    const int colbase = blockIdx.x * 128;
    const unsigned short* Ause = A;
    const unsigned short* Wuse = W;
    int rlocal = rowbase;
    if (rowbase >= MTOT) { Ause = A_hi; Wuse = W_hi; rlocal = rowbase - MTOT; }

    const int wave = tid >> 6, lane = tid & 63;
    const int wm = wave >> 1, wn = wave & 1;
    const int lr = lane & 15;
    const int lc = lane >> 4;

    const int r0 = tid >> 2;
    const int cl = (tid & 3) ^ ((r0 >> 1) & 3);
    const unsigned short* Ag0 = Ause + (size_t)(rlocal + r0) * lda + (cl << 3);
    const unsigned short* Ag1 = Ause + (size_t)(rlocal + r0 + 64) * lda + (cl << 3);
    const unsigned short* Wg0 = Wuse + (size_t)(colbase + r0) * K + (cl << 3);
    const unsigned short* Wg1 = Wuse + (size_t)(colbase + r0 + 64) * K + (cl << 3);

    f32x4 acc[4][4];
#pragma unroll
    for (int i = 0; i < 4; ++i)
#pragma unroll
        for (int j = 0; j < 4; ++j)
            acc[i][j] = (f32x4){0.f, 0.f, 0.f, 0.f};

#define G_STAGE(bi, ko) do {                                   \
        gload16(Ag0 + (ko), &As[bi][wave << 4][0]);            \
        gload16(Ag1 + (ko), &As[bi][64 + (wave << 4)][0]);     \
        gload16(Wg0 + (ko), &Ws[bi][wave << 4][0]);            \
        gload16(Wg1 + (ko), &Ws[bi][64 + (wave << 4)][0]);     \
    } while (0)

#define G_COMPUTE(bi) do {                                     \
        bf16x8 af[4], bfv[4];                                  \
        _Pragma("unroll")                                      \
        for (int i = 0; i < 4; ++i) {                          \
            int R = wm * 64 + i * 16 + lr;                     \
            int pc = lc ^ ((R >> 1) & 3);                      \
            af[i] = *(const bf16x8*)&As[bi][R][pc << 3];       \
        }                                                      \
        _Pragma("unroll")                                      \
        for (int j = 0; j < 4; ++j) {                          \
            int R = wn * 64 + j * 16 + lr;                     \
            int pc = lc ^ ((R >> 1) & 3);                      \
            bfv[j] = *(const bf16x8*)&Ws[bi][R][pc << 3];      \
        }                                                      \
        _Pragma("unroll")                                      \
        for (int i = 0; i < 4; ++i)                            \
            _Pragma("unroll")                                  \
            for (int j = 0; j < 4; ++j)                        \
                acc[i][j] = __builtin_amdgcn_mfma_f32_16x16x32_bf16( \
                    af[i], bfv[j], acc[i][j], 0, 0, 0);        \
    } while (0)

    G_STAGE(0, 0);
    __syncthreads();
    for (int k0 = 0; k0 < K; k0 += 64) {
        G_STAGE(1, k0 + 32);
        __builtin_amdgcn_sched_barrier(0);
        G_COMPUTE(0);
        __syncthreads();
        if (k0 + 64 < K) G_STAGE(0, k0 + 64);
        __builtin_amdgcn_sched_barrier(0);
        G_COMPUTE(1);
        __syncthreads();
    }
#undef G_STAGE
#undef G_COMPUTE

    const int crow0 = rowbase + wm * 64 + ((lane >> 4) << 2);
    const int ccol0 = colbase + wn * 64 + lr;
#pragma unroll
    for (int j = 0; j < 4; ++j) {
        int col = ccol0 + j * 16;
        float bv = bias ? bias[col] : 0.f;
#pragma unroll
        for (int i = 0; i < 4; ++i) {
#pragma unroll
            for (int r = 0; r < 4; ++r) {
                int row = crow0 + i * 16 + r;
                float v = acc[i][j][r] + bv;
                if (act == 1) v = fmaxf(v, 0.f);
                if (c_bf16)
                    ((unsigned short*)Cp)[(size_t)row * ldc + col] = f2bf(v);
                else
                    ((float*)Cp)[(size_t)row * ldc + col] = v;
            }
        }
    }
}

// ---------------------------------------------------------------------------
// Dual-dir xproj (split-K): dbc2[2M,64] += xcbf2[2M,1024] @ xpw^T
// ---------------------------------------------------------------------------
__global__ __launch_bounds__(256) void xproj_bf16(
    const unsigned short* __restrict__ A,
    const unsigned short* __restrict__ Wf,
    const unsigned short* __restrict__ Wb,
    float* __restrict__ Cp)
{
    __shared__ unsigned short As[2][128][32];
    __shared__ unsigned short Ws[2][64][32];

    const int tid = threadIdx.x;
    const int rowbase = blockIdx.x * 128;
    const int kbase = blockIdx.y * 256;
    const unsigned short* W = (rowbase >= MTOT) ? Wb : Wf;
    const int wave = tid >> 6, lane = tid & 63;
    const int wm = wave >> 1, wn = wave & 1;
    const int lr = lane & 15;
    const int lc = lane >> 4;

    const int r0 = tid >> 2;
    const int cl = (tid & 3) ^ ((r0 >> 1) & 3);
    const unsigned short* Ag0 = A + (size_t)(rowbase + r0) * EDIM + kbase + (cl << 3);
    const unsigned short* Ag1 = A + (size_t)(rowbase + r0 + 64) * EDIM + kbase + (cl << 3);
    const unsigned short* Wg  = W + (size_t)r0 * EDIM + kbase + (cl << 3);

    f32x4 acc[4][2];
#pragma unroll
    for (int i = 0; i < 4; ++i)
#pragma unroll
        for (int j = 0; j < 2; ++j)
            acc[i][j] = (f32x4){0.f, 0.f, 0.f, 0.f};

#define X_STAGE(bi, ko) do {                                   \
        gload16(Ag0 + (ko), &As[bi][wave << 4][0]);            \
        gload16(Ag1 + (ko), &As[bi][64 + (wave << 4)][0]);     \
        gload16(Wg  + (ko), &Ws[bi][wave << 4][0]);            \
    } while (0)

#define X_COMPUTE(bi) do {                                     \
        bf16x8 af[4], bfv[2];                                  \
        _Pragma("unroll")                                      \
        for (int i = 0; i < 4; ++i) {                          \
            int R = wm * 64 + i * 16 + lr;                     \
            int pc = lc ^ ((R >> 1) & 3);                      \
            af[i] = *(const bf16x8*)&As[bi][R][pc << 3];       \
        }                                                      \
        _Pragma("unroll")                                      \
        for (int j = 0; j < 2; ++j) {                          \
            int R = wn * 32 + j * 16 + lr;                     \
            int pc = lc ^ ((R >> 1) & 3);                      \
            bfv[j] = *(const bf16x8*)&Ws[bi][R][pc << 3];      \
        }                                                      \
        _Pragma("unroll")                                      \
        for (int i = 0; i < 4; ++i)                            \
            _Pragma("unroll")                                  \
            for (int j = 0; j < 2; ++j)                        \
                acc[i][j] = __builtin_amdgcn_mfma_f32_16x16x32_bf16( \
                    af[i], bfv[j], acc[i][j], 0, 0, 0);        \
    } while (0)

    X_STAGE(0, 0);
    __syncthreads();
    for (int k0 = 0; k0 < 256; k0 += 64) {
        X_STAGE(1, k0 + 32);
        __builtin_amdgcn_sched_barrier(0);
        X_COMPUTE(0);
        __syncthreads();
        if (k0 + 64 < 256) X_STAGE(0, k0 + 64);
        __builtin_amdgcn_sched_barrier(0);
        X_COMPUTE(1);
        __syncthreads();
    }
#undef X_STAGE
#undef X_COMPUTE

    const int crow0 = rowbase + wm * 64 + ((lane >> 4) << 2);
    const int ccol0 = wn * 32 + lr;
#pragma unroll
    for (int i = 0; i < 4; ++i)
#pragma unroll
        for (int j = 0; j < 2; ++j)
#pragma unroll
            for (int r = 0; r < 4; ++r)
                atomicAdd(&Cp[(size_t)(crow0 + i * 16 + r) * 64 + ccol0 + j * 16],
                          acc[i][j][r]);
}

// ---------------------------------------------------------------------------
// Dual-dir dt: delta2[2M][1024] (bf16), 16 rows/block, fast softplus.
// ---------------------------------------------------------------------------
__global__ __launch_bounds__(256) void dt_fused(
    const float* __restrict__ dbc2,
    const float* __restrict__ dtw_f, const float* __restrict__ dtb_f,
    const float* __restrict__ dtw_b, const float* __restrict__ dtb_b,
    unsigned short* __restrict__ delta2)
{
    __shared__ float sd[16][32];

    const int e  = blockIdx.x * 256 + threadIdx.x;
    const int m0 = blockIdx.y * 16;
    const float* dtw = (m0 >= MTOT) ? dtw_b : dtw_f;
    const float* dtb = (m0 >= MTOT) ? dtb_b : dtb_f;

    float w[32];
#pragma unroll
    for (int k = 0; k < 8; ++k) {
        float4 v = *(const float4*)&dtw[(size_t)e * 32 + k * 4];
        w[k * 4 + 0] = v.x; w[k * 4 + 1] = v.y;
        w[k * 4 + 2] = v.z; w[k * 4 + 3] = v.w;
    }
    const float bv = dtb[e];

    if (threadIdx.x < 128) {
        int r = threadIdx.x >> 3;
        int c = (threadIdx.x & 7) << 2;
        *(float4*)&sd[r][c] = *(const float4*)&dbc2[(size_t)(m0 + r) * 64 + c];
    }
    __syncthreads();

#pragma unroll
    for (int mm = 0; mm < 16; ++mm) {
        float acc = bv;
#pragma unroll
        for (int k = 0; k < 8; ++k) {
            float4 b4 = *(const float4*)&sd[mm][k * 4];
            acc = fmaf(b4.x, w[k * 4 + 0], acc);
            acc = fmaf(b4.y, w[k * 4 + 1], acc);
            acc = fmaf(b4.z, w[k * 4 + 2], acc);
            acc = fmaf(b4.w, w[k * 4 + 3], acc);
        }
        delta2[(size_t)(m0 + mm) * EDIM + e] = f2bf(softplus_fast(acc));
    }
}

// ---------------------------------------------------------------------------
// Dual-dir depthwise causal conv + bias + silu (bf16 in/out).
// ---------------------------------------------------------------------------
__global__ __launch_bounds__(256) void conv_silu(
    const unsigned short* __restrict__ xzf, const unsigned short* __restrict__ xzb_,
    const float* __restrict__ cwf, const float* __restrict__ cbf,
    const float* __restrict__ cwb, const float* __restrict__ cbb,
    unsigned short* __restrict__ xcbf2)
{
    const int dir = blockIdx.y;
    const unsigned short* xzb = dir ? xzb_ : xzf;
    const float* cw = dir ? cwb : cwf;
    const float* cb = dir ? cbb : cbf;
    const int e = threadIdx.x << 2;
    const int m = blockIdx.x;
    const int t = m & (LSEQ - 1);

    float4 w0 = *(const float4*)&cw[e * 4];
    float4 w1 = *(const float4*)&cw[e * 4 + 4];
    float4 w2 = *(const float4*)&cw[e * 4 + 8];
    float4 w3 = *(const float4*)&cw[e * 4 + 12];
    float4 acc = *(const float4*)&cb[e];
#pragma unroll
    for (int k = 0; k < 4; ++k) {
        if (t - 3 + k >= 0) {
            const unsigned short* p = &xzb[(size_t)(m - 3 + k) * 2048 + e];
            uint2 raw = *(const uint2*)p;
            float x0 = bf2f((unsigned short)(raw.x & 0xffff));
            float x1 = bf2f((unsigned short)(raw.x >> 16));
            float x2 = bf2f((unsigned short)(raw.y & 0xffff));
            float x3 = bf2f((unsigned short)(raw.y >> 16));
            acc.x = fmaf((&w0.x)[k], x0, acc.x);
            acc.y = fmaf((&w1.x)[k], x1, acc.y);
            acc.z = fmaf((&w2.x)[k], x2, acc.z);
            acc.w = fmaf((&w3.x)[k], x3, acc.w);
        }
    }
    float4 o;
    o.x = acc.x / (1.f + __expf(-acc.x));
    o.y = acc.y / (1.f + __expf(-acc.y));
    o.z = acc.z / (1.f + __expf(-acc.z));
    o.w = acc.w / (1.f + __expf(-acc.w));
    unsigned short b4[4] = {f2bf(o.x), f2bf(o.y), f2bf(o.z), f2bf(o.w)};
    *(uint2*)&xcbf2[((size_t)dir * MTOT + m) * EDIM + e] = *(uint2*)b4;
}

// ---------------------------------------------------------------------------
// Dual-dir chunked scan with power-chain fast path.
// ---------------------------------------------------------------------------
__global__ __launch_bounds__(256) void scan_part1(
    const unsigned short* __restrict__ delta2,
    const unsigned short* __restrict__ xcbf2,
    const float* __restrict__ dbc2,
    const float* __restrict__ Alog_f, const float* __restrict__ Alog_b,
    float* __restrict__ Psum, float* __restrict__ Ssum)
{
    __shared__ float sB[CHLEN][16];

    const int bd = blockIdx.y;               // 0..15 = dir*8 + b
    const int dir = bd >> 3;
    const int b = bd & 7;
    const int ch = blockIdx.z;
    const int tid = threadIdx.x;
    const int e  = blockIdx.x * 256 + tid;
    const size_t dirOff = (size_t)dir * MTOT;
    const int row0 = b * LSEQ + ch * CHLEN;
    const float* Alog = dir ? Alog_b : Alog_f;

#pragma unroll
    for (int it = 0; it < 4; ++it) {
        int q = tid + it * 256;
        int t = q >> 4, n = q & 15;
        sB[t][n] = dbc2[(dirOff + row0 + t) * 64 + 32 + n];
    }

    float Aen[16];
    bool fastA = true;
#pragma unroll
    for (int k = 0; k < 4; ++k) {
        float4 a4 = *(const float4*)&Alog[e * DSTATE + k * 4];
        Aen[k * 4 + 0] = -__expf(a4.x);
        Aen[k * 4 + 1] = -__expf(a4.y);
        Aen[k * 4 + 2] = -__expf(a4.z);
        Aen[k * 4 + 3] = -__expf(a4.w);
    }
#pragma unroll
    for (int n = 0; n < 16; ++n)
        fastA = fastA && (fabsf(Aen[n] + (float)(n + 1)) <= 1e-3f * (n + 1));

    float h[16];
#pragma unroll
    for (int n = 0; n < 16; ++n) h[n] = 0.f;
    float sumd = 0.f;

    __syncthreads();

    const size_t base = (dirOff + row0) * EDIM + e;
    float dnx = bf2f(delta2[base]);
    float xnx = bf2f(xcbf2[base]);

    for (int t = 0; t < CHLEN; ++t) {
        float d = dnx, xcv = xnx;
        if (t + 1 < CHLEN) {
            dnx = bf2f(delta2[base + (size_t)(t + 1) * EDIM]);
            xnx = bf2f(xcbf2[base + (size_t)(t + 1) * EDIM]);
        }
        sumd += d;
        float dx = d * xcv;
        float Bt[16];
        *(float4*)&Bt[0]  = *(const float4*)&sB[t][0];
        *(float4*)&Bt[4]  = *(const float4*)&sB[t][4];
        *(float4*)&Bt[8]  = *(const float4*)&sB[t][8];
        *(float4*)&Bt[12] = *(const float4*)&sB[t][12];
        float da[16];
        if (fastA) {
            pow16(__expf(-d), da);
        } else {
#pragma unroll
            for (int n = 0; n < 16; ++n) da[n] = __expf(d * Aen[n]);
        }
#pragma unroll
        for (int n = 0; n < 16; ++n)
            h[n] = fmaf(da[n], h[n], dx * Bt[n]);
    }

    size_t idx = ((size_t)(bd * NCH + ch) * EDIM + e) * DSTATE;
    float P[16];
    if (fastA) {
        pow16(__expf(-sumd), P);
    } else {
#pragma unroll
        for (int n = 0; n < 16; ++n) P[n] = __expf(Aen[n] * sumd);
    }
#pragma unroll
    for (int k = 0; k < 4; ++k) {
        *(float4*)&Psum[idx + k * 4] = *(float4*)&P[k * 4];
        *(float4*)&Ssum[idx + k * 4] = *(float4*)&h[k * 4];
    }
}

__global__ __launch_bounds__(256) void scan_combine(
    float* __restrict__ Psum, const float* __restrict__ Ssum)
{
    int i = blockIdx.x * 256 + threadIdx.x;
    int bd = i >> 14;
    int r = i & 16383;
    float H = 0.f;
#pragma unroll
    for (int ch = 0; ch < NCH; ++ch) {
        size_t idx = ((size_t)(bd * NCH + ch) << 14) + r;
        float p = Psum[idx];
        float s = Ssum[idx];
        Psum[idx] = H;
        H = fmaf(p, H, s);
    }
}

__global__ __launch_bounds__(256) void scan_part2(
    unsigned short* __restrict__ delta2,          // in: delta, out: g (in-place)
    const unsigned short* __restrict__ xcbf2,
    const float* __restrict__ dbc2,
    const float* __restrict__ Alog_f, const float* __restrict__ Alog_b,
    const float* __restrict__ Dvec_f, const float* __restrict__ Dvec_b,
    const unsigned short* __restrict__ xzf, const unsigned short* __restrict__ xzb_,
    const float* __restrict__ Hstart)
{
    __shared__ float sB[CHLEN][16], sC[CHLEN][16];

    const int bd = blockIdx.y;
    const int dir = bd >> 3;
    const int b = bd & 7;
    const int ch = blockIdx.z;
    const int tid = threadIdx.x;
    const int e  = blockIdx.x * 256 + tid;
    const size_t dirOff = (size_t)dir * MTOT;
    const int row0 = b * LSEQ + ch * CHLEN;
    const float* Alog = dir ? Alog_b : Alog_f;
    const float* Dvec = dir ? Dvec_b : Dvec_f;
    const unsigned short* zb = dir ? xzb_ : xzf;

#pragma unroll
    for (int it = 0; it < 8; ++it) {
        int q = tid + it * 256;
        int t = q >> 5, c = q & 31;
        float v = dbc2[(dirOff + row0 + t) * 64 + 32 + c];
        if (c < 16) sB[t][c] = v; else sC[t][c - 16] = v;
    }

    float Aen[16];
    bool fastA = true;
#pragma unroll
    for (int k = 0; k < 4; ++k) {
        float4 a4 = *(const float4*)&Alog[e * DSTATE + k * 4];
        Aen[k * 4 + 0] = -__expf(a4.x);
        Aen[k * 4 + 1] = -__expf(a4.y);
        Aen[k * 4 + 2] = -__expf(a4.z);
        Aen[k * 4 + 3] = -__expf(a4.w);
    }
#pragma unroll
    for (int n = 0; n < 16; ++n)
        fastA = fastA && (fabsf(Aen[n] + (float)(n + 1)) <= 1e-3f * (n + 1));
    const float Dv = Dvec[e];

    float h[16];
    {
        size_t idx = ((size_t)(bd * NCH + ch) * EDIM + e) * DSTATE;
#pragma unroll
        for (int k = 0; k < 4; ++k)
            *(float4*)&h[k * 4] = *(const float4*)&Hstart[idx + k * 4];
    }

    __syncthreads();

    const size_t base = (dirOff + row0) * EDIM + e;
    const size_t zbase = (size_t)row0 * 2048 + 1024 + e;
    float dnx = bf2f(delta2[base]);
    float xnx = bf2f(xcbf2[base]);
    float znx = bf2f(zb[zbase]);

    for (int t = 0; t < CHLEN; ++t) {
        float d = dnx, xcv = xnx, zv = znx;
        if (t + 1 < CHLEN) {
            dnx = bf2f(delta2[base + (size_t)(t + 1) * EDIM]);
            xnx = bf2f(xcbf2[base + (size_t)(t + 1) * EDIM]);
            znx = bf2f(zb[zbase + (size_t)(t + 1) * 2048]);
        }
        float dx = d * xcv;
        float Bt[16], Ct[16];
        *(float4*)&Bt[0]  = *(const float4*)&sB[t][0];
        *(float4*)&Bt[4]  = *(const float4*)&sB[t][4];
        *(float4*)&Bt[8]  = *(const float4*)&sB[t][8];
        *(float4*)&Bt[12] = *(const float4*)&sB[t][12];
        *(float4*)&Ct[0]  = *(const float4*)&sC[t][0];
        *(float4*)&Ct[4]  = *(const float4*)&sC[t][4];
        *(float4*)&Ct[8]  = *(const float4*)&sC[t][8];
        *(float4*)&Ct[12] = *(const float4*)&sC[t][12];
        float da[16];
        if (fastA) {
            pow16(__expf(-d), da);
        } else {
#pragma unroll
            for (int n = 0; n < 16; ++n) da[n] = __expf(d * Aen[n]);
        }
        float y = 0.f;
#pragma unroll
        for (int n = 0; n < 16; ++n) {
            h[n] = fmaf(da[n], h[n], dx * Bt[n]);
            y = fmaf(h[n], Ct[n], y);
        }
        y = fmaf(Dv, xcv, y);
        float sig = 1.f / (1.f + __expf(-zv));
        float zz  = zv * sig;
        delta2[base + (size_t)t * EDIM] = f2bf(fmaf(zz, y - xcv, xcv));
    }
}

// ---------------------------------------------------------------------------
__device__ __forceinline__ void block_reduce4(float4& s, float4* red, int tid)
{
#pragma unroll
    for (int off = 1; off < 64; off <<= 1) {
        s.x += __shfl_xor(s.x, off);
        s.y += __shfl_xor(s.y, off);
        s.z += __shfl_xor(s.z, off);
        s.w += __shfl_xor(s.w, off);
    }
    if ((tid & 63) == 0) red[tid >> 6] = s;
    __syncthreads();
    float4 a = red[0], b = red[1], c = red[2], d = red[3];
    s.x = a.x + b.x + c.x + d.x;
    s.y = a.y + b.y + c.y + d.y;
    s.z = a.z + b.z + c.z + d.z;
    s.w = a.w + b.w + c.w + d.w;
}

__global__ __launch_bounds__(256) void ln_combine(
    const float* __restrict__ yproj, const float* __restrict__ x,
    const float* __restrict__ g1, const float* __restrict__ b1,
    const float* __restrict__ g2, const float* __restrict__ b2,
    float* __restrict__ xs, unsigned short* __restrict__ xsbf)
{
    __shared__ float4 red[4];
    const int row = blockIdx.x, tid = threadIdx.x;
    const float* yf = yproj + (size_t)row * DMODEL;
    const float* yb = yproj + (size_t)(MTOT + row) * DMODEL;
    const float* xr = x + (size_t)row * DMODEL;

    float vf[2], vb[2];
#pragma unroll
    for (int j = 0; j < 2; ++j) {
        int i = tid + j * 256;
        float xi = xr[i];
        vf[j] = yf[i] + xi;
        vb[j] = yb[i] + xi;
    }
    float4 s = make_float4(vf[0] + vf[1], vf[0] * vf[0] + vf[1] * vf[1],
                           vb[0] + vb[1], vb[0] * vb[0] + vb[1] * vb[1]);
    block_reduce4(s, red, tid);
    const float inv = 1.f / DMODEL;
    float mf = s.x * inv, mb = s.z * inv;
    float rf = rsqrtf(s.y * inv - mf * mf + EPSLN);
    float rb = rsqrtf(s.w * inv - mb * mb + EPSLN);
#pragma unroll
    for (int j = 0; j < 2; ++j) {
        int i = tid + j * 256;
        float a  = (vf[j] - mf) * rf * g1[i] + b1[i];
        float bb = (vb[j] - mb) * rb * g2[i] + b2[i];
        float v = a + bb;
        xs[(size_t)row * DMODEL + i] = v;
        xsbf[(size_t)row * DMODEL + i] = f2bf(v);
    }
}

__global__ __launch_bounds__(256) void ln_final(
    const float* __restrict__ h2, const float* __restrict__ xs,
    const float* __restrict__ g3, const float* __restrict__ b3,
    float* __restrict__ out)
{
    __shared__ float4 red[4];
    const int row = blockIdx.x, tid = threadIdx.x;
    float v[2];
#pragma unroll
    for (int j = 0; j < 2; ++j) {
        int i = tid + j * 256;
        v[j] = h2[(size_t)row * DMODEL + i] + xs[(size_t)row * DMODEL + i];
    }
    float4 s = make_float4(v[0] + v[1], v[0] * v[0] + v[1] * v[1], 0.f, 0.f);
    block_reduce4(s, red, tid);
    const float inv = 1.f / DMODEL;
    float m  = s.x * inv;
    float rs = rsqrtf(s.y * inv - m * m + EPSLN);
#pragma unroll
    for (int j = 0; j < 2; ++j) {
        int i = tid + j * 256;
        out[(size_t)row * DMODEL + i] = (v[j] - m) * rs * g3[i] + b3[i];
    }
}

// ---------------------------------------------------------------------------
extern "C" void kernel_launch(void* const* d_in, const int* in_sizes, int n_in,
                              void* d_out, int out_size, void* d_ws, size_t ws_size,
                              hipStream_t stream)
{
    (void)in_sizes; (void)n_in;

    const float* x    = (const float*)d_in[28];
    const float* n1g  = (const float*)d_in[18];
    const float* n1b  = (const float*)d_in[19];
    const float* n2g  = (const float*)d_in[20];
    const float* n2b  = (const float*)d_in[21];
    const float* n3g  = (const float*)d_in[22];
    const float* n3b  = (const float*)d_in[23];
    const float* ff1w = (const float*)d_in[24];
    const float* ff1b = (const float*)d_in[25];
    const float* ff2w = (const float*)d_in[26];
    const float* ff2b = (const float*)d_in[27];

    const size_t need_floats =
        (size_t)MTOT * 2048 + (size_t)MTOT * 1024 + (size_t)MTOT * 1024 +
        (size_t)MTOT * 64 + (size_t)2 * MTOT * 512 + (size_t)MTOT * 512;
    if (ws_size < need_floats * sizeof(float)) return;
    if (out_size < MTOT * DMODEL) return;

    float* ws = (float*)d_ws;
    float* region0 = ws;
    float* region1 = ws + (size_t)16 * 1048576;
    float* region2 = ws + (size_t)24 * 1048576;
    float* super   = ws + (size_t)32 * 1048576;

    unsigned short* xzf_bf = (unsigned short*)region0;
    unsigned short* xzb_bf = xzf_bf + (size_t)MTOT * 2048;
    unsigned short* xcbf2  = (unsigned short*)region1;
    unsigned short* delta2 = (unsigned short*)region2;   // becomes g2
    float* dbc2 = super;                                 // 1M floats [2M][64]
    float* Psum = super + (size_t)1 * 1048576;
    float* Ssum = super + (size_t)5 * 1048576;
    unsigned short* xpwb_f = (unsigned short*)(super + (size_t)9 * 1048576);
    unsigned short* xpwb_b = xpwb_f + 65536;
    // post-scan overlays:
    float* yproj = super;
    float* xs    = super + (size_t)8 * 1048576;
    unsigned short* xsbf = (unsigned short*)region0;
    unsigned short* h1bf = (unsigned short*)(region0 + (size_t)4 * 1048576);
    float* h2    = region1;

    unsigned short* ob     = (unsigned short*)d_out;
    unsigned short* xbf    = ob;
    unsigned short* inwf_b = ob + (size_t)4194304;
    unsigned short* inwb_b = ob + (size_t)5242880;
    unsigned short* outwf_b= ob + (size_t)6291456;
    unsigned short* outwb_b= ob + (size_t)6815744;
    unsigned short* ff1w_b = ob + (size_t)7340032;
    unsigned short* ff2w_b = ob + (size_t)7864320;

    cast_all<<<4160, 256, 0, stream>>>(
        x, xbf,
        (const float*)d_in[0], inwf_b,
        (const float*)d_in[9], inwb_b,
        (const float*)d_in[8], outwf_b,
        (const float*)d_in[17], outwb_b,
        ff1w, ff1w_b,
        ff2w, ff2w_b,
        (const float*)d_in[3], xpwb_f,
        (const float*)d_in[12], xpwb_b);

    inproj_bf16<<<dim3(4096 / 128, MTOT / 128), 256, 0, stream>>>(
        xbf, inwf_b, inwb_b, xzf_bf, xzb_bf);

    conv_silu<<<dim3(MTOT, 2), 256, 0, stream>>>(
        xzf_bf, xzb_bf,
        (const float*)d_in[1], (const float*)d_in[2],
        (const float*)d_in[10], (const float*)d_in[11], xcbf2);

    hipMemsetAsync(dbc2, 0, (size_t)2 * MTOT * 64 * sizeof(float), stream);
    xproj_bf16<<<dim3(2 * MTOT / 128, 4), 256, 0, stream>>>(
        xcbf2, xpwb_f, xpwb_b, dbc2);

    dt_fused<<<dim3(EDIM / 256, 2 * MTOT / 16), 256, 0, stream>>>(
        dbc2, (const float*)d_in[4], (const float*)d_in[5],
        (const float*)d_in[13], (const float*)d_in[14], delta2);

    scan_part1<<<dim3(EDIM / 256, 2 * BATCH, NCH), 256, 0, stream>>>(
        delta2, xcbf2, dbc2,
        (const float*)d_in[6], (const float*)d_in[15], Psum, Ssum);
    scan_combine<<<(2 * BATCH * EDIM * DSTATE) / 256, 256, 0, stream>>>(
        Psum, Ssum);
    scan_part2<<<dim3(EDIM / 256, 2 * BATCH, NCH), 256, 0, stream>>>(
        delta2, xcbf2, dbc2,
        (const float*)d_in[6], (const float*)d_in[15],
        (const float*)d_in[7], (const float*)d_in[16],
        xzf_bf, xzb_bf, Psum);

    gemm_bf16<<<dim3(512 / 128, 2 * MTOT / 128), 256, 0, stream>>>(
        delta2, delta2 + (size_t)MTOT * EDIM, EDIM, outwf_b, outwb_b,
        nullptr, yproj, DMODEL, 0, EDIM, 0);

    ln_combine<<<MTOT, 256, 0, stream>>>(yproj, x, n1g, n1b, n2g, n2b, xs, xsbf);
    gemm_bf16<<<dim3(DFF / 128, MTOT / 128), 256, 0, stream>>>(
        xsbf, xsbf, DMODEL, ff1w_b, ff1w_b, ff1b, h1bf, DFF, 1, DMODEL, 1);
    gemm_bf16<<<dim3(DMODEL / 128, MTOT / 128), 256, 0, stream>>>(
        h1bf, h1bf, DFF, ff2w_b, ff2w_b, ff2b, h2, DMODEL, 0, DFF, 0);
    ln_final<<<MTOT, 256, 0, stream>>>(h2, xs, n3g, n3b, (float*)d_out);
}

// Round 21
// 322.659 us; speedup vs baseline: 1.1787x; 1.1117x over previous
//
#include <hip/hip_runtime.h>
#include <hip/hip_bf16.h>

// Problem constants (fixed by reference)
#define LSEQ   1024
#define BATCH  8
#define MTOT   8192      // B*L
#define DMODEL 512
#define EDIM   1024      // EXPAND*D_MODEL
#define DSTATE 16
#define DTRANK 32
#define DFF    1024
#define EPSLN  1e-5f
#define NCH    16        // scan chunks per direction
#define CHLEN  64        // LSEQ/NCH

typedef __attribute__((ext_vector_type(8))) short bf16x8;
typedef __attribute__((ext_vector_type(4))) float f32x4;

__device__ __forceinline__ unsigned short f2bf(float f) {
    __hip_bfloat16 h = __float2bfloat16(f);   // RNE
    unsigned short u;
    __builtin_memcpy(&u, &h, 2);
    return u;
}
__device__ __forceinline__ float bf2f(unsigned short u) {
    unsigned int x = ((unsigned int)u) << 16;
    float f;
    __builtin_memcpy(&f, &x, 4);
    return f;
}

// fast softplus: HW v_exp + v_log (libm log1pf cost r16's dt 78us)
__device__ __forceinline__ float softplus_fast(float v) {
    float sp = __logf(1.f + __expf(v));
    return v > 80.f ? v : sp;
}

// q^(n+1) for n=0..15, log-depth chain (replaces 16 exps when Aen=-(n+1))
__device__ __forceinline__ void pow16(float q, float* da) {
    da[0] = q;
    da[1] = q * q;
    da[2] = da[1] * q;
    da[3] = da[1] * da[1];
    da[4] = da[3] * da[0];
    da[5] = da[3] * da[1];
    da[6] = da[3] * da[2];
    da[7] = da[3] * da[3];
    da[8]  = da[7] * da[0];
    da[9]  = da[7] * da[1];
    da[10] = da[7] * da[2];
    da[11] = da[7] * da[3];
    da[12] = da[7] * da[4];
    da[13] = da[7] * da[5];
    da[14] = da[7] * da[6];
    da[15] = da[7] * da[7];
}

// async global->LDS, 16B per lane. LDS dest = wave-uniform base + lane*16.
__device__ __forceinline__ void gload16(const unsigned short* g, unsigned short* l) {
    __builtin_amdgcn_global_load_lds(
        (const __attribute__((address_space(1))) void*)g,
        (__attribute__((address_space(3))) void*)l, 16, 0, 0);
}

// ---------------------------------------------------------------------------
// Merged f32->bf16 cast: 9 segments in one dispatch.
// ---------------------------------------------------------------------------
__device__ __forceinline__ void cast8(const float* in, unsigned short* out, int i) {
    float4 f0 = *(const float4*)&in[(size_t)i * 8];
    float4 f1 = *(const float4*)&in[(size_t)i * 8 + 4];
    unsigned short v[8] = {f2bf(f0.x), f2bf(f0.y), f2bf(f0.z), f2bf(f0.w),
                           f2bf(f1.x), f2bf(f1.y), f2bf(f1.z), f2bf(f1.w)};
    *(uint4*)&out[(size_t)i * 8] = *(uint4*)v;
}

__global__ __launch_bounds__(256) void cast_all(
    const float* x,  unsigned short* xb,
    const float* w1, unsigned short* w1b,
    const float* w2, unsigned short* w2b,
    const float* w3, unsigned short* w3b,
    const float* w4, unsigned short* w4b,
    const float* w5, unsigned short* w5b,
    const float* w6, unsigned short* w6b,
    const float* w7, unsigned short* w7b,
    const float* w8, unsigned short* w8b)
{
    const int blk = blockIdx.x;
    const int tid = threadIdx.x;
    if (blk < 2048)        cast8(x,  xb,  blk * 256 + tid);
    else if (blk < 2560)   cast8(w1, w1b, (blk - 2048) * 256 + tid);
    else if (blk < 3072)   cast8(w2, w2b, (blk - 2560) * 256 + tid);
    else if (blk < 3328)   cast8(w3, w3b, (blk - 3072) * 256 + tid);
    else if (blk < 3584)   cast8(w4, w4b, (blk - 3328) * 256 + tid);
    else if (blk < 3840)   cast8(w5, w5b, (blk - 3584) * 256 + tid);
    else if (blk < 4096)   cast8(w6, w6b, (blk - 3840) * 256 + tid);
    else if (blk < 4128)   cast8(w7, w7b, (blk - 4096) * 256 + tid);
    else                   cast8(w8, w8b, (blk - 4128) * 256 + tid);
}

// ---------------------------------------------------------------------------
// Fused dual-direction in-projection. r21: xi and z written to SEPARATE dense
// buffers [M][1024] per dir (each 128-col tile falls wholly in xi or z since
// colbase is 128-aligned) — conv/scan reads become dense DRAM pages (r20
// profile: conv at 21% HBM from half-density xi|z interleaved rows).
// ---------------------------------------------------------------------------
__global__ __launch_bounds__(256) void inproj_bf16(
    const unsigned short* __restrict__ A,
    const unsigned short* __restrict__ Wf,
    const unsigned short* __restrict__ Wb,
    unsigned short* __restrict__ xi_f, unsigned short* __restrict__ z_f,
    unsigned short* __restrict__ xi_b, unsigned short* __restrict__ z_b)
{
    __shared__ unsigned short As[2][128][32];
    __shared__ unsigned short Ws[2][128][32];

    const int K = DMODEL;
    const int tid = threadIdx.x;
    const int rowbase = blockIdx.y * 128;
    const int colg = blockIdx.x * 128;
    const int back = colg >= 2048;
    const unsigned short* W = back ? Wb : Wf;
    const int colbase = colg - (back ? 2048 : 0);
    const int is_z = colbase >= 1024;
    unsigned short* Cout = back ? (is_z ? z_b : xi_b) : (is_z ? z_f : xi_f);
    const int cofs = is_z ? 1024 : 0;

    const int wave = tid >> 6, lane = tid & 63;
    const int wm = wave >> 1, wn = wave & 1;
    const int lr = lane & 15;
    const int lc = lane >> 4;

    const int r0 = tid >> 2;
    const int cl = (tid & 3) ^ ((r0 >> 1) & 3);
    const unsigned short* Ag0 = A + (size_t)(rowbase + r0) * K + (cl << 3);
    const unsigned short* Ag1 = A + (size_t)(rowbase + r0 + 64) * K + (cl << 3);
    const unsigned short* Wg0 = W + (size_t)(colbase + r0) * K + (cl << 3);
    const unsigned short* Wg1 = W + (size_t)(colbase + r0 + 64) * K + (cl << 3);

    f32x4 acc[4][4];
#pragma unroll
    for (int i = 0; i < 4; ++i)
#pragma unroll
        for (int j = 0; j < 4; ++j)
            acc[i][j] = (f32x4){0.f, 0.f, 0.f, 0.f};

#define G_STAGE(bi, ko) do {                                   \
        gload16(Ag0 + (ko), &As[bi][wave << 4][0]);            \
        gload16(Ag1 + (ko), &As[bi][64 + (wave << 4)][0]);     \
        gload16(Wg0 + (ko), &Ws[bi][wave << 4][0]);            \
        gload16(Wg1 + (ko), &Ws[bi][64 + (wave << 4)][0]);     \
    } while (0)

#define G_COMPUTE(bi) do {                                     \
        bf16x8 af[4], bfv[4];                                  \
        _Pragma("unroll")                                      \
        for (int i = 0; i < 4; ++i) {                          \
            int R = wm * 64 + i * 16 + lr;                     \
            int pc = lc ^ ((R >> 1) & 3);                      \
            af[i] = *(const bf16x8*)&As[bi][R][pc << 3];       \
        }                                                      \
        _Pragma("unroll")                                      \
        for (int j = 0; j < 4; ++j) {                          \
            int R = wn * 64 + j * 16 + lr;                     \
            int pc = lc ^ ((R >> 1) & 3);                      \
            bfv[j] = *(const bf16x8*)&Ws[bi][R][pc << 3];      \
        }                                                      \
        _Pragma("unroll")                                      \
        for (int i = 0; i < 4; ++i)                            \
            _Pragma("unroll")                                  \
            for (int j = 0; j < 4; ++j)                        \
                acc[i][j] = __builtin_amdgcn_mfma_f32_16x16x32_bf16( \
                    af[i], bfv[j], acc[i][j], 0, 0, 0);        \
    } while (0)

    G_STAGE(0, 0);
    __syncthreads();
    for (int k0 = 0; k0 < K; k0 += 64) {
        G_STAGE(1, k0 + 32);
        __builtin_amdgcn_sched_barrier(0);
        G_COMPUTE(0);
        __syncthreads();
        if (k0 + 64 < K) G_STAGE(0, k0 + 64);
        __builtin_amdgcn_sched_barrier(0);
        G_COMPUTE(1);
        __syncthreads();
    }
#undef G_STAGE
#undef G_COMPUTE

    const int crow0 = rowbase + wm * 64 + ((lane >> 4) << 2);
    const int ccol0 = colbase + wn * 64 + lr;
#pragma unroll
    for (int j = 0; j < 4; ++j) {
        int col = ccol0 + j * 16 - cofs;          // 0..1023 within buffer
#pragma unroll
        for (int i = 0; i < 4; ++i) {
#pragma unroll
            for (int r = 0; r < 4; ++r) {
                int row = crow0 + i * 16 + r;
                if (back) row = (row & ~(LSEQ - 1)) + (LSEQ - 1 - (row & (LSEQ - 1)));
                Cout[(size_t)row * 1024 + col] = f2bf(acc[i][j][r]);
            }
        }
    }
}

// ---------------------------------------------------------------------------
// bf16 MFMA GEMM v5: rows >= MTOT switch to (A_hi, W_hi) — merged dispatches.
// ---------------------------------------------------------------------------
__global__ __launch_bounds__(256) void gemm_bf16(
    const unsigned short* __restrict__ A,
    const unsigned short* __restrict__ A_hi, int lda,
    const unsigned short* __restrict__ W,
    const unsigned short* __restrict__ W_hi,
    const float* __restrict__ bias,
    void* __restrict__ Cp, int ldc, int c_bf16,
    int K, int act)
{
    __shared__ unsigned short As[2][128][32];
    __shared__ unsigned short Ws[2][128][32];

    const int tid = threadIdx.x;
    const int rowbase = blockIdx.y * 128;
    const int colbase = blockIdx.x * 128;
    const unsigned short* Ause = A;
    const unsigned short* Wuse = W;
    int rlocal = rowbase;
    if (rowbase >= MTOT) { Ause = A_hi; Wuse = W_hi; rlocal = rowbase - MTOT; }

    const int wave = tid >> 6, lane = tid & 63;
    const int wm = wave >> 1, wn = wave & 1;
    const int lr = lane & 15;
    const int lc = lane >> 4;

    const int r0 = tid >> 2;
    const int cl = (tid & 3) ^ ((r0 >> 1) & 3);
    const unsigned short* Ag0 = Ause + (size_t)(rlocal + r0) * lda + (cl << 3);
    const unsigned short* Ag1 = Ause + (size_t)(rlocal + r0 + 64) * lda + (cl << 3);
    const unsigned short* Wg0 = Wuse + (size_t)(colbase + r0) * K + (cl << 3);
    const unsigned short* Wg1 = Wuse + (size_t)(colbase + r0 + 64) * K + (cl << 3);

    f32x4 acc[4][4];
#pragma unroll
    for (int i = 0; i < 4; ++i)
#pragma unroll
        for (int j = 0; j < 4; ++j)
            acc[i][j] = (f32x4){0.f, 0.f, 0.f, 0.f};

#define G_STAGE(bi, ko) do {                                   \
        gload16(Ag0 + (ko), &As[bi][wave << 4][0]);            \
        gload16(Ag1 + (ko), &As[bi][64 + (wave << 4)][0]);     \
        gload16(Wg0 + (ko), &Ws[bi][wave << 4][0]);            \
        gload16(Wg1 + (ko), &Ws[bi][64 + (wave << 4)][0]);     \
    } while (0)

#define G_COMPUTE(bi) do {                                     \
        bf16x8 af[4], bfv[4];                                  \
        _Pragma("unroll")                                      \
        for (int i = 0; i < 4; ++i) {                          \
            int R = wm * 64 + i * 16 + lr;                     \
            int pc = lc ^ ((R >> 1) & 3);                      \
            af[i] = *(const bf16x8*)&As[bi][R][pc << 3];       \
        }                                                      \
        _Pragma("unroll")                                      \
        for (int j = 0; j < 4; ++j) {                          \
            int R = wn * 64 + j * 16 + lr;                     \
            int pc = lc ^ ((R >> 1) & 3);                      \
            bfv[j] = *(const bf16x8*)&Ws[bi][R][pc << 3];      \
        }                                                      \
        _Pragma("unroll")                                      \
        for (int i = 0; i < 4; ++i)                            \
            _Pragma("unroll")                                  \
            for (int j = 0; j < 4; ++j)                        \
                acc[i][j] = __builtin_amdgcn_mfma_f32_16x16x32_bf16( \
                    af[i], bfv[j], acc[i][j], 0, 0, 0);        \
    } while (0)

    G_STAGE(0, 0);
    __syncthreads();
    for (int k0 = 0; k0 < K; k0 += 64) {
        G_STAGE(1, k0 + 32);
        __builtin_amdgcn_sched_barrier(0);
        G_COMPUTE(0);
        __syncthreads();
        if (k0 + 64 < K) G_STAGE(0, k0 + 64);
        __builtin_amdgcn_sched_barrier(0);
        G_COMPUTE(1);
        __syncthreads();
    }
#undef G_STAGE
#undef G_COMPUTE

    const int crow0 = rowbase + wm * 64 + ((lane >> 4) << 2);
    const int ccol0 = colbase + wn * 64 + lr;
#pragma unroll
    for (int j = 0; j < 4; ++j) {
        int col = ccol0 + j * 16;
        float bv = bias ? bias[col] : 0.f;
#pragma unroll
        for (int i = 0; i < 4; ++i) {
#pragma unroll
            for (int r = 0; r < 4; ++r) {
                int row = crow0 + i * 16 + r;
                float v = acc[i][j][r] + bv;
                if (act == 1) v = fmaxf(v, 0.f);
                if (c_bf16)
                    ((unsigned short*)Cp)[(size_t)row * ldc + col] = f2bf(v);
                else
                    ((float*)Cp)[(size_t)row * ldc + col] = v;
            }
        }
    }
}

// ---------------------------------------------------------------------------
// Dual-dir xproj (split-K): dbc2[2M,64] += xcbf2[2M,1024] @ xpw^T
// ---------------------------------------------------------------------------
__global__ __launch_bounds__(256) void xproj_bf16(
    const unsigned short* __restrict__ A,
    const unsigned short* __restrict__ Wf,
    const unsigned short* __restrict__ Wb,
    float* __restrict__ Cp)
{
    __shared__ unsigned short As[2][128][32];
    __shared__ unsigned short Ws[2][64][32];

    const int tid = threadIdx.x;
    const int rowbase = blockIdx.x * 128;
    const int kbase = blockIdx.y * 256;
    const unsigned short* W = (rowbase >= MTOT) ? Wb : Wf;
    const int wave = tid >> 6, lane = tid & 63;
    const int wm = wave >> 1, wn = wave & 1;
    const int lr = lane & 15;
    const int lc = lane >> 4;

    const int r0 = tid >> 2;
    const int cl = (tid & 3) ^ ((r0 >> 1) & 3);
    const unsigned short* Ag0 = A + (size_t)(rowbase + r0) * EDIM + kbase + (cl << 3);
    const unsigned short* Ag1 = A + (size_t)(rowbase + r0 + 64) * EDIM + kbase + (cl << 3);
    const unsigned short* Wg  = W + (size_t)r0 * EDIM + kbase + (cl << 3);

    f32x4 acc[4][2];
#pragma unroll
    for (int i = 0; i < 4; ++i)
#pragma unroll
        for (int j = 0; j < 2; ++j)
            acc[i][j] = (f32x4){0.f, 0.f, 0.f, 0.f};

#define X_STAGE(bi, ko) do {                                   \
        gload16(Ag0 + (ko), &As[bi][wave << 4][0]);            \
        gload16(Ag1 + (ko), &As[bi][64 + (wave << 4)][0]);     \
        gload16(Wg  + (ko), &Ws[bi][wave << 4][0]);            \
    } while (0)

#define X_COMPUTE(bi) do {                                     \
        bf16x8 af[4], bfv[2];                                  \
        _Pragma("unroll")                                      \
        for (int i = 0; i < 4; ++i) {                          \
            int R = wm * 64 + i * 16 + lr;                     \
            int pc = lc ^ ((R >> 1) & 3);                      \
            af[i] = *(const bf16x8*)&As[bi][R][pc << 3];       \
        }                                                      \
        _Pragma("unroll")                                      \
        for (int j = 0; j < 2; ++j) {                          \
            int R = wn * 32 + j * 16 + lr;                     \
            int pc = lc ^ ((R >> 1) & 3);                      \
            bfv[j] = *(const bf16x8*)&Ws[bi][R][pc << 3];      \
        }                                                      \
        _Pragma("unroll")                                      \
        for (int i = 0; i < 4; ++i)                            \
            _Pragma("unroll")                                  \
            for (int j = 0; j < 2; ++j)                        \
                acc[i][j] = __builtin_amdgcn_mfma_f32_16x16x32_bf16( \
                    af[i], bfv[j], acc[i][j], 0, 0, 0);        \
    } while (0)

    X_STAGE(0, 0);
    __syncthreads();
    for (int k0 = 0; k0 < 256; k0 += 64) {
        X_STAGE(1, k0 + 32);
        __builtin_amdgcn_sched_barrier(0);
        X_COMPUTE(0);
        __syncthreads();
        if (k0 + 64 < 256) X_STAGE(0, k0 + 64);
        __builtin_amdgcn_sched_barrier(0);
        X_COMPUTE(1);
        __syncthreads();
    }
#undef X_STAGE
#undef X_COMPUTE

    const int crow0 = rowbase + wm * 64 + ((lane >> 4) << 2);
    const int ccol0 = wn * 32 + lr;
#pragma unroll
    for (int i = 0; i < 4; ++i)
#pragma unroll
        for (int j = 0; j < 2; ++j)
#pragma unroll
            for (int r = 0; r < 4; ++r)
                atomicAdd(&Cp[(size_t)(crow0 + i * 16 + r) * 64 + ccol0 + j * 16],
                          acc[i][j][r]);
}

// ---------------------------------------------------------------------------
// Dual-dir dt: delta2[2M][1024] (bf16), 16 rows/block, fast softplus.
// ---------------------------------------------------------------------------
__global__ __launch_bounds__(256) void dt_fused(
    const float* __restrict__ dbc2,
    const float* __restrict__ dtw_f, const float* __restrict__ dtb_f,
    const float* __restrict__ dtw_b, const float* __restrict__ dtb_b,
    unsigned short* __restrict__ delta2)
{
    __shared__ float sd[16][32];

    const int e  = blockIdx.x * 256 + threadIdx.x;
    const int m0 = blockIdx.y * 16;
    const float* dtw = (m0 >= MTOT) ? dtw_b : dtw_f;
    const float* dtb = (m0 >= MTOT) ? dtb_b : dtb_f;

    float w[32];
#pragma unroll
    for (int k = 0; k < 8; ++k) {
        float4 v = *(const float4*)&dtw[(size_t)e * 32 + k * 4];
        w[k * 4 + 0] = v.x; w[k * 4 + 1] = v.y;
        w[k * 4 + 2] = v.z; w[k * 4 + 3] = v.w;
    }
    const float bv = dtb[e];

    if (threadIdx.x < 128) {
        int r = threadIdx.x >> 3;
        int c = (threadIdx.x & 7) << 2;
        *(float4*)&sd[r][c] = *(const float4*)&dbc2[(size_t)(m0 + r) * 64 + c];
    }
    __syncthreads();

#pragma unroll
    for (int mm = 0; mm < 16; ++mm) {
        float acc = bv;
#pragma unroll
        for (int k = 0; k < 8; ++k) {
            float4 b4 = *(const float4*)&sd[mm][k * 4];
            acc = fmaf(b4.x, w[k * 4 + 0], acc);
            acc = fmaf(b4.y, w[k * 4 + 1], acc);
            acc = fmaf(b4.z, w[k * 4 + 2], acc);
            acc = fmaf(b4.w, w[k * 4 + 3], acc);
        }
        delta2[(size_t)(m0 + mm) * EDIM + e] = f2bf(softplus_fast(acc));
    }
}

// ---------------------------------------------------------------------------
// Dual-dir depthwise causal conv + bias + silu, r21: dense xi input + 4-row
// blocking (7 tap-row loads per thread instead of 16; weights amortized 4x).
// Grid (MTOT/4, 2). Rows m0..m0+3 always share a sequence (4 | 1024).
// ---------------------------------------------------------------------------
__global__ __launch_bounds__(256) void conv_silu(
    const unsigned short* __restrict__ xi_f, const unsigned short* __restrict__ xi_b,
    const float* __restrict__ cwf, const float* __restrict__ cbf,
    const float* __restrict__ cwb, const float* __restrict__ cbb,
    unsigned short* __restrict__ xcbf2)
{
    const int dir = blockIdx.y;
    const unsigned short* xi = dir ? xi_b : xi_f;
    const float* cw = dir ? cwb : cwf;
    const float* cb = dir ? cbb : cbf;
    const int e = threadIdx.x << 2;
    const int m0 = blockIdx.x << 2;           // 0..8188
    const int t0 = m0 & (LSEQ - 1);

    float4 w0 = *(const float4*)&cw[e * 4];
    float4 w1 = *(const float4*)&cw[e * 4 + 4];
    float4 w2 = *(const float4*)&cw[e * 4 + 8];
    float4 w3 = *(const float4*)&cw[e * 4 + 12];
    float4 bias = *(const float4*)&cb[e];

    // load tap rows m0-3 .. m0+3 (7 rows x 4 cols)
    float v[7][4];
#pragma unroll
    for (int r = 0; r < 7; ++r) {
        if (t0 - 3 + r >= 0) {
            uint2 raw = *(const uint2*)&xi[(size_t)(m0 - 3 + r) * 1024 + e];
            v[r][0] = bf2f((unsigned short)(raw.x & 0xffff));
            v[r][1] = bf2f((unsigned short)(raw.x >> 16));
            v[r][2] = bf2f((unsigned short)(raw.y & 0xffff));
            v[r][3] = bf2f((unsigned short)(raw.y >> 16));
        } else {
            v[r][0] = v[r][1] = v[r][2] = v[r][3] = 0.f;
        }
    }

#pragma unroll
    for (int rr = 0; rr < 4; ++rr) {          // output rows m0+rr
        float4 acc = bias;
        acc.x = fmaf(w0.x, v[rr][0], acc.x);
        acc.y = fmaf(w1.x, v[rr][1], acc.y);
        acc.z = fmaf(w2.x, v[rr][2], acc.z);
        acc.w = fmaf(w3.x, v[rr][3], acc.w);
        acc.x = fmaf(w0.y, v[rr + 1][0], acc.x);
        acc.y = fmaf(w1.y, v[rr + 1][1], acc.y);
        acc.z = fmaf(w2.y, v[rr + 1][2], acc.z);
        acc.w = fmaf(w3.y, v[rr + 1][3], acc.w);
        acc.x = fmaf(w0.z, v[rr + 2][0], acc.x);
        acc.y = fmaf(w1.z, v[rr + 2][1], acc.y);
        acc.z = fmaf(w2.z, v[rr + 2][2], acc.z);
        acc.w = fmaf(w3.z, v[rr + 2][3], acc.w);
        acc.x = fmaf(w0.w, v[rr + 3][0], acc.x);
        acc.y = fmaf(w1.w, v[rr + 3][1], acc.y);
        acc.z = fmaf(w2.w, v[rr + 3][2], acc.z);
        acc.w = fmaf(w3.w, v[rr + 3][3], acc.w);
        float4 o;
        o.x = acc.x / (1.f + __expf(-acc.x));
        o.y = acc.y / (1.f + __expf(-acc.y));
        o.z = acc.z / (1.f + __expf(-acc.z));
        o.w = acc.w / (1.f + __expf(-acc.w));
        unsigned short b4[4] = {f2bf(o.x), f2bf(o.y), f2bf(o.z), f2bf(o.w)};
        *(uint2*)&xcbf2[((size_t)dir * MTOT + m0 + rr) * EDIM + e] = *(uint2*)b4;
    }
}

// ---------------------------------------------------------------------------
// Dual-dir chunked scan with power-chain fast path.
// ---------------------------------------------------------------------------
__global__ __launch_bounds__(256) void scan_part1(
    const unsigned short* __restrict__ delta2,
    const unsigned short* __restrict__ xcbf2,
    const float* __restrict__ dbc2,
    const float* __restrict__ Alog_f, const float* __restrict__ Alog_b,
    float* __restrict__ Psum, float* __restrict__ Ssum)
{
    __shared__ float sB[CHLEN][16];

    const int bd = blockIdx.y;               // 0..15 = dir*8 + b
    const int dir = bd >> 3;
    const int b = bd & 7;
    const int ch = blockIdx.z;
    const int tid = threadIdx.x;
    const int e  = blockIdx.x * 256 + tid;
    const size_t dirOff = (size_t)dir * MTOT;
    const int row0 = b * LSEQ + ch * CHLEN;
    const float* Alog = dir ? Alog_b : Alog_f;

#pragma unroll
    for (int it = 0; it < 4; ++it) {
        int q = tid + it * 256;
        int t = q >> 4, n = q & 15;
        sB[t][n] = dbc2[(dirOff + row0 + t) * 64 + 32 + n];
    }

    float Aen[16];
    bool fastA = true;
#pragma unroll
    for (int k = 0; k < 4; ++k) {
        float4 a4 = *(const float4*)&Alog[e * DSTATE + k * 4];
        Aen[k * 4 + 0] = -__expf(a4.x);
        Aen[k * 4 + 1] = -__expf(a4.y);
        Aen[k * 4 + 2] = -__expf(a4.z);
        Aen[k * 4 + 3] = -__expf(a4.w);
    }
#pragma unroll
    for (int n = 0; n < 16; ++n)
        fastA = fastA && (fabsf(Aen[n] + (float)(n + 1)) <= 1e-3f * (n + 1));

    float h[16];
#pragma unroll
    for (int n = 0; n < 16; ++n) h[n] = 0.f;
    float sumd = 0.f;

    __syncthreads();

    const size_t base = (dirOff + row0) * EDIM + e;
    float dnx = bf2f(delta2[base]);
    float xnx = bf2f(xcbf2[base]);

    for (int t = 0; t < CHLEN; ++t) {
        float d = dnx, xcv = xnx;
        if (t + 1 < CHLEN) {
            dnx = bf2f(delta2[base + (size_t)(t + 1) * EDIM]);
            xnx = bf2f(xcbf2[base + (size_t)(t + 1) * EDIM]);
        }
        sumd += d;
        float dx = d * xcv;
        float Bt[16];
        *(float4*)&Bt[0]  = *(const float4*)&sB[t][0];
        *(float4*)&Bt[4]  = *(const float4*)&sB[t][4];
        *(float4*)&Bt[8]  = *(const float4*)&sB[t][8];
        *(float4*)&Bt[12] = *(const float4*)&sB[t][12];
        float da[16];
        if (fastA) {
            pow16(__expf(-d), da);
        } else {
#pragma unroll
            for (int n = 0; n < 16; ++n) da[n] = __expf(d * Aen[n]);
        }
#pragma unroll
        for (int n = 0; n < 16; ++n)
            h[n] = fmaf(da[n], h[n], dx * Bt[n]);
    }

    size_t idx = ((size_t)(bd * NCH + ch) * EDIM + e) * DSTATE;
    float P[16];
    if (fastA) {
        pow16(__expf(-sumd), P);
    } else {
#pragma unroll
        for (int n = 0; n < 16; ++n) P[n] = __expf(Aen[n] * sumd);
    }
#pragma unroll
    for (int k = 0; k < 4; ++k) {
        *(float4*)&Psum[idx + k * 4] = *(float4*)&P[k * 4];
        *(float4*)&Ssum[idx + k * 4] = *(float4*)&h[k * 4];
    }
}

__global__ __launch_bounds__(256) void scan_combine(
    float* __restrict__ Psum, const float* __restrict__ Ssum)
{
    int i = blockIdx.x * 256 + threadIdx.x;
    int bd = i >> 14;
    int r = i & 16383;
    float H = 0.f;
#pragma unroll
    for (int ch = 0; ch < NCH; ++ch) {
        size_t idx = ((size_t)(bd * NCH + ch) << 14) + r;
        float p = Psum[idx];
        float s = Ssum[idx];
        Psum[idx] = H;
        H = fmaf(p, H, s);
    }
}

__global__ __launch_bounds__(256) void scan_part2(
    unsigned short* __restrict__ delta2,          // in: delta, out: g (in-place)
    const unsigned short* __restrict__ xcbf2,
    const float* __restrict__ dbc2,
    const float* __restrict__ Alog_f, const float* __restrict__ Alog_b,
    const float* __restrict__ Dvec_f, const float* __restrict__ Dvec_b,
    const unsigned short* __restrict__ z_f, const unsigned short* __restrict__ z_b,
    const float* __restrict__ Hstart)
{
    __shared__ float sB[CHLEN][16], sC[CHLEN][16];

    const int bd = blockIdx.y;
    const int dir = bd >> 3;
    const int b = bd & 7;
    const int ch = blockIdx.z;
    const int tid = threadIdx.x;
    const int e  = blockIdx.x * 256 + tid;
    const size_t dirOff = (size_t)dir * MTOT;
    const int row0 = b * LSEQ + ch * CHLEN;
    const float* Alog = dir ? Alog_b : Alog_f;
    const float* Dvec = dir ? Dvec_b : Dvec_f;
    const unsigned short* zb = dir ? z_b : z_f;

#pragma unroll
    for (int it = 0; it < 8; ++it) {
        int q = tid + it * 256;
        int t = q >> 5, c = q & 31;
        float v = dbc2[(dirOff + row0 + t) * 64 + 32 + c];
        if (c < 16) sB[t][c] = v; else sC[t][c - 16] = v;
    }

    float Aen[16];
    bool fastA = true;
#pragma unroll
    for (int k = 0; k < 4; ++k) {
        float4 a4 = *(const float4*)&Alog[e * DSTATE + k * 4];
        Aen[k * 4 + 0] = -__expf(a4.x);
        Aen[k * 4 + 1] = -__expf(a4.y);
        Aen[k * 4 + 2] = -__expf(a4.z);
        Aen[k * 4 + 3] = -__expf(a4.w);
    }
#pragma unroll
    for (int n = 0; n < 16; ++n)
        fastA = fastA && (fabsf(Aen[n] + (float)(n + 1)) <= 1e-3f * (n + 1));
    const float Dv = Dvec[e];

    float h[16];
    {
        size_t idx = ((size_t)(bd * NCH + ch) * EDIM + e) * DSTATE;
#pragma unroll
        for (int k = 0; k < 4; ++k)
            *(float4*)&h[k * 4] = *(const float4*)&Hstart[idx + k * 4];
    }

    __syncthreads();

    const size_t base = (dirOff + row0) * EDIM + e;
    const size_t zbase = (size_t)row0 * 1024 + e;    // dense z buffer
    float dnx = bf2f(delta2[base]);
    float xnx = bf2f(xcbf2[base]);
    float znx = bf2f(zb[zbase]);

    for (int t = 0; t < CHLEN; ++t) {
        float d = dnx, xcv = xnx, zv = znx;
        if (t + 1 < CHLEN) {
            dnx = bf2f(delta2[base + (size_t)(t + 1) * EDIM]);
            xnx = bf2f(xcbf2[base + (size_t)(t + 1) * EDIM]);
            znx = bf2f(zb[zbase + (size_t)(t + 1) * 1024]);
        }
        float dx = d * xcv;
        float Bt[16], Ct[16];
        *(float4*)&Bt[0]  = *(const float4*)&sB[t][0];
        *(float4*)&Bt[4]  = *(const float4*)&sB[t][4];
        *(float4*)&Bt[8]  = *(const float4*)&sB[t][8];
        *(float4*)&Bt[12] = *(const float4*)&sB[t][12];
        *(float4*)&Ct[0]  = *(const float4*)&sC[t][0];
        *(float4*)&Ct[4]  = *(const float4*)&sC[t][4];
        *(float4*)&Ct[8]  = *(const float4*)&sC[t][8];
        *(float4*)&Ct[12] = *(const float4*)&sC[t][12];
        float da[16];
        if (fastA) {
            pow16(__expf(-d), da);
        } else {
#pragma unroll
            for (int n = 0; n < 16; ++n) da[n] = __expf(d * Aen[n]);
        }
        float y = 0.f;
#pragma unroll
        for (int n = 0; n < 16; ++n) {
            h[n] = fmaf(da[n], h[n], dx * Bt[n]);
            y = fmaf(h[n], Ct[n], y);
        }
        y = fmaf(Dv, xcv, y);
        float sig = 1.f / (1.f + __expf(-zv));
        float zz  = zv * sig;
        delta2[base + (size_t)t * EDIM] = f2bf(fmaf(zz, y - xcv, xcv));
    }
}

// ---------------------------------------------------------------------------
__device__ __forceinline__ void block_reduce4(float4& s, float4* red, int tid)
{
#pragma unroll
    for (int off = 1; off < 64; off <<= 1) {
        s.x += __shfl_xor(s.x, off);
        s.y += __shfl_xor(s.y, off);
        s.z += __shfl_xor(s.z, off);
        s.w += __shfl_xor(s.w, off);
    }
    if ((tid & 63) == 0) red[tid >> 6] = s;
    __syncthreads();
    float4 a = red[0], b = red[1], c = red[2], d = red[3];
    s.x = a.x + b.x + c.x + d.x;
    s.y = a.y + b.y + c.y + d.y;
    s.z = a.z + b.z + c.z + d.z;
    s.w = a.w + b.w + c.w + d.w;
}

__global__ __launch_bounds__(256) void ln_combine(
    const float* __restrict__ yproj, const float* __restrict__ x,
    const float* __restrict__ g1, const float* __restrict__ b1,
    const float* __restrict__ g2, const float* __restrict__ b2,
    float* __restrict__ xs, unsigned short* __restrict__ xsbf)
{
    __shared__ float4 red[4];
    const int row = blockIdx.x, tid = threadIdx.x;
    const float* yf = yproj + (size_t)row * DMODEL;
    const float* yb = yproj + (size_t)(MTOT + row) * DMODEL;
    const float* xr = x + (size_t)row * DMODEL;

    float vf[2], vb[2];
#pragma unroll
    for (int j = 0; j < 2; ++j) {
        int i = tid + j * 256;
        float xi = xr[i];
        vf[j] = yf[i] + xi;
        vb[j] = yb[i] + xi;
    }
    float4 s = make_float4(vf[0] + vf[1], vf[0] * vf[0] + vf[1] * vf[1],
                           vb[0] + vb[1], vb[0] * vb[0] + vb[1] * vb[1]);
    block_reduce4(s, red, tid);
    const float inv = 1.f / DMODEL;
    float mf = s.x * inv, mb = s.z * inv;
    float rf = rsqrtf(s.y * inv - mf * mf + EPSLN);
    float rb = rsqrtf(s.w * inv - mb * mb + EPSLN);
#pragma unroll
    for (int j = 0; j < 2; ++j) {
        int i = tid + j * 256;
        float a  = (vf[j] - mf) * rf * g1[i] + b1[i];
        float bb = (vb[j] - mb) * rb * g2[i] + b2[i];
        float v = a + bb;
        xs[(size_t)row * DMODEL + i] = v;
        xsbf[(size_t)row * DMODEL + i] = f2bf(v);
    }
}

__global__ __launch_bounds__(256) void ln_final(
    const float* __restrict__ h2, const float* __restrict__ xs,
    const float* __restrict__ g3, const float* __restrict__ b3,
    float* __restrict__ out)
{
    __shared__ float4 red[4];
    const int row = blockIdx.x, tid = threadIdx.x;
    float v[2];
#pragma unroll
    for (int j = 0; j < 2; ++j) {
        int i = tid + j * 256;
        v[j] = h2[(size_t)row * DMODEL + i] + xs[(size_t)row * DMODEL + i];
    }
    float4 s = make_float4(v[0] + v[1], v[0] * v[0] + v[1] * v[1], 0.f, 0.f);
    block_reduce4(s, red, tid);
    const float inv = 1.f / DMODEL;
    float m  = s.x * inv;
    float rs = rsqrtf(s.y * inv - m * m + EPSLN);
#pragma unroll
    for (int j = 0; j < 2; ++j) {
        int i = tid + j * 256;
        out[(size_t)row * DMODEL + i] = (v[j] - m) * rs * g3[i] + b3[i];
    }
}

// ---------------------------------------------------------------------------
extern "C" void kernel_launch(void* const* d_in, const int* in_sizes, int n_in,
                              void* d_out, int out_size, void* d_ws, size_t ws_size,
                              hipStream_t stream)
{
    (void)in_sizes; (void)n_in;

    const float* x    = (const float*)d_in[28];
    const float* n1g  = (const float*)d_in[18];
    const float* n1b  = (const float*)d_in[19];
    const float* n2g  = (const float*)d_in[20];
    const float* n2b  = (const float*)d_in[21];
    const float* n3g  = (const float*)d_in[22];
    const float* n3b  = (const float*)d_in[23];
    const float* ff1w = (const float*)d_in[24];
    const float* ff1b = (const float*)d_in[25];
    const float* ff2w = (const float*)d_in[26];
    const float* ff2b = (const float*)d_in[27];

    const size_t need_floats =
        (size_t)MTOT * 2048 + (size_t)MTOT * 1024 + (size_t)MTOT * 1024 +
        (size_t)MTOT * 64 + (size_t)2 * MTOT * 512 + (size_t)MTOT * 512;
    if (ws_size < need_floats * sizeof(float)) return;
    if (out_size < MTOT * DMODEL) return;

    float* ws = (float*)d_ws;
    float* region0 = ws;
    float* region1 = ws + (size_t)16 * 1048576;
    float* region2 = ws + (size_t)24 * 1048576;
    float* super   = ws + (size_t)32 * 1048576;

    // region0: 4 dense bf16 buffers [8192][1024]: xi_f | z_f | xi_b | z_b
    unsigned short* xi_f = (unsigned short*)region0;
    unsigned short* z_f  = xi_f + (size_t)MTOT * 1024;
    unsigned short* xi_b = z_f  + (size_t)MTOT * 1024;
    unsigned short* z_b  = xi_b + (size_t)MTOT * 1024;
    unsigned short* xcbf2  = (unsigned short*)region1;
    unsigned short* delta2 = (unsigned short*)region2;   // becomes g2
    float* dbc2 = super;                                 // 1M floats [2M][64]
    float* Psum = super + (size_t)1 * 1048576;
    float* Ssum = super + (size_t)5 * 1048576;
    unsigned short* xpwb_f = (unsigned short*)(super + (size_t)9 * 1048576);
    unsigned short* xpwb_b = xpwb_f + 65536;
    // post-scan overlays:
    float* yproj = super;
    float* xs    = super + (size_t)8 * 1048576;
    unsigned short* xsbf = (unsigned short*)region0;     // xi/z dead after scans
    unsigned short* h1bf = (unsigned short*)(region0 + (size_t)4 * 1048576);
    float* h2    = region1;

    unsigned short* ob     = (unsigned short*)d_out;
    unsigned short* xbf    = ob;
    unsigned short* inwf_b = ob + (size_t)4194304;
    unsigned short* inwb_b = ob + (size_t)5242880;
    unsigned short* outwf_b= ob + (size_t)6291456;
    unsigned short* outwb_b= ob + (size_t)6815744;
    unsigned short* ff1w_b = ob + (size_t)7340032;
    unsigned short* ff2w_b = ob + (size_t)7864320;

    cast_all<<<4160, 256, 0, stream>>>(
        x, xbf,
        (const float*)d_in[0], inwf_b,
        (const float*)d_in[9], inwb_b,
        (const float*)d_in[8], outwf_b,
        (const float*)d_in[17], outwb_b,
        ff1w, ff1w_b,
        ff2w, ff2w_b,
        (const float*)d_in[3], xpwb_f,
        (const float*)d_in[12], xpwb_b);

    inproj_bf16<<<dim3(4096 / 128, MTOT / 128), 256, 0, stream>>>(
        xbf, inwf_b, inwb_b, xi_f, z_f, xi_b, z_b);

    conv_silu<<<dim3(MTOT / 4, 2), 256, 0, stream>>>(
        xi_f, xi_b,
        (const float*)d_in[1], (const float*)d_in[2],
        (const float*)d_in[10], (const float*)d_in[11], xcbf2);

    hipMemsetAsync(dbc2, 0, (size_t)2 * MTOT * 64 * sizeof(float), stream);
    xproj_bf16<<<dim3(2 * MTOT / 128, 4), 256, 0, stream>>>(
        xcbf2, xpwb_f, xpwb_b, dbc2);

    dt_fused<<<dim3(EDIM / 256, 2 * MTOT / 16), 256, 0, stream>>>(
        dbc2, (const float*)d_in[4], (const float*)d_in[5],
        (const float*)d_in[13], (const float*)d_in[14], delta2);

    scan_part1<<<dim3(EDIM / 256, 2 * BATCH, NCH), 256, 0, stream>>>(
        delta2, xcbf2, dbc2,
        (const float*)d_in[6], (const float*)d_in[15], Psum, Ssum);
    scan_combine<<<(2 * BATCH * EDIM * DSTATE) / 256, 256, 0, stream>>>(
        Psum, Ssum);
    scan_part2<<<dim3(EDIM / 256, 2 * BATCH, NCH), 256, 0, stream>>>(
        delta2, xcbf2, dbc2,
        (const float*)d_in[6], (const float*)d_in[15],
        (const float*)d_in[7], (const float*)d_in[16],
        z_f, z_b, Psum);

    gemm_bf16<<<dim3(512 / 128, 2 * MTOT / 128), 256, 0, stream>>>(
        delta2, delta2 + (size_t)MTOT * EDIM, EDIM, outwf_b, outwb_b,
        nullptr, yproj, DMODEL, 0, EDIM, 0);

    ln_combine<<<MTOT, 256, 0, stream>>>(yproj, x, n1g, n1b, n2g, n2b, xs, xsbf);
    gemm_bf16<<<dim3(DFF / 128, MTOT / 128), 256, 0, stream>>>(
        xsbf, xsbf, DMODEL, ff1w_b, ff1w_b, ff1b, h1bf, DFF, 1, DMODEL, 1);
    gemm_bf16<<<dim3(DMODEL / 128, MTOT / 128), 256, 0, stream>>>(
        h1bf, h1bf, DFF, ff2w_b, ff2w_b, ff2b, h2, DMODEL, 0, DFF, 0);
    ln_final<<<MTOT, 256, 0, stream>>>(h2, xs, n3g, n3b, (float*)d_out);
}

// Round 22
// 315.198 us; speedup vs baseline: 1.2066x; 1.0237x over previous
//
#include <hip/hip_runtime.h>
#include <hip/hip_bf16.h>

// Problem constants (fixed by reference)
#define LSEQ   1024
#define BATCH  8
#define MTOT   8192      // B*L
#define DMODEL 512
#define EDIM   1024      // EXPAND*D_MODEL
#define DSTATE 16
#define DTRANK 32
#define DFF    1024
#define EPSLN  1e-5f
#define NCH    16        // scan chunks per direction
#define CHLEN  64        // LSEQ/NCH

typedef __attribute__((ext_vector_type(8))) short bf16x8;
typedef __attribute__((ext_vector_type(4))) float f32x4;

__device__ __forceinline__ unsigned short f2bf(float f) {
    __hip_bfloat16 h = __float2bfloat16(f);   // RNE
    unsigned short u;
    __builtin_memcpy(&u, &h, 2);
    return u;
}
__device__ __forceinline__ float bf2f(unsigned short u) {
    unsigned int x = ((unsigned int)u) << 16;
    float f;
    __builtin_memcpy(&f, &x, 4);
    return f;
}

// fast softplus: HW v_exp + v_log (libm log1pf cost r16's dt 78us)
__device__ __forceinline__ float softplus_fast(float v) {
    float sp = __logf(1.f + __expf(v));
    return v > 80.f ? v : sp;
}

// q^(n+1) for n=0..15, log-depth chain (replaces 16 exps when Aen=-(n+1))
__device__ __forceinline__ void pow16(float q, float* da) {
    da[0] = q;
    da[1] = q * q;
    da[2] = da[1] * q;
    da[3] = da[1] * da[1];
    da[4] = da[3] * da[0];
    da[5] = da[3] * da[1];
    da[6] = da[3] * da[2];
    da[7] = da[3] * da[3];
    da[8]  = da[7] * da[0];
    da[9]  = da[7] * da[1];
    da[10] = da[7] * da[2];
    da[11] = da[7] * da[3];
    da[12] = da[7] * da[4];
    da[13] = da[7] * da[5];
    da[14] = da[7] * da[6];
    da[15] = da[7] * da[7];
}

// async global->LDS, 16B per lane. LDS dest = wave-uniform base + lane*16.
__device__ __forceinline__ void gload16(const unsigned short* g, unsigned short* l) {
    __builtin_amdgcn_global_load_lds(
        (const __attribute__((address_space(1))) void*)g,
        (__attribute__((address_space(3))) void*)l, 16, 0, 0);
}

// T1 XCD-aware chunked block swizzle (nwg % 8 == 0 at all call sites):
// consecutive linear blocks share an A-panel; default dispatch round-robins
// them across 8 XCD-private L2s. Remap so each XCD gets a contiguous chunk.
__device__ __forceinline__ void xcd_swizzle(int& bx, int& by) {
    int bid = by * gridDim.x + bx;
    int nwg = gridDim.x * gridDim.y;
    int s = (bid & 7) * (nwg >> 3) + (bid >> 3);
    bx = s % gridDim.x;
    by = s / gridDim.x;
}

// ---------------------------------------------------------------------------
// Merged f32->bf16 cast: 9 segments in one dispatch.
// ---------------------------------------------------------------------------
__device__ __forceinline__ void cast8(const float* in, unsigned short* out, int i) {
    float4 f0 = *(const float4*)&in[(size_t)i * 8];
    float4 f1 = *(const float4*)&in[(size_t)i * 8 + 4];
    unsigned short v[8] = {f2bf(f0.x), f2bf(f0.y), f2bf(f0.z), f2bf(f0.w),
                           f2bf(f1.x), f2bf(f1.y), f2bf(f1.z), f2bf(f1.w)};
    *(uint4*)&out[(size_t)i * 8] = *(uint4*)v;
}

__global__ __launch_bounds__(256) void cast_all(
    const float* x,  unsigned short* xb,
    const float* w1, unsigned short* w1b,
    const float* w2, unsigned short* w2b,
    const float* w3, unsigned short* w3b,
    const float* w4, unsigned short* w4b,
    const float* w5, unsigned short* w5b,
    const float* w6, unsigned short* w6b,
    const float* w7, unsigned short* w7b,
    const float* w8, unsigned short* w8b)
{
    const int blk = blockIdx.x;
    const int tid = threadIdx.x;
    if (blk < 2048)        cast8(x,  xb,  blk * 256 + tid);
    else if (blk < 2560)   cast8(w1, w1b, (blk - 2048) * 256 + tid);
    else if (blk < 3072)   cast8(w2, w2b, (blk - 2560) * 256 + tid);
    else if (blk < 3328)   cast8(w3, w3b, (blk - 3072) * 256 + tid);
    else if (blk < 3584)   cast8(w4, w4b, (blk - 3328) * 256 + tid);
    else if (blk < 3840)   cast8(w5, w5b, (blk - 3584) * 256 + tid);
    else if (blk < 4096)   cast8(w6, w6b, (blk - 3840) * 256 + tid);
    else if (blk < 4128)   cast8(w7, w7b, (blk - 4096) * 256 + tid);
    else                   cast8(w8, w8b, (blk - 4128) * 256 + tid);
}

// ---------------------------------------------------------------------------
// Fused dual-direction in-projection: dense xi/z buffers, XCD swizzle (r22).
// ---------------------------------------------------------------------------
__global__ __launch_bounds__(256) void inproj_bf16(
    const unsigned short* __restrict__ A,
    const unsigned short* __restrict__ Wf,
    const unsigned short* __restrict__ Wb,
    unsigned short* __restrict__ xi_f, unsigned short* __restrict__ z_f,
    unsigned short* __restrict__ xi_b, unsigned short* __restrict__ z_b)
{
    __shared__ unsigned short As[2][128][32];
    __shared__ unsigned short Ws[2][128][32];

    const int K = DMODEL;
    const int tid = threadIdx.x;
    int bx = blockIdx.x, by = blockIdx.y;
    xcd_swizzle(bx, by);
    const int rowbase = by * 128;
    const int colg = bx * 128;
    const int back = colg >= 2048;
    const unsigned short* W = back ? Wb : Wf;
    const int colbase = colg - (back ? 2048 : 0);
    const int is_z = colbase >= 1024;
    unsigned short* Cout = back ? (is_z ? z_b : xi_b) : (is_z ? z_f : xi_f);
    const int cofs = is_z ? 1024 : 0;

    const int wave = tid >> 6, lane = tid & 63;
    const int wm = wave >> 1, wn = wave & 1;
    const int lr = lane & 15;
    const int lc = lane >> 4;

    const int r0 = tid >> 2;
    const int cl = (tid & 3) ^ ((r0 >> 1) & 3);
    const unsigned short* Ag0 = A + (size_t)(rowbase + r0) * K + (cl << 3);
    const unsigned short* Ag1 = A + (size_t)(rowbase + r0 + 64) * K + (cl << 3);
    const unsigned short* Wg0 = W + (size_t)(colbase + r0) * K + (cl << 3);
    const unsigned short* Wg1 = W + (size_t)(colbase + r0 + 64) * K + (cl << 3);

    f32x4 acc[4][4];
#pragma unroll
    for (int i = 0; i < 4; ++i)
#pragma unroll
        for (int j = 0; j < 4; ++j)
            acc[i][j] = (f32x4){0.f, 0.f, 0.f, 0.f};

#define G_STAGE(bi, ko) do {                                   \
        gload16(Ag0 + (ko), &As[bi][wave << 4][0]);            \
        gload16(Ag1 + (ko), &As[bi][64 + (wave << 4)][0]);     \
        gload16(Wg0 + (ko), &Ws[bi][wave << 4][0]);            \
        gload16(Wg1 + (ko), &Ws[bi][64 + (wave << 4)][0]);     \
    } while (0)

#define G_COMPUTE(bi) do {                                     \
        bf16x8 af[4], bfv[4];                                  \
        _Pragma("unroll")                                      \
        for (int i = 0; i < 4; ++i) {                          \
            int R = wm * 64 + i * 16 + lr;                     \
            int pc = lc ^ ((R >> 1) & 3);                      \
            af[i] = *(const bf16x8*)&As[bi][R][pc << 3];       \
        }                                                      \
        _Pragma("unroll")                                      \
        for (int j = 0; j < 4; ++j) {                          \
            int R = wn * 64 + j * 16 + lr;                     \
            int pc = lc ^ ((R >> 1) & 3);                      \
            bfv[j] = *(const bf16x8*)&Ws[bi][R][pc << 3];      \
        }                                                      \
        _Pragma("unroll")                                      \
        for (int i = 0; i < 4; ++i)                            \
            _Pragma("unroll")                                  \
            for (int j = 0; j < 4; ++j)                        \
                acc[i][j] = __builtin_amdgcn_mfma_f32_16x16x32_bf16( \
                    af[i], bfv[j], acc[i][j], 0, 0, 0);        \
    } while (0)

    G_STAGE(0, 0);
    __syncthreads();
    for (int k0 = 0; k0 < K; k0 += 64) {
        G_STAGE(1, k0 + 32);
        __builtin_amdgcn_sched_barrier(0);
        G_COMPUTE(0);
        __syncthreads();
        if (k0 + 64 < K) G_STAGE(0, k0 + 64);
        __builtin_amdgcn_sched_barrier(0);
        G_COMPUTE(1);
        __syncthreads();
    }
#undef G_STAGE
#undef G_COMPUTE

    const int crow0 = rowbase + wm * 64 + ((lane >> 4) << 2);
    const int ccol0 = colbase + wn * 64 + lr;
#pragma unroll
    for (int j = 0; j < 4; ++j) {
        int col = ccol0 + j * 16 - cofs;          // 0..1023 within buffer
#pragma unroll
        for (int i = 0; i < 4; ++i) {
#pragma unroll
            for (int r = 0; r < 4; ++r) {
                int row = crow0 + i * 16 + r;
                if (back) row = (row & ~(LSEQ - 1)) + (LSEQ - 1 - (row & (LSEQ - 1)));
                Cout[(size_t)row * 1024 + col] = f2bf(acc[i][j][r]);
            }
        }
    }
}

// ---------------------------------------------------------------------------
// bf16 MFMA GEMM v5 + XCD swizzle: rows >= MTOT switch to (A_hi, W_hi).
// ---------------------------------------------------------------------------
__global__ __launch_bounds__(256) void gemm_bf16(
    const unsigned short* __restrict__ A,
    const unsigned short* __restrict__ A_hi, int lda,
    const unsigned short* __restrict__ W,
    const unsigned short* __restrict__ W_hi,
    const float* __restrict__ bias,
    void* __restrict__ Cp, int ldc, int c_bf16,
    int K, int act)
{
    __shared__ unsigned short As[2][128][32];
    __shared__ unsigned short Ws[2][128][32];

    const int tid = threadIdx.x;
    int bx = blockIdx.x, by = blockIdx.y;
    xcd_swizzle(bx, by);
    const int rowbase = by * 128;
    const int colbase = bx * 128;
    const unsigned short* Ause = A;
    const unsigned short* Wuse = W;
    int rlocal = rowbase;
    if (rowbase >= MTOT) { Ause = A_hi; Wuse = W_hi; rlocal = rowbase - MTOT; }

    const int wave = tid >> 6, lane = tid & 63;
    const int wm = wave >> 1, wn = wave & 1;
    const int lr = lane & 15;
    const int lc = lane >> 4;

    const int r0 = tid >> 2;
    const int cl = (tid & 3) ^ ((r0 >> 1) & 3);
    const unsigned short* Ag0 = Ause + (size_t)(rlocal + r0) * lda + (cl << 3);
    const unsigned short* Ag1 = Ause + (size_t)(rlocal + r0 + 64) * lda + (cl << 3);
    const unsigned short* Wg0 = Wuse + (size_t)(colbase + r0) * K + (cl << 3);
    const unsigned short* Wg1 = Wuse + (size_t)(colbase + r0 + 64) * K + (cl << 3);

    f32x4 acc[4][4];
#pragma unroll
    for (int i = 0; i < 4; ++i)
#pragma unroll
        for (int j = 0; j < 4; ++j)
            acc[i][j] = (f32x4){0.f, 0.f, 0.f, 0.f};

#define G_STAGE(bi, ko) do {                                   \
        gload16(Ag0 + (ko), &As[bi][wave << 4][0]);            \
        gload16(Ag1 + (ko), &As[bi][64 + (wave << 4)][0]);     \
        gload16(Wg0 + (ko), &Ws[bi][wave << 4][0]);            \
        gload16(Wg1 + (ko), &Ws[bi][64 + (wave << 4)][0]);     \
    } while (0)

#define G_COMPUTE(bi) do {                                     \
        bf16x8 af[4], bfv[4];                                  \
        _Pragma("unroll")                                      \
        for (int i = 0; i < 4; ++i) {                          \
            int R = wm * 64 + i * 16 + lr;                     \
            int pc = lc ^ ((R >> 1) & 3);                      \
            af[i] = *(const bf16x8*)&As[bi][R][pc << 3];       \
        }                                                      \
        _Pragma("unroll")                                      \
        for (int j = 0; j < 4; ++j) {                          \
            int R = wn * 64 + j * 16 + lr;                     \
            int pc = lc ^ ((R >> 1) & 3);                      \
            bfv[j] = *(const bf16x8*)&Ws[bi][R][pc << 3];      \
        }                                                      \
        _Pragma("unroll")                                      \
        for (int i = 0; i < 4; ++i)                            \
            _Pragma("unroll")                                  \
            for (int j = 0; j < 4; ++j)                        \
                acc[i][j] = __builtin_amdgcn_mfma_f32_16x16x32_bf16( \
                    af[i], bfv[j], acc[i][j], 0, 0, 0);        \
    } while (0)

    G_STAGE(0, 0);
    __syncthreads();
    for (int k0 = 0; k0 < K; k0 += 64) {
        G_STAGE(1, k0 + 32);
        __builtin_amdgcn_sched_barrier(0);
        G_COMPUTE(0);
        __syncthreads();
        if (k0 + 64 < K) G_STAGE(0, k0 + 64);
        __builtin_amdgcn_sched_barrier(0);
        G_COMPUTE(1);
        __syncthreads();
    }
#undef G_STAGE
#undef G_COMPUTE

    const int crow0 = rowbase + wm * 64 + ((lane >> 4) << 2);
    const int ccol0 = colbase + wn * 64 + lr;
#pragma unroll
    for (int j = 0; j < 4; ++j) {
        int col = ccol0 + j * 16;
        float bv = bias ? bias[col] : 0.f;
#pragma unroll
        for (int i = 0; i < 4; ++i) {
#pragma unroll
            for (int r = 0; r < 4; ++r) {
                int row = crow0 + i * 16 + r;
                float v = acc[i][j][r] + bv;
                if (act == 1) v = fmaxf(v, 0.f);
                if (c_bf16)
                    ((unsigned short*)Cp)[(size_t)row * ldc + col] = f2bf(v);
                else
                    ((float*)Cp)[(size_t)row * ldc + col] = v;
            }
        }
    }
}

// ---------------------------------------------------------------------------
// Dual-dir xproj (split-K): dbc2[2M,64] += xcbf2[2M,1024] @ xpw^T
// ---------------------------------------------------------------------------
__global__ __launch_bounds__(256) void xproj_bf16(
    const unsigned short* __restrict__ A,
    const unsigned short* __restrict__ Wf,
    const unsigned short* __restrict__ Wb,
    float* __restrict__ Cp)
{
    __shared__ unsigned short As[2][128][32];
    __shared__ unsigned short Ws[2][64][32];

    const int tid = threadIdx.x;
    const int rowbase = blockIdx.x * 128;
    const int kbase = blockIdx.y * 256;
    const unsigned short* W = (rowbase >= MTOT) ? Wb : Wf;
    const int wave = tid >> 6, lane = tid & 63;
    const int wm = wave >> 1, wn = wave & 1;
    const int lr = lane & 15;
    const int lc = lane >> 4;

    const int r0 = tid >> 2;
    const int cl = (tid & 3) ^ ((r0 >> 1) & 3);
    const unsigned short* Ag0 = A + (size_t)(rowbase + r0) * EDIM + kbase + (cl << 3);
    const unsigned short* Ag1 = A + (size_t)(rowbase + r0 + 64) * EDIM + kbase + (cl << 3);
    const unsigned short* Wg  = W + (size_t)r0 * EDIM + kbase + (cl << 3);

    f32x4 acc[4][2];
#pragma unroll
    for (int i = 0; i < 4; ++i)
#pragma unroll
        for (int j = 0; j < 2; ++j)
            acc[i][j] = (f32x4){0.f, 0.f, 0.f, 0.f};

#define X_STAGE(bi, ko) do {                                   \
        gload16(Ag0 + (ko), &As[bi][wave << 4][0]);            \
        gload16(Ag1 + (ko), &As[bi][64 + (wave << 4)][0]);     \
        gload16(Wg  + (ko), &Ws[bi][wave << 4][0]);            \
    } while (0)

#define X_COMPUTE(bi) do {                                     \
        bf16x8 af[4], bfv[2];                                  \
        _Pragma("unroll")                                      \
        for (int i = 0; i < 4; ++i) {                          \
            int R = wm * 64 + i * 16 + lr;                     \
            int pc = lc ^ ((R >> 1) & 3);                      \
            af[i] = *(const bf16x8*)&As[bi][R][pc << 3];       \
        }                                                      \
        _Pragma("unroll")                                      \
        for (int j = 0; j < 2; ++j) {                          \
            int R = wn * 32 + j * 16 + lr;                     \
            int pc = lc ^ ((R >> 1) & 3);                      \
            bfv[j] = *(const bf16x8*)&Ws[bi][R][pc << 3];      \
        }                                                      \
        _Pragma("unroll")                                      \
        for (int i = 0; i < 4; ++i)                            \
            _Pragma("unroll")                                  \
            for (int j = 0; j < 2; ++j)                        \
                acc[i][j] = __builtin_amdgcn_mfma_f32_16x16x32_bf16( \
                    af[i], bfv[j], acc[i][j], 0, 0, 0);        \
    } while (0)

    X_STAGE(0, 0);
    __syncthreads();
    for (int k0 = 0; k0 < 256; k0 += 64) {
        X_STAGE(1, k0 + 32);
        __builtin_amdgcn_sched_barrier(0);
        X_COMPUTE(0);
        __syncthreads();
        if (k0 + 64 < 256) X_STAGE(0, k0 + 64);
        __builtin_amdgcn_sched_barrier(0);
        X_COMPUTE(1);
        __syncthreads();
    }
#undef X_STAGE
#undef X_COMPUTE

    const int crow0 = rowbase + wm * 64 + ((lane >> 4) << 2);
    const int ccol0 = wn * 32 + lr;
#pragma unroll
    for (int i = 0; i < 4; ++i)
#pragma unroll
        for (int j = 0; j < 2; ++j)
#pragma unroll
            for (int r = 0; r < 4; ++r)
                atomicAdd(&Cp[(size_t)(crow0 + i * 16 + r) * 64 + ccol0 + j * 16],
                          acc[i][j][r]);
}

// ---------------------------------------------------------------------------
// Dual-dir dt: delta2[2M][1024] (bf16), 16 rows/block, fast softplus.
// ---------------------------------------------------------------------------
__global__ __launch_bounds__(256) void dt_fused(
    const float* __restrict__ dbc2,
    const float* __restrict__ dtw_f, const float* __restrict__ dtb_f,
    const float* __restrict__ dtw_b, const float* __restrict__ dtb_b,
    unsigned short* __restrict__ delta2)
{
    __shared__ float sd[16][32];

    const int e  = blockIdx.x * 256 + threadIdx.x;
    const int m0 = blockIdx.y * 16;
    const float* dtw = (m0 >= MTOT) ? dtw_b : dtw_f;
    const float* dtb = (m0 >= MTOT) ? dtb_b : dtb_f;

    float w[32];
#pragma unroll
    for (int k = 0; k < 8; ++k) {
        float4 v = *(const float4*)&dtw[(size_t)e * 32 + k * 4];
        w[k * 4 + 0] = v.x; w[k * 4 + 1] = v.y;
        w[k * 4 + 2] = v.z; w[k * 4 + 3] = v.w;
    }
    const float bv = dtb[e];

    if (threadIdx.x < 128) {
        int r = threadIdx.x >> 3;
        int c = (threadIdx.x & 7) << 2;
        *(float4*)&sd[r][c] = *(const float4*)&dbc2[(size_t)(m0 + r) * 64 + c];
    }
    __syncthreads();

#pragma unroll
    for (int mm = 0; mm < 16; ++mm) {
        float acc = bv;
#pragma unroll
        for (int k = 0; k < 8; ++k) {
            float4 b4 = *(const float4*)&sd[mm][k * 4];
            acc = fmaf(b4.x, w[k * 4 + 0], acc);
            acc = fmaf(b4.y, w[k * 4 + 1], acc);
            acc = fmaf(b4.z, w[k * 4 + 2], acc);
            acc = fmaf(b4.w, w[k * 4 + 3], acc);
        }
        delta2[(size_t)(m0 + mm) * EDIM + e] = f2bf(softplus_fast(acc));
    }
}

// ---------------------------------------------------------------------------
// Dual-dir depthwise causal conv + bias + silu, dense xi + 4-row blocking.
// ---------------------------------------------------------------------------
__global__ __launch_bounds__(256) void conv_silu(
    const unsigned short* __restrict__ xi_f, const unsigned short* __restrict__ xi_b,
    const float* __restrict__ cwf, const float* __restrict__ cbf,
    const float* __restrict__ cwb, const float* __restrict__ cbb,
    unsigned short* __restrict__ xcbf2)
{
    const int dir = blockIdx.y;
    const unsigned short* xi = dir ? xi_b : xi_f;
    const float* cw = dir ? cwb : cwf;
    const float* cb = dir ? cbb : cbf;
    const int e = threadIdx.x << 2;
    const int m0 = blockIdx.x << 2;           // 0..8188
    const int t0 = m0 & (LSEQ - 1);

    float4 w0 = *(const float4*)&cw[e * 4];
    float4 w1 = *(const float4*)&cw[e * 4 + 4];
    float4 w2 = *(const float4*)&cw[e * 4 + 8];
    float4 w3 = *(const float4*)&cw[e * 4 + 12];
    float4 bias = *(const float4*)&cb[e];

    // load tap rows m0-3 .. m0+3 (7 rows x 4 cols)
    float v[7][4];
#pragma unroll
    for (int r = 0; r < 7; ++r) {
        if (t0 - 3 + r >= 0) {
            uint2 raw = *(const uint2*)&xi[(size_t)(m0 - 3 + r) * 1024 + e];
            v[r][0] = bf2f((unsigned short)(raw.x & 0xffff));
            v[r][1] = bf2f((unsigned short)(raw.x >> 16));
            v[r][2] = bf2f((unsigned short)(raw.y & 0xffff));
            v[r][3] = bf2f((unsigned short)(raw.y >> 16));
        } else {
            v[r][0] = v[r][1] = v[r][2] = v[r][3] = 0.f;
        }
    }

#pragma unroll
    for (int rr = 0; rr < 4; ++rr) {          // output rows m0+rr
        float4 acc = bias;
        acc.x = fmaf(w0.x, v[rr][0], acc.x);
        acc.y = fmaf(w1.x, v[rr][1], acc.y);
        acc.z = fmaf(w2.x, v[rr][2], acc.z);
        acc.w = fmaf(w3.x, v[rr][3], acc.w);
        acc.x = fmaf(w0.y, v[rr + 1][0], acc.x);
        acc.y = fmaf(w1.y, v[rr + 1][1], acc.y);
        acc.z = fmaf(w2.y, v[rr + 1][2], acc.z);
        acc.w = fmaf(w3.y, v[rr + 1][3], acc.w);
        acc.x = fmaf(w0.z, v[rr + 2][0], acc.x);
        acc.y = fmaf(w1.z, v[rr + 2][1], acc.y);
        acc.z = fmaf(w2.z, v[rr + 2][2], acc.z);
        acc.w = fmaf(w3.z, v[rr + 2][3], acc.w);
        acc.x = fmaf(w0.w, v[rr + 3][0], acc.x);
        acc.y = fmaf(w1.w, v[rr + 3][1], acc.y);
        acc.z = fmaf(w2.w, v[rr + 3][2], acc.z);
        acc.w = fmaf(w3.w, v[rr + 3][3], acc.w);
        float4 o;
        o.x = acc.x / (1.f + __expf(-acc.x));
        o.y = acc.y / (1.f + __expf(-acc.y));
        o.z = acc.z / (1.f + __expf(-acc.z));
        o.w = acc.w / (1.f + __expf(-acc.w));
        unsigned short b4[4] = {f2bf(o.x), f2bf(o.y), f2bf(o.z), f2bf(o.w)};
        *(uint2*)&xcbf2[((size_t)dir * MTOT + m0 + rr) * EDIM + e] = *(uint2*)b4;
    }
}

// ---------------------------------------------------------------------------
// Dual-dir chunked scan with power-chain fast path.
// ---------------------------------------------------------------------------
__global__ __launch_bounds__(256) void scan_part1(
    const unsigned short* __restrict__ delta2,
    const unsigned short* __restrict__ xcbf2,
    const float* __restrict__ dbc2,
    const float* __restrict__ Alog_f, const float* __restrict__ Alog_b,
    float* __restrict__ Psum, float* __restrict__ Ssum)
{
    __shared__ float sB[CHLEN][16];

    const int bd = blockIdx.y;               // 0..15 = dir*8 + b
    const int dir = bd >> 3;
    const int b = bd & 7;
    const int ch = blockIdx.z;
    const int tid = threadIdx.x;
    const int e  = blockIdx.x * 256 + tid;
    const size_t dirOff = (size_t)dir * MTOT;
    const int row0 = b * LSEQ + ch * CHLEN;
    const float* Alog = dir ? Alog_b : Alog_f;

#pragma unroll
    for (int it = 0; it < 4; ++it) {
        int q = tid + it * 256;
        int t = q >> 4, n = q & 15;
        sB[t][n] = dbc2[(dirOff + row0 + t) * 64 + 32 + n];
    }

    float Aen[16];
    bool fastA = true;
#pragma unroll
    for (int k = 0; k < 4; ++k) {
        float4 a4 = *(const float4*)&Alog[e * DSTATE + k * 4];
        Aen[k * 4 + 0] = -__expf(a4.x);
        Aen[k * 4 + 1] = -__expf(a4.y);
        Aen[k * 4 + 2] = -__expf(a4.z);
        Aen[k * 4 + 3] = -__expf(a4.w);
    }
#pragma unroll
    for (int n = 0; n < 16; ++n)
        fastA = fastA && (fabsf(Aen[n] + (float)(n + 1)) <= 1e-3f * (n + 1));

    float h[16];
#pragma unroll
    for (int n = 0; n < 16; ++n) h[n] = 0.f;
    float sumd = 0.f;

    __syncthreads();

    const size_t base = (dirOff + row0) * EDIM + e;
    float dnx = bf2f(delta2[base]);
    float xnx = bf2f(xcbf2[base]);

    for (int t = 0; t < CHLEN; ++t) {
        float d = dnx, xcv = xnx;
        if (t + 1 < CHLEN) {
            dnx = bf2f(delta2[base + (size_t)(t + 1) * EDIM]);
            xnx = bf2f(xcbf2[base + (size_t)(t + 1) * EDIM]);
        }
        sumd += d;
        float dx = d * xcv;
        float Bt[16];
        *(float4*)&Bt[0]  = *(const float4*)&sB[t][0];
        *(float4*)&Bt[4]  = *(const float4*)&sB[t][4];
        *(float4*)&Bt[8]  = *(const float4*)&sB[t][8];
        *(float4*)&Bt[12] = *(const float4*)&sB[t][12];
        float da[16];
        if (fastA) {
            pow16(__expf(-d), da);
        } else {
#pragma unroll
            for (int n = 0; n < 16; ++n) da[n] = __expf(d * Aen[n]);
        }
#pragma unroll
        for (int n = 0; n < 16; ++n)
            h[n] = fmaf(da[n], h[n], dx * Bt[n]);
    }

    size_t idx = ((size_t)(bd * NCH + ch) * EDIM + e) * DSTATE;
    float P[16];
    if (fastA) {
        pow16(__expf(-sumd), P);
    } else {
#pragma unroll
        for (int n = 0; n < 16; ++n) P[n] = __expf(Aen[n] * sumd);
    }
#pragma unroll
    for (int k = 0; k < 4; ++k) {
        *(float4*)&Psum[idx + k * 4] = *(float4*)&P[k * 4];
        *(float4*)&Ssum[idx + k * 4] = *(float4*)&h[k * 4];
    }
}

__global__ __launch_bounds__(256) void scan_combine(
    float* __restrict__ Psum, const float* __restrict__ Ssum)
{
    int i = blockIdx.x * 256 + threadIdx.x;
    int bd = i >> 14;
    int r = i & 16383;
    float H = 0.f;
#pragma unroll
    for (int ch = 0; ch < NCH; ++ch) {
        size_t idx = ((size_t)(bd * NCH + ch) << 14) + r;
        float p = Psum[idx];
        float s = Ssum[idx];
        Psum[idx] = H;
        H = fmaf(p, H, s);
    }
}

__global__ __launch_bounds__(256) void scan_part2(
    unsigned short* __restrict__ delta2,          // in: delta, out: g (in-place)
    const unsigned short* __restrict__ xcbf2,
    const float* __restrict__ dbc2,
    const float* __restrict__ Alog_f, const float* __restrict__ Alog_b,
    const float* __restrict__ Dvec_f, const float* __restrict__ Dvec_b,
    const unsigned short* __restrict__ z_f, const unsigned short* __restrict__ z_b,
    const float* __restrict__ Hstart)
{
    __shared__ float sB[CHLEN][16], sC[CHLEN][16];

    const int bd = blockIdx.y;
    const int dir = bd >> 3;
    const int b = bd & 7;
    const int ch = blockIdx.z;
    const int tid = threadIdx.x;
    const int e  = blockIdx.x * 256 + tid;
    const size_t dirOff = (size_t)dir * MTOT;
    const int row0 = b * LSEQ + ch * CHLEN;
    const float* Alog = dir ? Alog_b : Alog_f;
    const float* Dvec = dir ? Dvec_b : Dvec_f;
    const unsigned short* zb = dir ? z_b : z_f;

#pragma unroll
    for (int it = 0; it < 8; ++it) {
        int q = tid + it * 256;
        int t = q >> 5, c = q & 31;
        float v = dbc2[(dirOff + row0 + t) * 64 + 32 + c];
        if (c < 16) sB[t][c] = v; else sC[t][c - 16] = v;
    }

    float Aen[16];
    bool fastA = true;
#pragma unroll
    for (int k = 0; k < 4; ++k) {
        float4 a4 = *(const float4*)&Alog[e * DSTATE + k * 4];
        Aen[k * 4 + 0] = -__expf(a4.x);
        Aen[k * 4 + 1] = -__expf(a4.y);
        Aen[k * 4 + 2] = -__expf(a4.z);
        Aen[k * 4 + 3] = -__expf(a4.w);
    }
#pragma unroll
    for (int n = 0; n < 16; ++n)
        fastA = fastA && (fabsf(Aen[n] + (float)(n + 1)) <= 1e-3f * (n + 1));
    const float Dv = Dvec[e];

    float h[16];
    {
        size_t idx = ((size_t)(bd * NCH + ch) * EDIM + e) * DSTATE;
#pragma unroll
        for (int k = 0; k < 4; ++k)
            *(float4*)&h[k * 4] = *(const float4*)&Hstart[idx + k * 4];
    }

    __syncthreads();

    const size_t base = (dirOff + row0) * EDIM + e;
    const size_t zbase = (size_t)row0 * 1024 + e;    // dense z buffer
    float dnx = bf2f(delta2[base]);
    float xnx = bf2f(xcbf2[base]);
    float znx = bf2f(zb[zbase]);

    for (int t = 0; t < CHLEN; ++t) {
        float d = dnx, xcv = xnx, zv = znx;
        if (t + 1 < CHLEN) {
            dnx = bf2f(delta2[base + (size_t)(t + 1) * EDIM]);
            xnx = bf2f(xcbf2[base + (size_t)(t + 1) * EDIM]);
            znx = bf2f(zb[zbase + (size_t)(t + 1) * 1024]);
        }
        float dx = d * xcv;
        float Bt[16], Ct[16];
        *(float4*)&Bt[0]  = *(const float4*)&sB[t][0];
        *(float4*)&Bt[4]  = *(const float4*)&sB[t][4];
        *(float4*)&Bt[8]  = *(const float4*)&sB[t][8];
        *(float4*)&Bt[12] = *(const float4*)&sB[t][12];
        *(float4*)&Ct[0]  = *(const float4*)&sC[t][0];
        *(float4*)&Ct[4]  = *(const float4*)&sC[t][4];
        *(float4*)&Ct[8]  = *(const float4*)&sC[t][8];
        *(float4*)&Ct[12] = *(const float4*)&sC[t][12];
        float da[16];
        if (fastA) {
            pow16(__expf(-d), da);
        } else {
#pragma unroll
            for (int n = 0; n < 16; ++n) da[n] = __expf(d * Aen[n]);
        }
        float y = 0.f;
#pragma unroll
        for (int n = 0; n < 16; ++n) {
            h[n] = fmaf(da[n], h[n], dx * Bt[n]);
            y = fmaf(h[n], Ct[n], y);
        }
        y = fmaf(Dv, xcv, y);
        float sig = 1.f / (1.f + __expf(-zv));
        float zz  = zv * sig;
        delta2[base + (size_t)t * EDIM] = f2bf(fmaf(zz, y - xcv, xcv));
    }
}

// ---------------------------------------------------------------------------
__device__ __forceinline__ void block_reduce4(float4& s, float4* red, int tid)
{
#pragma unroll
    for (int off = 1; off < 64; off <<= 1) {
        s.x += __shfl_xor(s.x, off);
        s.y += __shfl_xor(s.y, off);
        s.z += __shfl_xor(s.z, off);
        s.w += __shfl_xor(s.w, off);
    }
    if ((tid & 63) == 0) red[tid >> 6] = s;
    __syncthreads();
    float4 a = red[0], b = red[1], c = red[2], d = red[3];
    s.x = a.x + b.x + c.x + d.x;
    s.y = a.y + b.y + c.y + d.y;
    s.z = a.z + b.z + c.z + d.z;
    s.w = a.w + b.w + c.w + d.w;
}

__global__ __launch_bounds__(256) void ln_combine(
    const float* __restrict__ yproj, const float* __restrict__ x,
    const float* __restrict__ g1, const float* __restrict__ b1,
    const float* __restrict__ g2, const float* __restrict__ b2,
    float* __restrict__ xs, unsigned short* __restrict__ xsbf)
{
    __shared__ float4 red[4];
    const int row = blockIdx.x, tid = threadIdx.x;
    const float* yf = yproj + (size_t)row * DMODEL;
    const float* yb = yproj + (size_t)(MTOT + row) * DMODEL;
    const float* xr = x + (size_t)row * DMODEL;

    float vf[2], vb[2];
#pragma unroll
    for (int j = 0; j < 2; ++j) {
        int i = tid + j * 256;
        float xi = xr[i];
        vf[j] = yf[i] + xi;
        vb[j] = yb[i] + xi;
    }
    float4 s = make_float4(vf[0] + vf[1], vf[0] * vf[0] + vf[1] * vf[1],
                           vb[0] + vb[1], vb[0] * vb[0] + vb[1] * vb[1]);
    block_reduce4(s, red, tid);
    const float inv = 1.f / DMODEL;
    float mf = s.x * inv, mb = s.z * inv;
    float rf = rsqrtf(s.y * inv - mf * mf + EPSLN);
    float rb = rsqrtf(s.w * inv - mb * mb + EPSLN);
#pragma unroll
    for (int j = 0; j < 2; ++j) {
        int i = tid + j * 256;
        float a  = (vf[j] - mf) * rf * g1[i] + b1[i];
        float bb = (vb[j] - mb) * rb * g2[i] + b2[i];
        float v = a + bb;
        xs[(size_t)row * DMODEL + i] = v;
        xsbf[(size_t)row * DMODEL + i] = f2bf(v);
    }
}

__global__ __launch_bounds__(256) void ln_final(
    const float* __restrict__ h2, const float* __restrict__ xs,
    const float* __restrict__ g3, const float* __restrict__ b3,
    float* __restrict__ out)
{
    __shared__ float4 red[4];
    const int row = blockIdx.x, tid = threadIdx.x;
    float v[2];
#pragma unroll
    for (int j = 0; j < 2; ++j) {
        int i = tid + j * 256;
        v[j] = h2[(size_t)row * DMODEL + i] + xs[(size_t)row * DMODEL + i];
    }
    float4 s = make_float4(v[0] + v[1], v[0] * v[0] + v[1] * v[1], 0.f, 0.f);
    block_reduce4(s, red, tid);
    const float inv = 1.f / DMODEL;
    float m  = s.x * inv;
    float rs = rsqrtf(s.y * inv - m * m + EPSLN);
#pragma unroll
    for (int j = 0; j < 2; ++j) {
        int i = tid + j * 256;
        out[(size_t)row * DMODEL + i] = (v[j] - m) * rs * g3[i] + b3[i];
    }
}

// ---------------------------------------------------------------------------
extern "C" void kernel_launch(void* const* d_in, const int* in_sizes, int n_in,
                              void* d_out, int out_size, void* d_ws, size_t ws_size,
                              hipStream_t stream)
{
    (void)in_sizes; (void)n_in;

    const float* x    = (const float*)d_in[28];
    const float* n1g  = (const float*)d_in[18];
    const float* n1b  = (const float*)d_in[19];
    const float* n2g  = (const float*)d_in[20];
    const float* n2b  = (const float*)d_in[21];
    const float* n3g  = (const float*)d_in[22];
    const float* n3b  = (const float*)d_in[23];
    const float* ff1w = (const float*)d_in[24];
    const float* ff1b = (const float*)d_in[25];
    const float* ff2w = (const float*)d_in[26];
    const float* ff2b = (const float*)d_in[27];

    const size_t need_floats =
        (size_t)MTOT * 2048 + (size_t)MTOT * 1024 + (size_t)MTOT * 1024 +
        (size_t)MTOT * 64 + (size_t)2 * MTOT * 512 + (size_t)MTOT * 512;
    if (ws_size < need_floats * sizeof(float)) return;
    if (out_size < MTOT * DMODEL) return;

    float* ws = (float*)d_ws;
    float* region0 = ws;
    float* region1 = ws + (size_t)16 * 1048576;
    float* region2 = ws + (size_t)24 * 1048576;
    float* super   = ws + (size_t)32 * 1048576;

    // region0: 4 dense bf16 buffers [8192][1024]: xi_f | z_f | xi_b | z_b
    unsigned short* xi_f = (unsigned short*)region0;
    unsigned short* z_f  = xi_f + (size_t)MTOT * 1024;
    unsigned short* xi_b = z_f  + (size_t)MTOT * 1024;
    unsigned short* z_b  = xi_b + (size_t)MTOT * 1024;
    unsigned short* xcbf2  = (unsigned short*)region1;
    unsigned short* delta2 = (unsigned short*)region2;   // becomes g2
    float* dbc2 = super;                                 // 1M floats [2M][64]
    float* Psum = super + (size_t)1 * 1048576;
    float* Ssum = super + (size_t)5 * 1048576;
    unsigned short* xpwb_f = (unsigned short*)(super + (size_t)9 * 1048576);
    unsigned short* xpwb_b = xpwb_f + 65536;
    // post-scan overlays:
    float* yproj = super;
    float* xs    = super + (size_t)8 * 1048576;
    unsigned short* xsbf = (unsigned short*)region0;     // xi/z dead after scans
    unsigned short* h1bf = (unsigned short*)(region0 + (size_t)4 * 1048576);
    float* h2    = region1;

    unsigned short* ob     = (unsigned short*)d_out;
    unsigned short* xbf    = ob;
    unsigned short* inwf_b = ob + (size_t)4194304;
    unsigned short* inwb_b = ob + (size_t)5242880;
    unsigned short* outwf_b= ob + (size_t)6291456;
    unsigned short* outwb_b= ob + (size_t)6815744;
    unsigned short* ff1w_b = ob + (size_t)7340032;
    unsigned short* ff2w_b = ob + (size_t)7864320;

    cast_all<<<4160, 256, 0, stream>>>(
        x, xbf,
        (const float*)d_in[0], inwf_b,
        (const float*)d_in[9], inwb_b,
        (const float*)d_in[8], outwf_b,
        (const float*)d_in[17], outwb_b,
        ff1w, ff1w_b,
        ff2w, ff2w_b,
        (const float*)d_in[3], xpwb_f,
        (const float*)d_in[12], xpwb_b);

    inproj_bf16<<<dim3(4096 / 128, MTOT / 128), 256, 0, stream>>>(
        xbf, inwf_b, inwb_b, xi_f, z_f, xi_b, z_b);

    conv_silu<<<dim3(MTOT / 4, 2), 256, 0, stream>>>(
        xi_f, xi_b,
        (const float*)d_in[1], (const float*)d_in[2],
        (const float*)d_in[10], (const float*)d_in[11], xcbf2);

    hipMemsetAsync(dbc2, 0, (size_t)2 * MTOT * 64 * sizeof(float), stream);
    xproj_bf16<<<dim3(2 * MTOT / 128, 4), 256, 0, stream>>>(
        xcbf2, xpwb_f, xpwb_b, dbc2);

    dt_fused<<<dim3(EDIM / 256, 2 * MTOT / 16), 256, 0, stream>>>(
        dbc2, (const float*)d_in[4], (const float*)d_in[5],
        (const float*)d_in[13], (const float*)d_in[14], delta2);

    scan_part1<<<dim3(EDIM / 256, 2 * BATCH, NCH), 256, 0, stream>>>(
        delta2, xcbf2, dbc2,
        (const float*)d_in[6], (const float*)d_in[15], Psum, Ssum);
    scan_combine<<<(2 * BATCH * EDIM * DSTATE) / 256, 256, 0, stream>>>(
        Psum, Ssum);
    scan_part2<<<dim3(EDIM / 256, 2 * BATCH, NCH), 256, 0, stream>>>(
        delta2, xcbf2, dbc2,
        (const float*)d_in[6], (const float*)d_in[15],
        (const float*)d_in[7], (const float*)d_in[16],
        z_f, z_b, Psum);

    gemm_bf16<<<dim3(512 / 128, 2 * MTOT / 128), 256, 0, stream>>>(
        delta2, delta2 + (size_t)MTOT * EDIM, EDIM, outwf_b, outwb_b,
        nullptr, yproj, DMODEL, 0, EDIM, 0);

    ln_combine<<<MTOT, 256, 0, stream>>>(yproj, x, n1g, n1b, n2g, n2b, xs, xsbf);
    gemm_bf16<<<dim3(DFF / 128, MTOT / 128), 256, 0, stream>>>(
        xsbf, xsbf, DMODEL, ff1w_b, ff1w_b, ff1b, h1bf, DFF, 1, DMODEL, 1);
    gemm_bf16<<<dim3(DMODEL / 128, MTOT / 128), 256, 0, stream>>>(
        h1bf, h1bf, DFF, ff2w_b, ff2w_b, ff2b, h2, DMODEL, 0, DFF, 0);
    ln_final<<<MTOT, 256, 0, stream>>>(h2, xs, n3g, n3b, (float*)d_out);
}

// Round 23
// 313.728 us; speedup vs baseline: 1.2122x; 1.0047x over previous
//
#include <hip/hip_runtime.h>
#include <hip/hip_bf16.h>

// Problem constants (fixed by reference)
#define LSEQ   1024
#define BATCH  8
#define MTOT   8192      // B*L
#define DMODEL 512
#define EDIM   1024      // EXPAND*D_MODEL
#define DSTATE 16
#define DTRANK 32
#define DFF    1024
#define EPSLN  1e-5f
#define NCH    16        // scan chunks per direction
#define CHLEN  64        // LSEQ/NCH

typedef __attribute__((ext_vector_type(8))) short bf16x8;
typedef __attribute__((ext_vector_type(4))) float f32x4;

__device__ __forceinline__ unsigned short f2bf(float f) {
    __hip_bfloat16 h = __float2bfloat16(f);   // RNE
    unsigned short u;
    __builtin_memcpy(&u, &h, 2);
    return u;
}
__device__ __forceinline__ float bf2f(unsigned short u) {
    unsigned int x = ((unsigned int)u) << 16;
    float f;
    __builtin_memcpy(&f, &x, 4);
    return f;
}

// fast softplus: HW v_exp + v_log (libm log1pf cost r16's dt 78us)
__device__ __forceinline__ float softplus_fast(float v) {
    float sp = __logf(1.f + __expf(v));
    return v > 80.f ? v : sp;
}

// q^(n+1) for n=0..15, log-depth chain (replaces 16 exps when Aen=-(n+1))
__device__ __forceinline__ void pow16(float q, float* da) {
    da[0] = q;
    da[1] = q * q;
    da[2] = da[1] * q;
    da[3] = da[1] * da[1];
    da[4] = da[3] * da[0];
    da[5] = da[3] * da[1];
    da[6] = da[3] * da[2];
    da[7] = da[3] * da[3];
    da[8]  = da[7] * da[0];
    da[9]  = da[7] * da[1];
    da[10] = da[7] * da[2];
    da[11] = da[7] * da[3];
    da[12] = da[7] * da[4];
    da[13] = da[7] * da[5];
    da[14] = da[7] * da[6];
    da[15] = da[7] * da[7];
}

// async global->LDS, 16B per lane. LDS dest = wave-uniform base + lane*16.
__device__ __forceinline__ void gload16(const unsigned short* g, unsigned short* l) {
    __builtin_amdgcn_global_load_lds(
        (const __attribute__((address_space(1))) void*)g,
        (__attribute__((address_space(3))) void*)l, 16, 0, 0);
}

// T1 XCD-aware chunked block swizzle (nwg % 8 == 0 at all call sites).
__device__ __forceinline__ void xcd_swizzle(int& bx, int& by) {
    int bid = by * gridDim.x + bx;
    int nwg = gridDim.x * gridDim.y;
    int s = (bid & 7) * (nwg >> 3) + (bid >> 3);
    bx = s % gridDim.x;
    by = s / gridDim.x;
}

// ---------------------------------------------------------------------------
// Merged f32->bf16 cast: 9 segments in one dispatch.
// ---------------------------------------------------------------------------
__device__ __forceinline__ void cast8(const float* in, unsigned short* out, int i) {
    float4 f0 = *(const float4*)&in[(size_t)i * 8];
    float4 f1 = *(const float4*)&in[(size_t)i * 8 + 4];
    unsigned short v[8] = {f2bf(f0.x), f2bf(f0.y), f2bf(f0.z), f2bf(f0.w),
                           f2bf(f1.x), f2bf(f1.y), f2bf(f1.z), f2bf(f1.w)};
    *(uint4*)&out[(size_t)i * 8] = *(uint4*)v;
}

__global__ __launch_bounds__(256) void cast_all(
    const float* x,  unsigned short* xb,
    const float* w1, unsigned short* w1b,
    const float* w2, unsigned short* w2b,
    const float* w3, unsigned short* w3b,
    const float* w4, unsigned short* w4b,
    const float* w5, unsigned short* w5b,
    const float* w6, unsigned short* w6b,
    const float* w7, unsigned short* w7b,
    const float* w8, unsigned short* w8b)
{
    const int blk = blockIdx.x;
    const int tid = threadIdx.x;
    if (blk < 2048)        cast8(x,  xb,  blk * 256 + tid);
    else if (blk < 2560)   cast8(w1, w1b, (blk - 2048) * 256 + tid);
    else if (blk < 3072)   cast8(w2, w2b, (blk - 2560) * 256 + tid);
    else if (blk < 3328)   cast8(w3, w3b, (blk - 3072) * 256 + tid);
    else if (blk < 3584)   cast8(w4, w4b, (blk - 3328) * 256 + tid);
    else if (blk < 3840)   cast8(w5, w5b, (blk - 3584) * 256 + tid);
    else if (blk < 4096)   cast8(w6, w6b, (blk - 3840) * 256 + tid);
    else if (blk < 4128)   cast8(w7, w7b, (blk - 4096) * 256 + tid);
    else                   cast8(w8, w8b, (blk - 4128) * 256 + tid);
}

// ---------------------------------------------------------------------------
// Fused dual-direction in-projection: dense xi/z, XCD swizzle, min-waves hint.
// ---------------------------------------------------------------------------
__global__ __launch_bounds__(256, 4) void inproj_bf16(
    const unsigned short* __restrict__ A,
    const unsigned short* __restrict__ Wf,
    const unsigned short* __restrict__ Wb,
    unsigned short* __restrict__ xi_f, unsigned short* __restrict__ z_f,
    unsigned short* __restrict__ xi_b, unsigned short* __restrict__ z_b)
{
    __shared__ unsigned short As[2][128][32];
    __shared__ unsigned short Ws[2][128][32];

    const int K = DMODEL;
    const int tid = threadIdx.x;
    int bx = blockIdx.x, by = blockIdx.y;
    xcd_swizzle(bx, by);
    const int rowbase = by * 128;
    const int colg = bx * 128;
    const int back = colg >= 2048;
    const unsigned short* W = back ? Wb : Wf;
    const int colbase = colg - (back ? 2048 : 0);
    const int is_z = colbase >= 1024;
    unsigned short* Cout = back ? (is_z ? z_b : xi_b) : (is_z ? z_f : xi_f);
    const int cofs = is_z ? 1024 : 0;

    const int wave = tid >> 6, lane = tid & 63;
    const int wm = wave >> 1, wn = wave & 1;
    const int lr = lane & 15;
    const int lc = lane >> 4;

    const int r0 = tid >> 2;
    const int cl = (tid & 3) ^ ((r0 >> 1) & 3);
    const unsigned short* Ag0 = A + (size_t)(rowbase + r0) * K + (cl << 3);
    const unsigned short* Ag1 = A + (size_t)(rowbase + r0 + 64) * K + (cl << 3);
    const unsigned short* Wg0 = W + (size_t)(colbase + r0) * K + (cl << 3);
    const unsigned short* Wg1 = W + (size_t)(colbase + r0 + 64) * K + (cl << 3);

    f32x4 acc[4][4];
#pragma unroll
    for (int i = 0; i < 4; ++i)
#pragma unroll
        for (int j = 0; j < 4; ++j)
            acc[i][j] = (f32x4){0.f, 0.f, 0.f, 0.f};

#define G_STAGE(bi, ko) do {                                   \
        gload16(Ag0 + (ko), &As[bi][wave << 4][0]);            \
        gload16(Ag1 + (ko), &As[bi][64 + (wave << 4)][0]);     \
        gload16(Wg0 + (ko), &Ws[bi][wave << 4][0]);            \
        gload16(Wg1 + (ko), &Ws[bi][64 + (wave << 4)][0]);     \
    } while (0)

#define G_COMPUTE(bi) do {                                     \
        bf16x8 af[4], bfv[4];                                  \
        _Pragma("unroll")                                      \
        for (int i = 0; i < 4; ++i) {                          \
            int R = wm * 64 + i * 16 + lr;                     \
            int pc = lc ^ ((R >> 1) & 3);                      \
            af[i] = *(const bf16x8*)&As[bi][R][pc << 3];       \
        }                                                      \
        _Pragma("unroll")                                      \
        for (int j = 0; j < 4; ++j) {                          \
            int R = wn * 64 + j * 16 + lr;                     \
            int pc = lc ^ ((R >> 1) & 3);                      \
            bfv[j] = *(const bf16x8*)&Ws[bi][R][pc << 3];      \
        }                                                      \
        _Pragma("unroll")                                      \
        for (int i = 0; i < 4; ++i)                            \
            _Pragma("unroll")                                  \
            for (int j = 0; j < 4; ++j)                        \
                acc[i][j] = __builtin_amdgcn_mfma_f32_16x16x32_bf16( \
                    af[i], bfv[j], acc[i][j], 0, 0, 0);        \
    } while (0)

    G_STAGE(0, 0);
    __syncthreads();
    for (int k0 = 0; k0 < K; k0 += 64) {
        G_STAGE(1, k0 + 32);
        __builtin_amdgcn_sched_barrier(0);
        G_COMPUTE(0);
        __syncthreads();
        if (k0 + 64 < K) G_STAGE(0, k0 + 64);
        __builtin_amdgcn_sched_barrier(0);
        G_COMPUTE(1);
        __syncthreads();
    }
#undef G_STAGE
#undef G_COMPUTE

    const int crow0 = rowbase + wm * 64 + ((lane >> 4) << 2);
    const int ccol0 = colbase + wn * 64 + lr;
#pragma unroll
    for (int j = 0; j < 4; ++j) {
        int col = ccol0 + j * 16 - cofs;          // 0..1023 within buffer
#pragma unroll
        for (int i = 0; i < 4; ++i) {
#pragma unroll
            for (int r = 0; r < 4; ++r) {
                int row = crow0 + i * 16 + r;
                if (back) row = (row & ~(LSEQ - 1)) + (LSEQ - 1 - (row & (LSEQ - 1)));
                Cout[(size_t)row * 1024 + col] = f2bf(acc[i][j][r]);
            }
        }
    }
}

// ---------------------------------------------------------------------------
// bf16 MFMA GEMM v5 + XCD swizzle + min-waves hint.
// ---------------------------------------------------------------------------
__global__ __launch_bounds__(256, 4) void gemm_bf16(
    const unsigned short* __restrict__ A,
    const unsigned short* __restrict__ A_hi, int lda,
    const unsigned short* __restrict__ W,
    const unsigned short* __restrict__ W_hi,
    const float* __restrict__ bias,
    void* __restrict__ Cp, int ldc, int c_bf16,
    int K, int act)
{
    __shared__ unsigned short As[2][128][32];
    __shared__ unsigned short Ws[2][128][32];

    const int tid = threadIdx.x;
    int bx = blockIdx.x, by = blockIdx.y;
    xcd_swizzle(bx, by);
    const int rowbase = by * 128;
    const int colbase = bx * 128;
    const unsigned short* Ause = A;
    const unsigned short* Wuse = W;
    int rlocal = rowbase;
    if (rowbase >= MTOT) { Ause = A_hi; Wuse = W_hi; rlocal = rowbase - MTOT; }

    const int wave = tid >> 6, lane = tid & 63;
    const int wm = wave >> 1, wn = wave & 1;
    const int lr = lane & 15;
    const int lc = lane >> 4;

    const int r0 = tid >> 2;
    const int cl = (tid & 3) ^ ((r0 >> 1) & 3);
    const unsigned short* Ag0 = Ause + (size_t)(rlocal + r0) * lda + (cl << 3);
    const unsigned short* Ag1 = Ause + (size_t)(rlocal + r0 + 64) * lda + (cl << 3);
    const unsigned short* Wg0 = Wuse + (size_t)(colbase + r0) * K + (cl << 3);
    const unsigned short* Wg1 = Wuse + (size_t)(colbase + r0 + 64) * K + (cl << 3);

    f32x4 acc[4][4];
#pragma unroll
    for (int i = 0; i < 4; ++i)
#pragma unroll
        for (int j = 0; j < 4; ++j)
            acc[i][j] = (f32x4){0.f, 0.f, 0.f, 0.f};

#define G_STAGE(bi, ko) do {                                   \
        gload16(Ag0 + (ko), &As[bi][wave << 4][0]);            \
        gload16(Ag1 + (ko), &As[bi][64 + (wave << 4)][0]);     \
        gload16(Wg0 + (ko), &Ws[bi][wave << 4][0]);            \
        gload16(Wg1 + (ko), &Ws[bi][64 + (wave << 4)][0]);     \
    } while (0)

#define G_COMPUTE(bi) do {                                     \
        bf16x8 af[4], bfv[4];                                  \
        _Pragma("unroll")                                      \
        for (int i = 0; i < 4; ++i) {                          \
            int R = wm * 64 + i * 16 + lr;                     \
            int pc = lc ^ ((R >> 1) & 3);                      \
            af[i] = *(const bf16x8*)&As[bi][R][pc << 3];       \
        }                                                      \
        _Pragma("unroll")                                      \
        for (int j = 0; j < 4; ++j) {                          \
            int R = wn * 64 + j * 16 + lr;                     \
            int pc = lc ^ ((R >> 1) & 3);                      \
            bfv[j] = *(const bf16x8*)&Ws[bi][R][pc << 3];      \
        }                                                      \
        _Pragma("unroll")                                      \
        for (int i = 0; i < 4; ++i)                            \
            _Pragma("unroll")                                  \
            for (int j = 0; j < 4; ++j)                        \
                acc[i][j] = __builtin_amdgcn_mfma_f32_16x16x32_bf16( \
                    af[i], bfv[j], acc[i][j], 0, 0, 0);        \
    } while (0)

    G_STAGE(0, 0);
    __syncthreads();
    for (int k0 = 0; k0 < K; k0 += 64) {
        G_STAGE(1, k0 + 32);
        __builtin_amdgcn_sched_barrier(0);
        G_COMPUTE(0);
        __syncthreads();
        if (k0 + 64 < K) G_STAGE(0, k0 + 64);
        __builtin_amdgcn_sched_barrier(0);
        G_COMPUTE(1);
        __syncthreads();
    }
#undef G_STAGE
#undef G_COMPUTE

    const int crow0 = rowbase + wm * 64 + ((lane >> 4) << 2);
    const int ccol0 = colbase + wn * 64 + lr;
#pragma unroll
    for (int j = 0; j < 4; ++j) {
        int col = ccol0 + j * 16;
        float bv = bias ? bias[col] : 0.f;
#pragma unroll
        for (int i = 0; i < 4; ++i) {
#pragma unroll
            for (int r = 0; r < 4; ++r) {
                int row = crow0 + i * 16 + r;
                float v = acc[i][j][r] + bv;
                if (act == 1) v = fmaxf(v, 0.f);
                if (c_bf16)
                    ((unsigned short*)Cp)[(size_t)row * ldc + col] = f2bf(v);
                else
                    ((float*)Cp)[(size_t)row * ldc + col] = v;
            }
        }
    }
}

// ---------------------------------------------------------------------------
// Dual-dir xproj (split-K): dbc2[2M,64] += xcbf2[2M,1024] @ xpw^T
// ---------------------------------------------------------------------------
__global__ __launch_bounds__(256, 4) void xproj_bf16(
    const unsigned short* __restrict__ A,
    const unsigned short* __restrict__ Wf,
    const unsigned short* __restrict__ Wb,
    float* __restrict__ Cp)
{
    __shared__ unsigned short As[2][128][32];
    __shared__ unsigned short Ws[2][64][32];

    const int tid = threadIdx.x;
    const int rowbase = blockIdx.x * 128;
    const int kbase = blockIdx.y * 256;
    const unsigned short* W = (rowbase >= MTOT) ? Wb : Wf;
    const int wave = tid >> 6, lane = tid & 63;
    const int wm = wave >> 1, wn = wave & 1;
    const int lr = lane & 15;
    const int lc = lane >> 4;

    const int r0 = tid >> 2;
    const int cl = (tid & 3) ^ ((r0 >> 1) & 3);
    const unsigned short* Ag0 = A + (size_t)(rowbase + r0) * EDIM + kbase + (cl << 3);
    const unsigned short* Ag1 = A + (size_t)(rowbase + r0 + 64) * EDIM + kbase + (cl << 3);
    const unsigned short* Wg  = W + (size_t)r0 * EDIM + kbase + (cl << 3);

    f32x4 acc[4][2];
#pragma unroll
    for (int i = 0; i < 4; ++i)
#pragma unroll
        for (int j = 0; j < 2; ++j)
            acc[i][j] = (f32x4){0.f, 0.f, 0.f, 0.f};

#define X_STAGE(bi, ko) do {                                   \
        gload16(Ag0 + (ko), &As[bi][wave << 4][0]);            \
        gload16(Ag1 + (ko), &As[bi][64 + (wave << 4)][0]);     \
        gload16(Wg  + (ko), &Ws[bi][wave << 4][0]);            \
    } while (0)

#define X_COMPUTE(bi) do {                                     \
        bf16x8 af[4], bfv[2];                                  \
        _Pragma("unroll")                                      \
        for (int i = 0; i < 4; ++i) {                          \
            int R = wm * 64 + i * 16 + lr;                     \
            int pc = lc ^ ((R >> 1) & 3);                      \
            af[i] = *(const bf16x8*)&As[bi][R][pc << 3];       \
        }                                                      \
        _Pragma("unroll")                                      \
        for (int j = 0; j < 2; ++j) {                          \
            int R = wn * 32 + j * 16 + lr;                     \
            int pc = lc ^ ((R >> 1) & 3);                      \
            bfv[j] = *(const bf16x8*)&Ws[bi][R][pc << 3];      \
        }                                                      \
        _Pragma("unroll")                                      \
        for (int i = 0; i < 4; ++i)                            \
            _Pragma("unroll")                                  \
            for (int j = 0; j < 2; ++j)                        \
                acc[i][j] = __builtin_amdgcn_mfma_f32_16x16x32_bf16( \
                    af[i], bfv[j], acc[i][j], 0, 0, 0);        \
    } while (0)

    X_STAGE(0, 0);
    __syncthreads();
    for (int k0 = 0; k0 < 256; k0 += 64) {
        X_STAGE(1, k0 + 32);
        __builtin_amdgcn_sched_barrier(0);
        X_COMPUTE(0);
        __syncthreads();
        if (k0 + 64 < 256) X_STAGE(0, k0 + 64);
        __builtin_amdgcn_sched_barrier(0);
        X_COMPUTE(1);
        __syncthreads();
    }
#undef X_STAGE
#undef X_COMPUTE

    const int crow0 = rowbase + wm * 64 + ((lane >> 4) << 2);
    const int ccol0 = wn * 32 + lr;
#pragma unroll
    for (int i = 0; i < 4; ++i)
#pragma unroll
        for (int j = 0; j < 2; ++j)
#pragma unroll
            for (int r = 0; r < 4; ++r)
                atomicAdd(&Cp[(size_t)(crow0 + i * 16 + r) * 64 + ccol0 + j * 16],
                          acc[i][j][r]);
}

// ---------------------------------------------------------------------------
// Dual-dir dt: delta2[2M][1024] (bf16), 16 rows/block, fast softplus.
// ---------------------------------------------------------------------------
__global__ __launch_bounds__(256) void dt_fused(
    const float* __restrict__ dbc2,
    const float* __restrict__ dtw_f, const float* __restrict__ dtb_f,
    const float* __restrict__ dtw_b, const float* __restrict__ dtb_b,
    unsigned short* __restrict__ delta2)
{
    __shared__ float sd[16][32];

    const int e  = blockIdx.x * 256 + threadIdx.x;
    const int m0 = blockIdx.y * 16;
    const float* dtw = (m0 >= MTOT) ? dtw_b : dtw_f;
    const float* dtb = (m0 >= MTOT) ? dtb_b : dtb_f;

    float w[32];
#pragma unroll
    for (int k = 0; k < 8; ++k) {
        float4 v = *(const float4*)&dtw[(size_t)e * 32 + k * 4];
        w[k * 4 + 0] = v.x; w[k * 4 + 1] = v.y;
        w[k * 4 + 2] = v.z; w[k * 4 + 3] = v.w;
    }
    const float bv = dtb[e];

    if (threadIdx.x < 128) {
        int r = threadIdx.x >> 3;
        int c = (threadIdx.x & 7) << 2;
        *(float4*)&sd[r][c] = *(const float4*)&dbc2[(size_t)(m0 + r) * 64 + c];
    }
    __syncthreads();

#pragma unroll
    for (int mm = 0; mm < 16; ++mm) {
        float acc = bv;
#pragma unroll
        for (int k = 0; k < 8; ++k) {
            float4 b4 = *(const float4*)&sd[mm][k * 4];
            acc = fmaf(b4.x, w[k * 4 + 0], acc);
            acc = fmaf(b4.y, w[k * 4 + 1], acc);
            acc = fmaf(b4.z, w[k * 4 + 2], acc);
            acc = fmaf(b4.w, w[k * 4 + 3], acc);
        }
        delta2[(size_t)(m0 + mm) * EDIM + e] = f2bf(softplus_fast(acc));
    }
}

// ---------------------------------------------------------------------------
// Dual-dir depthwise causal conv + bias + silu, dense xi + 8-row blocking
// (11 tap-row loads per 8 outputs; weights amortized 8x). Grid (MTOT/8, 2).
// ---------------------------------------------------------------------------
__global__ __launch_bounds__(256) void conv_silu(
    const unsigned short* __restrict__ xi_f, const unsigned short* __restrict__ xi_b,
    const float* __restrict__ cwf, const float* __restrict__ cbf,
    const float* __restrict__ cwb, const float* __restrict__ cbb,
    unsigned short* __restrict__ xcbf2)
{
    const int dir = blockIdx.y;
    const unsigned short* xi = dir ? xi_b : xi_f;
    const float* cw = dir ? cwb : cwf;
    const float* cb = dir ? cbb : cbf;
    const int e = threadIdx.x << 2;
    const int m0 = blockIdx.x << 3;           // 0..8184
    const int t0 = m0 & (LSEQ - 1);

    float4 w0 = *(const float4*)&cw[e * 4];
    float4 w1 = *(const float4*)&cw[e * 4 + 4];
    float4 w2 = *(const float4*)&cw[e * 4 + 8];
    float4 w3 = *(const float4*)&cw[e * 4 + 12];
    float4 bias = *(const float4*)&cb[e];

    // load tap rows m0-3 .. m0+7 (11 rows x 4 cols)
    float v[11][4];
#pragma unroll
    for (int r = 0; r < 11; ++r) {
        if (t0 - 3 + r >= 0) {
            uint2 raw = *(const uint2*)&xi[(size_t)(m0 - 3 + r) * 1024 + e];
            v[r][0] = bf2f((unsigned short)(raw.x & 0xffff));
            v[r][1] = bf2f((unsigned short)(raw.x >> 16));
            v[r][2] = bf2f((unsigned short)(raw.y & 0xffff));
            v[r][3] = bf2f((unsigned short)(raw.y >> 16));
        } else {
            v[r][0] = v[r][1] = v[r][2] = v[r][3] = 0.f;
        }
    }

#pragma unroll
    for (int rr = 0; rr < 8; ++rr) {          // output rows m0+rr
        float4 acc = bias;
        acc.x = fmaf(w0.x, v[rr][0], acc.x);
        acc.y = fmaf(w1.x, v[rr][1], acc.y);
        acc.z = fmaf(w2.x, v[rr][2], acc.z);
        acc.w = fmaf(w3.x, v[rr][3], acc.w);
        acc.x = fmaf(w0.y, v[rr + 1][0], acc.x);
        acc.y = fmaf(w1.y, v[rr + 1][1], acc.y);
        acc.z = fmaf(w2.y, v[rr + 1][2], acc.z);
        acc.w = fmaf(w3.y, v[rr + 1][3], acc.w);
        acc.x = fmaf(w0.z, v[rr + 2][0], acc.x);
        acc.y = fmaf(w1.z, v[rr + 2][1], acc.y);
        acc.z = fmaf(w2.z, v[rr + 2][2], acc.z);
        acc.w = fmaf(w3.z, v[rr + 2][3], acc.w);
        acc.x = fmaf(w0.w, v[rr + 3][0], acc.x);
        acc.y = fmaf(w1.w, v[rr + 3][1], acc.y);
        acc.z = fmaf(w2.w, v[rr + 3][2], acc.z);
        acc.w = fmaf(w3.w, v[rr + 3][3], acc.w);
        float4 o;
        o.x = acc.x / (1.f + __expf(-acc.x));
        o.y = acc.y / (1.f + __expf(-acc.y));
        o.z = acc.z / (1.f + __expf(-acc.z));
        o.w = acc.w / (1.f + __expf(-acc.w));
        unsigned short b4[4] = {f2bf(o.x), f2bf(o.y), f2bf(o.z), f2bf(o.w)};
        *(uint2*)&xcbf2[((size_t)dir * MTOT + m0 + rr) * EDIM + e] = *(uint2*)b4;
    }
}

// ---------------------------------------------------------------------------
// Dual-dir chunked scan with power-chain fast path.
// ---------------------------------------------------------------------------
__global__ __launch_bounds__(256) void scan_part1(
    const unsigned short* __restrict__ delta2,
    const unsigned short* __restrict__ xcbf2,
    const float* __restrict__ dbc2,
    const float* __restrict__ Alog_f, const float* __restrict__ Alog_b,
    float* __restrict__ Psum, float* __restrict__ Ssum)
{
    __shared__ float sB[CHLEN][16];

    const int bd = blockIdx.y;               // 0..15 = dir*8 + b
    const int dir = bd >> 3;
    const int b = bd & 7;
    const int ch = blockIdx.z;
    const int tid = threadIdx.x;
    const int e  = blockIdx.x * 256 + tid;
    const size_t dirOff = (size_t)dir * MTOT;
    const int row0 = b * LSEQ + ch * CHLEN;
    const float* Alog = dir ? Alog_b : Alog_f;

#pragma unroll
    for (int it = 0; it < 4; ++it) {
        int q = tid + it * 256;
        int t = q >> 4, n = q & 15;
        sB[t][n] = dbc2[(dirOff + row0 + t) * 64 + 32 + n];
    }

    float Aen[16];
    bool fastA = true;
#pragma unroll
    for (int k = 0; k < 4; ++k) {
        float4 a4 = *(const float4*)&Alog[e * DSTATE + k * 4];
        Aen[k * 4 + 0] = -__expf(a4.x);
        Aen[k * 4 + 1] = -__expf(a4.y);
        Aen[k * 4 + 2] = -__expf(a4.z);
        Aen[k * 4 + 3] = -__expf(a4.w);
    }
#pragma unroll
    for (int n = 0; n < 16; ++n)
        fastA = fastA && (fabsf(Aen[n] + (float)(n + 1)) <= 1e-3f * (n + 1));

    float h[16];
#pragma unroll
    for (int n = 0; n < 16; ++n) h[n] = 0.f;
    float sumd = 0.f;

    __syncthreads();

    const size_t base = (dirOff + row0) * EDIM + e;
    float dnx = bf2f(delta2[base]);
    float xnx = bf2f(xcbf2[base]);

    for (int t = 0; t < CHLEN; ++t) {
        float d = dnx, xcv = xnx;
        if (t + 1 < CHLEN) {
            dnx = bf2f(delta2[base + (size_t)(t + 1) * EDIM]);
            xnx = bf2f(xcbf2[base + (size_t)(t + 1) * EDIM]);
        }
        sumd += d;
        float dx = d * xcv;
        float Bt[16];
        *(float4*)&Bt[0]  = *(const float4*)&sB[t][0];
        *(float4*)&Bt[4]  = *(const float4*)&sB[t][4];
        *(float4*)&Bt[8]  = *(const float4*)&sB[t][8];
        *(float4*)&Bt[12] = *(const float4*)&sB[t][12];
        float da[16];
        if (fastA) {
            pow16(__expf(-d), da);
        } else {
#pragma unroll
            for (int n = 0; n < 16; ++n) da[n] = __expf(d * Aen[n]);
        }
#pragma unroll
        for (int n = 0; n < 16; ++n)
            h[n] = fmaf(da[n], h[n], dx * Bt[n]);
    }

    size_t idx = ((size_t)(bd * NCH + ch) * EDIM + e) * DSTATE;
    float P[16];
    if (fastA) {
        pow16(__expf(-sumd), P);
    } else {
#pragma unroll
        for (int n = 0; n < 16; ++n) P[n] = __expf(Aen[n] * sumd);
    }
#pragma unroll
    for (int k = 0; k < 4; ++k) {
        *(float4*)&Psum[idx + k * 4] = *(float4*)&P[k * 4];
        *(float4*)&Ssum[idx + k * 4] = *(float4*)&h[k * 4];
    }
}

__global__ __launch_bounds__(256) void scan_combine(
    float* __restrict__ Psum, const float* __restrict__ Ssum)
{
    int i = blockIdx.x * 256 + threadIdx.x;
    int bd = i >> 14;
    int r = i & 16383;
    float H = 0.f;
#pragma unroll
    for (int ch = 0; ch < NCH; ++ch) {
        size_t idx = ((size_t)(bd * NCH + ch) << 14) + r;
        float p = Psum[idx];
        float s = Ssum[idx];
        Psum[idx] = H;
        H = fmaf(p, H, s);
    }
}

__global__ __launch_bounds__(256) void scan_part2(
    unsigned short* __restrict__ delta2,          // in: delta, out: g (in-place)
    const unsigned short* __restrict__ xcbf2,
    const float* __restrict__ dbc2,
    const float* __restrict__ Alog_f, const float* __restrict__ Alog_b,
    const float* __restrict__ Dvec_f, const float* __restrict__ Dvec_b,
    const unsigned short* __restrict__ z_f, const unsigned short* __restrict__ z_b,
    const float* __restrict__ Hstart)
{
    __shared__ float sB[CHLEN][16], sC[CHLEN][16];

    const int bd = blockIdx.y;
    const int dir = bd >> 3;
    const int b = bd & 7;
    const int ch = blockIdx.z;
    const int tid = threadIdx.x;
    const int e  = blockIdx.x * 256 + tid;
    const size_t dirOff = (size_t)dir * MTOT;
    const int row0 = b * LSEQ + ch * CHLEN;
    const float* Alog = dir ? Alog_b : Alog_f;
    const float* Dvec = dir ? Dvec_b : Dvec_f;
    const unsigned short* zb = dir ? z_b : z_f;

#pragma unroll
    for (int it = 0; it < 8; ++it) {
        int q = tid + it * 256;
        int t = q >> 5, c = q & 31;
        float v = dbc2[(dirOff + row0 + t) * 64 + 32 + c];
        if (c < 16) sB[t][c] = v; else sC[t][c - 16] = v;
    }

    float Aen[16];
    bool fastA = true;
#pragma unroll
    for (int k = 0; k < 4; ++k) {
        float4 a4 = *(const float4*)&Alog[e * DSTATE + k * 4];
        Aen[k * 4 + 0] = -__expf(a4.x);
        Aen[k * 4 + 1] = -__expf(a4.y);
        Aen[k * 4 + 2] = -__expf(a4.z);
        Aen[k * 4 + 3] = -__expf(a4.w);
    }
#pragma unroll
    for (int n = 0; n < 16; ++n)
        fastA = fastA && (fabsf(Aen[n] + (float)(n + 1)) <= 1e-3f * (n + 1));
    const float Dv = Dvec[e];

    float h[16];
    {
        size_t idx = ((size_t)(bd * NCH + ch) * EDIM + e) * DSTATE;
#pragma unroll
        for (int k = 0; k < 4; ++k)
            *(float4*)&h[k * 4] = *(const float4*)&Hstart[idx + k * 4];
    }

    __syncthreads();

    const size_t base = (dirOff + row0) * EDIM + e;
    const size_t zbase = (size_t)row0 * 1024 + e;    // dense z buffer
    float dnx = bf2f(delta2[base]);
    float xnx = bf2f(xcbf2[base]);
    float znx = bf2f(zb[zbase]);

    for (int t = 0; t < CHLEN; ++t) {
        float d = dnx, xcv = xnx, zv = znx;
        if (t + 1 < CHLEN) {
            dnx = bf2f(delta2[base + (size_t)(t + 1) * EDIM]);
            xnx = bf2f(xcbf2[base + (size_t)(t + 1) * EDIM]);
            znx = bf2f(zb[zbase + (size_t)(t + 1) * 1024]);
        }
        float dx = d * xcv;
        float Bt[16], Ct[16];
        *(float4*)&Bt[0]  = *(const float4*)&sB[t][0];
        *(float4*)&Bt[4]  = *(const float4*)&sB[t][4];
        *(float4*)&Bt[8]  = *(const float4*)&sB[t][8];
        *(float4*)&Bt[12] = *(const float4*)&sB[t][12];
        *(float4*)&Ct[0]  = *(const float4*)&sC[t][0];
        *(float4*)&Ct[4]  = *(const float4*)&sC[t][4];
        *(float4*)&Ct[8]  = *(const float4*)&sC[t][8];
        *(float4*)&Ct[12] = *(const float4*)&sC[t][12];
        float da[16];
        if (fastA) {
            pow16(__expf(-d), da);
        } else {
#pragma unroll
            for (int n = 0; n < 16; ++n) da[n] = __expf(d * Aen[n]);
        }
        float y = 0.f;
#pragma unroll
        for (int n = 0; n < 16; ++n) {
            h[n] = fmaf(da[n], h[n], dx * Bt[n]);
            y = fmaf(h[n], Ct[n], y);
        }
        y = fmaf(Dv, xcv, y);
        float sig = 1.f / (1.f + __expf(-zv));
        float zz  = zv * sig;
        delta2[base + (size_t)t * EDIM] = f2bf(fmaf(zz, y - xcv, xcv));
    }
}

// ---------------------------------------------------------------------------
__device__ __forceinline__ void block_reduce4(float4& s, float4* red, int tid)
{
#pragma unroll
    for (int off = 1; off < 64; off <<= 1) {
        s.x += __shfl_xor(s.x, off);
        s.y += __shfl_xor(s.y, off);
        s.z += __shfl_xor(s.z, off);
        s.w += __shfl_xor(s.w, off);
    }
    if ((tid & 63) == 0) red[tid >> 6] = s;
    __syncthreads();
    float4 a = red[0], b = red[1], c = red[2], d = red[3];
    s.x = a.x + b.x + c.x + d.x;
    s.y = a.y + b.y + c.y + d.y;
    s.z = a.z + b.z + c.z + d.z;
    s.w = a.w + b.w + c.w + d.w;
}

__global__ __launch_bounds__(256) void ln_combine(
    const float* __restrict__ yproj, const float* __restrict__ x,
    const float* __restrict__ g1, const float* __restrict__ b1,
    const float* __restrict__ g2, const float* __restrict__ b2,
    float* __restrict__ xs, unsigned short* __restrict__ xsbf)
{
    __shared__ float4 red[4];
    const int row = blockIdx.x, tid = threadIdx.x;
    const float* yf = yproj + (size_t)row * DMODEL;
    const float* yb = yproj + (size_t)(MTOT + row) * DMODEL;
    const float* xr = x + (size_t)row * DMODEL;

    float vf[2], vb[2];
#pragma unroll
    for (int j = 0; j < 2; ++j) {
        int i = tid + j * 256;
        float xi = xr[i];
        vf[j] = yf[i] + xi;
        vb[j] = yb[i] + xi;
    }
    float4 s = make_float4(vf[0] + vf[1], vf[0] * vf[0] + vf[1] * vf[1],
                           vb[0] + vb[1], vb[0] * vb[0] + vb[1] * vb[1]);
    block_reduce4(s, red, tid);
    const float inv = 1.f / DMODEL;
    float mf = s.x * inv, mb = s.z * inv;
    float rf = rsqrtf(s.y * inv - mf * mf + EPSLN);
    float rb = rsqrtf(s.w * inv - mb * mb + EPSLN);
#pragma unroll
    for (int j = 0; j < 2; ++j) {
        int i = tid + j * 256;
        float a  = (vf[j] - mf) * rf * g1[i] + b1[i];
        float bb = (vb[j] - mb) * rb * g2[i] + b2[i];
        float v = a + bb;
        xs[(size_t)row * DMODEL + i] = v;
        xsbf[(size_t)row * DMODEL + i] = f2bf(v);
    }
}

__global__ __launch_bounds__(256) void ln_final(
    const float* __restrict__ h2, const float* __restrict__ xs,
    const float* __restrict__ g3, const float* __restrict__ b3,
    float* __restrict__ out)
{
    __shared__ float4 red[4];
    const int row = blockIdx.x, tid = threadIdx.x;
    float v[2];
#pragma unroll
    for (int j = 0; j < 2; ++j) {
        int i = tid + j * 256;
        v[j] = h2[(size_t)row * DMODEL + i] + xs[(size_t)row * DMODEL + i];
    }
    float4 s = make_float4(v[0] + v[1], v[0] * v[0] + v[1] * v[1], 0.f, 0.f);
    block_reduce4(s, red, tid);
    const float inv = 1.f / DMODEL;
    float m  = s.x * inv;
    float rs = rsqrtf(s.y * inv - m * m + EPSLN);
#pragma unroll
    for (int j = 0; j < 2; ++j) {
        int i = tid + j * 256;
        out[(size_t)row * DMODEL + i] = (v[j] - m) * rs * g3[i] + b3[i];
    }
}

// ---------------------------------------------------------------------------
extern "C" void kernel_launch(void* const* d_in, const int* in_sizes, int n_in,
                              void* d_out, int out_size, void* d_ws, size_t ws_size,
                              hipStream_t stream)
{
    (void)in_sizes; (void)n_in;

    const float* x    = (const float*)d_in[28];
    const float* n1g  = (const float*)d_in[18];
    const float* n1b  = (const float*)d_in[19];
    const float* n2g  = (const float*)d_in[20];
    const float* n2b  = (const float*)d_in[21];
    const float* n3g  = (const float*)d_in[22];
    const float* n3b  = (const float*)d_in[23];
    const float* ff1w = (const float*)d_in[24];
    const float* ff1b = (const float*)d_in[25];
    const float* ff2w = (const float*)d_in[26];
    const float* ff2b = (const float*)d_in[27];

    const size_t need_floats =
        (size_t)MTOT * 2048 + (size_t)MTOT * 1024 + (size_t)MTOT * 1024 +
        (size_t)MTOT * 64 + (size_t)2 * MTOT * 512 + (size_t)MTOT * 512;
    if (ws_size < need_floats * sizeof(float)) return;
    if (out_size < MTOT * DMODEL) return;

    float* ws = (float*)d_ws;
    float* region0 = ws;
    float* region1 = ws + (size_t)16 * 1048576;
    float* region2 = ws + (size_t)24 * 1048576;
    float* super   = ws + (size_t)32 * 1048576;

    // region0: 4 dense bf16 buffers [8192][1024]: xi_f | z_f | xi_b | z_b
    unsigned short* xi_f = (unsigned short*)region0;
    unsigned short* z_f  = xi_f + (size_t)MTOT * 1024;
    unsigned short* xi_b = z_f  + (size_t)MTOT * 1024;
    unsigned short* z_b  = xi_b + (size_t)MTOT * 1024;
    unsigned short* xcbf2  = (unsigned short*)region1;
    unsigned short* delta2 = (unsigned short*)region2;   // becomes g2
    float* dbc2 = super;                                 // 1M floats [2M][64]
    float* Psum = super + (size_t)1 * 1048576;
    float* Ssum = super + (size_t)5 * 1048576;
    unsigned short* xpwb_f = (unsigned short*)(super + (size_t)9 * 1048576);
    unsigned short* xpwb_b = xpwb_f + 65536;
    // post-scan overlays:
    float* yproj = super;
    float* xs    = super + (size_t)8 * 1048576;
    unsigned short* xsbf = (unsigned short*)region0;     // xi/z dead after scans
    unsigned short* h1bf = (unsigned short*)(region0 + (size_t)4 * 1048576);
    float* h2    = region1;

    unsigned short* ob     = (unsigned short*)d_out;
    unsigned short* xbf    = ob;
    unsigned short* inwf_b = ob + (size_t)4194304;
    unsigned short* inwb_b = ob + (size_t)5242880;
    unsigned short* outwf_b= ob + (size_t)6291456;
    unsigned short* outwb_b= ob + (size_t)6815744;
    unsigned short* ff1w_b = ob + (size_t)7340032;
    unsigned short* ff2w_b = ob + (size_t)7864320;

    cast_all<<<4160, 256, 0, stream>>>(
        x, xbf,
        (const float*)d_in[0], inwf_b,
        (const float*)d_in[9], inwb_b,
        (const float*)d_in[8], outwf_b,
        (const float*)d_in[17], outwb_b,
        ff1w, ff1w_b,
        ff2w, ff2w_b,
        (const float*)d_in[3], xpwb_f,
        (const float*)d_in[12], xpwb_b);

    inproj_bf16<<<dim3(4096 / 128, MTOT / 128), 256, 0, stream>>>(
        xbf, inwf_b, inwb_b, xi_f, z_f, xi_b, z_b);

    conv_silu<<<dim3(MTOT / 8, 2), 256, 0, stream>>>(
        xi_f, xi_b,
        (const float*)d_in[1], (const float*)d_in[2],
        (const float*)d_in[10], (const float*)d_in[11], xcbf2);

    hipMemsetAsync(dbc2, 0, (size_t)2 * MTOT * 64 * sizeof(float), stream);
    xproj_bf16<<<dim3(2 * MTOT / 128, 4), 256, 0, stream>>>(
        xcbf2, xpwb_f, xpwb_b, dbc2);

    dt_fused<<<dim3(EDIM / 256, 2 * MTOT / 16), 256, 0, stream>>>(
        dbc2, (const float*)d_in[4], (const float*)d_in[5],
        (const float*)d_in[13], (const float*)d_in[14], delta2);

    scan_part1<<<dim3(EDIM / 256, 2 * BATCH, NCH), 256, 0, stream>>>(
        delta2, xcbf2, dbc2,
        (const float*)d_in[6], (const float*)d_in[15], Psum, Ssum);
    scan_combine<<<(2 * BATCH * EDIM * DSTATE) / 256, 256, 0, stream>>>(
        Psum, Ssum);
    scan_part2<<<dim3(EDIM / 256, 2 * BATCH, NCH), 256, 0, stream>>>(
        delta2, xcbf2, dbc2,
        (const float*)d_in[6], (const float*)d_in[15],
        (const float*)d_in[7], (const float*)d_in[16],
        z_f, z_b, Psum);

    gemm_bf16<<<dim3(512 / 128, 2 * MTOT / 128), 256, 0, stream>>>(
        delta2, delta2 + (size_t)MTOT * EDIM, EDIM, outwf_b, outwb_b,
        nullptr, yproj, DMODEL, 0, EDIM, 0);

    ln_combine<<<MTOT, 256, 0, stream>>>(yproj, x, n1g, n1b, n2g, n2b, xs, xsbf);
    gemm_bf16<<<dim3(DFF / 128, MTOT / 128), 256, 0, stream>>>(
        xsbf, xsbf, DMODEL, ff1w_b, ff1w_b, ff1b, h1bf, DFF, 1, DMODEL, 1);
    gemm_bf16<<<dim3(DMODEL / 128, MTOT / 128), 256, 0, stream>>>(
        h1bf, h1bf, DFF, ff2w_b, ff2w_b, ff2b, h2, DMODEL, 0, DFF, 0);
    ln_final<<<MTOT, 256, 0, stream>>>(h2, xs, n3g, n3b, (float*)d_out);
}